// Round 8
// baseline (119166.260 us; speedup 1.0000x reference)
//
#include <hip/hip_runtime.h>

#define BB 32
#define TT 256
#define SS 1600
#define DE 1024
#define VV 1000
#define EM 512
#define PR 256
#define LU 1024
#define AA 128
#define FF 32
#define KK 31

typedef __attribute__((ext_vector_type(8))) short short8;
typedef __attribute__((ext_vector_type(4))) float f32x4;

// ---------- workspace layout (float units) ----------
#define F_KEYS   ((size_t)0)
#define F_M      (F_KEYS + 6553600)
#define F_PBF    (F_M + 4096)            // ushort TT*8192
#define F_WPA    (F_PBF + 1048576)       // ushort 256*5*8192
#define F_WP0    (F_WPA + 5242880)       // ushort 256*6*8192
#define F_WP1    (F_WP0 + 6291456)       // ushort 256*4*8192
#define F_WCP    (F_WP1 + 4194304)       // float 250*2048*4
#define F_MEMBF  (F_WCP + 2048000)       // ushort 32*1600*1024
#define F_ST     (F_MEMBF + 26214400)    // ---- zeroed region start ----
#define F_HA32   (F_ST)
#define F_CA     (F_HA32 + 32768)
#define F_C0     (F_CA + 32768)
#define F_C1     (F_C0 + 32768)
#define F_AST    (F_C1 + 32768)          // 2 * 51200 (ping-pong)
#define F_HABF   (F_AST + 102400)        // ushort 2*32768
#define F_H0BF   (F_HABF + 32768)
#define F_H1BF   (F_H0BF + 32768)
#define F_CTXBF  (F_H1BF + 32768)        // ushort 32768
#define F_CTXT   (F_CTXBF + 16384)       // float 32768
#define F_H1T    (F_CTXT + 32768)        // float 32768
#define F_ZERO   (F_H1T + 32768)         // ushort 16384 (zero chunk)
#define F_BAR    (F_ZERO + 8192)
#define F_STEND  (F_BAR + 64)            // ---- zeroed region end ----
#define F_HP     (F_STEND)               // float TT*32*8 padded to 256
#define F_SP     (F_HP + 2097152)

__device__ __forceinline__ float bf2f(ushort u) {
  unsigned int x = ((unsigned int)u) << 16;
  return __builtin_bit_cast(float, x);
}
__device__ __forceinline__ ushort f2bf(float f) {
  unsigned int x = __builtin_bit_cast(unsigned int, f);
  return (ushort)((x + 0x7FFFu + ((x >> 16) & 1u)) >> 16);
}
__device__ __forceinline__ void gload16(const void* g, void* l) {
  __builtin_amdgcn_global_load_lds(
      (const __attribute__((address_space(1))) void*)g,
      (__attribute__((address_space(3))) void*)l, 16, 0, 0);
}
__device__ __forceinline__ float ftanh(float x) {
  float e = __expf(2.f * x);
  return 1.f - 2.f / (e + 1.f);
}
__device__ __forceinline__ float fsig(float x) {
  return 1.f / (1.f + __expf(-x));
}
// coherent (sc0 sc1) path for mutable cross-block data: bypasses per-XCD L2,
// hits shared L3 -> no fences needed, read-only data stays L2-cached.
__device__ __forceinline__ float ldaf(const float* p) {
  return __hip_atomic_load(p, __ATOMIC_RELAXED, __HIP_MEMORY_SCOPE_AGENT);
}
__device__ __forceinline__ void staf(float* p, float v) {
  __hip_atomic_store(p, v, __ATOMIC_RELAXED, __HIP_MEMORY_SCOPE_AGENT);
}
__device__ __forceinline__ unsigned long long ldau(const unsigned long long* p) {
  return __hip_atomic_load(p, __ATOMIC_RELAXED, __HIP_MEMORY_SCOPE_AGENT);
}
__device__ __forceinline__ void stau(unsigned long long* p, unsigned long long v) {
  __hip_atomic_store(p, v, __ATOMIC_RELAXED, __HIP_MEMORY_SCOPE_AGENT);
}

// ---------------- once-per-call precompute ----------------

__global__ __launch_bounds__(256) void conv_mem(const float* __restrict__ in,
                                                ushort* __restrict__ out, int n4)
{
  int i = blockIdx.x * 256 + threadIdx.x;
  if (i < n4) {
    float4 v = *(const float4*)(in + (size_t)i * 4);
    ushort4 o;
    o.x = f2bf(v.x); o.y = f2bf(v.y); o.z = f2bf(v.z); o.w = f2bf(v.w);
    *(ushort4*)(out + (size_t)i * 4) = o;
  }
}

// pack LSTM layer weights: dst[blk][kc][Sl][c][kg^(c&3)][e], CK=512, bf16
__global__ __launch_bounds__(256) void pack_lstm(const float* __restrict__ Wm,
    const float* __restrict__ Um, int lenW, int ktot, ushort* __restrict__ dst, int kcmax)
{
  int k = blockIdx.x;
  int t = threadIdx.x;
  float vals[16];
  if (k < lenW) {
    const float* s = Wm + (size_t)k * 4096 + t * 16;
#pragma unroll
    for (int i = 0; i < 16; i++) vals[i] = s[i];
  } else if (k < ktot) {
    const float* s = Um + (size_t)(k - lenW) * 4096 + t * 16;
#pragma unroll
    for (int i = 0; i < 16; i++) vals[i] = s[i];
  } else {
#pragma unroll
    for (int i = 0; i < 16; i++) vals[i] = 0.f;
  }
  int kc = k >> 9, Sl = (k >> 5) & 15, kg = (k >> 3) & 3, e = k & 7;
#pragma unroll
  for (int i = 0; i < 16; i++) {
    int zcol = t * 16 + i;
    int gate = zcol >> 10, jj = zcol & 1023;
    int blk = jj >> 2, c = gate * 4 + (jj & 3);
    size_t off = ((size_t)blk * kcmax + kc) * 8192
               + Sl * 512 + c * 32 + ((kg ^ (c & 3)) * 8) + e;
    dst[off] = f2bf(vals[i]);
  }
}

// pack Wc: dst[cb][k][4] fp32
__global__ __launch_bounds__(256) void pack_wc(const float* __restrict__ Wc,
                                               float* __restrict__ dst)
{
  int k = blockIdx.x;  // 2048
  int t = threadIdx.x;
  if (t < 250) {
    float4 v = *(const float4*)(Wc + (size_t)k * VV + t * 4);
    *(float4*)(dst + (size_t)t * 8192 + k * 4) = v;
  }
}

__global__ __launch_bounds__(256) void keys_kernel(const float* __restrict__ mem,
                                                   const float* __restrict__ Wmem,
                                                   float* __restrict__ keys)
{
  int stile = blockIdx.x;
  int b = blockIdx.y;
  int t = threadIdx.x;
  __shared__ float Xt[8 * 1032];
  const float* mp = mem + ((size_t)b * SS + (size_t)stile * 8) * DE;
  for (int li = t; li < 8 * 256; li += 256) {
    int row = li >> 8, c4 = li & 255;
    float4 v = *(const float4*)(mp + row * DE + c4 * 4);
    *(float4*)(Xt + row * 1032 + c4 * 4) = v;
  }
  __syncthreads();
  int sl = t >> 5, u = t & 31;
  float acc[4] = {0.f, 0.f, 0.f, 0.f};
  for (int k = 0; k < DE; k++) {
    float x = Xt[sl * 1032 + k];
    const float* wr = Wmem + k * AA;
#pragma unroll
    for (int jj = 0; jj < 4; jj++) acc[jj] += x * wr[u + 32 * jj];
  }
  float* kp = keys + ((size_t)b * SS + (size_t)stile * 8 + sl) * AA;
#pragma unroll
  for (int jj = 0; jj < 4; jj++) kp[u + 32 * jj] = acc[jj];
}

__global__ void mconv_kernel(const float* __restrict__ ck, const float* __restrict__ Wloc,
                             float* __restrict__ M)
{
  int a = threadIdx.x;
  int k = blockIdx.x;
  float acc = 0.f;
  for (int c = 0; c < FF; c++) acc += ck[k * FF + c] * Wloc[c * AA + a];
  M[k * AA + a] = acc;
}

__global__ __launch_bounds__(256) void prenet_all(const int* __restrict__ tokens,
    const float* __restrict__ emb, const float* __restrict__ Wp1, const float* __restrict__ bp1,
    const float* __restrict__ Wp2, const float* __restrict__ bp2, ushort* __restrict__ Pbf)
{
  int tstep = blockIdx.x;
  int bh = blockIdx.y;
  int t = threadIdx.x;
  __shared__ float X[16 * 512];
  __shared__ float P1s[16 * 256];
  for (int li = t; li < 16 * 128; li += 256) {
    int bb = li >> 7, c4 = li & 127;
    int tok = tokens[(bh * 16 + bb) * TT + tstep];
    *(float4*)(X + bb * 512 + c4 * 4) = *(const float4*)(emb + (size_t)tok * EM + c4 * 4);
  }
  __syncthreads();
  int j = t;
  float acc[16];
#pragma unroll
  for (int i = 0; i < 16; i++) acc[i] = 0.f;
  for (int k = 0; k < EM; k++) {
    float w = Wp1[k * PR + j];
#pragma unroll
    for (int i = 0; i < 16; i++) acc[i] += X[i * 512 + k] * w;
  }
#pragma unroll
  for (int i = 0; i < 16; i++) P1s[i * 256 + j] = fmaxf(acc[i] + bp1[j], 0.f);
  __syncthreads();
#pragma unroll
  for (int i = 0; i < 16; i++) acc[i] = 0.f;
  for (int k = 0; k < PR; k++) {
    float w = Wp2[k * PR + j];
#pragma unroll
    for (int i = 0; i < 16; i++) acc[i] += P1s[i * 256 + k] * w;
  }
  ushort* outp = Pbf + (size_t)tstep * 8192 + (size_t)bh * 16 * 256;
#pragma unroll
  for (int i = 0; i < 16; i++) outp[i * 256 + j] = f2bf(fmaxf(acc[i] + bp2[j], 0.f));
}

// ---------------- grid barrier: NO cache-maintenance fences ----------------
// All cross-block data moves via sc1 (agent-atomic) path; vmcnt(0) drain before
// arrival guarantees visibility at the coherence point (L3).
__device__ __forceinline__ void gbar(int* cnt, int* sense, int ep)
{
  asm volatile("s_waitcnt vmcnt(0) lgkmcnt(0)" ::: "memory");
  __syncthreads();
  if (threadIdx.x == 0)
    __hip_atomic_fetch_add(&cnt[blockIdx.x & 31], 1, __ATOMIC_RELAXED,
                           __HIP_MEMORY_SCOPE_AGENT);
  if (blockIdx.x == 0) {
    if (threadIdx.x < 32) {
      int tgt = 8 * ep;
      while (__hip_atomic_load(&cnt[threadIdx.x], __ATOMIC_RELAXED,
                               __HIP_MEMORY_SCOPE_AGENT) < tgt)
        __builtin_amdgcn_s_sleep(2);
    }
    __syncthreads();
    if (threadIdx.x == 0)
      __hip_atomic_store(sense, ep, __ATOMIC_RELAXED, __HIP_MEMORY_SCOPE_AGENT);
  } else if (threadIdx.x == 0) {
    while (__hip_atomic_load(sense, __ATOMIC_RELAXED,
                             __HIP_MEMORY_SCOPE_AGENT) < ep)
      __builtin_amdgcn_s_sleep(2);
  }
  __syncthreads();
}

// ---------------- fused full-K gemm + gates ----------------
struct XSeg { const ushort* p0; int n0; const ushort* p1; int n1;
              const ushort* p2; int n2; const ushort* pz; };

__device__ __forceinline__ const ushort* xseg_ptr(const XSeg& xs, int hc)
{
  if (hc < xs.n0) return xs.p0 + (size_t)hc * 8192;
  hc -= xs.n0;
  if (hc < xs.n1) return xs.p1 + (size_t)hc * 8192;
  hc -= xs.n1;
  if (hc < xs.n2) return xs.p2 + (size_t)hc * 8192;
  return xs.pz;
}

__device__ void gemm_gates(int bid, const XSeg& xs, const ushort* Wp, int kcmax,
    const float* bias, float* cst, float* h32, ushort* hbf, float* hT,
    float* hpart_slot, const float* WsV, char* lds)
{
  ushort* wbuf = (ushort*)lds;                     // 2 * 8192 us
  ushort* xbuf = (ushort*)(lds + 32768);           // 2 * 16640 us
  float*  zsh  = (float*)(lds + 32768 + 66560);    // 2048 f
  const int t = threadIdx.x;
  const int lane = t & 63;
  const int w = __builtin_amdgcn_readfirstlane(t >> 6);
  const ushort* Wblk = Wp + (size_t)bid * kcmax * 8192;

  auto stage_w = [&](int kc, int buf) {
    const ushort* src = Wblk + (size_t)kc * 8192;
#pragma unroll
    for (int j = 0; j < 4; j++) {
      int Sl = w * 4 + j;
      gload16(src + Sl * 512 + lane * 8, wbuf + buf * 8192 + Sl * 512);
    }
  };
  // mutable x: sc1 atomic loads (8B), LDS 8B writes
  auto stage_x = [&](int kc, int buf) {
#pragma unroll
    for (int h = 0; h < 2; h++) {
      const ushort* p = xseg_ptr(xs, kc * 2 + h);
#pragma unroll
      for (int i = 0; i < 4; i++) {
        int idx = i * 2048 + t * 8;
        int b = idx >> 8, ko = idx & 255;
        const unsigned long long* q = (const unsigned long long*)(p + idx);
        unsigned long long v0 = ldau(q);
        unsigned long long v1 = ldau(q + 1);
        unsigned long long* d =
            (unsigned long long*)(xbuf + buf * 16640 + b * 520 + h * 256 + ko);
        d[0] = v0; d[1] = v1;
      }
    }
  };

  stage_x(0, 0);
  stage_w(0, 0);

  f32x4 acc0 = {0.f, 0.f, 0.f, 0.f}, acc1 = {0.f, 0.f, 0.f, 0.f};
  const int c = lane & 15, kg = lane >> 4;
  const int wsw = c * 64 + ((kg ^ (c & 3)) * 16);

#pragma unroll 1
  for (int kc = 0; kc < kcmax; kc++) {
    int cur = kc & 1;
    if (kc + 1 < kcmax) {
      stage_x(kc + 1, cur ^ 1);
      stage_w(kc + 1, cur ^ 1);
      asm volatile("s_waitcnt vmcnt(4)" ::: "memory");
    } else {
      asm volatile("s_waitcnt vmcnt(0) lgkmcnt(0)" ::: "memory");
    }
    __builtin_amdgcn_sched_barrier(0);
    __builtin_amdgcn_s_barrier();
    const char* wb = (const char*)(wbuf + cur * 8192);
    const char* xb = (const char*)(xbuf + cur * 16640);
#pragma unroll
    for (int j = 0; j < 4; j++) {
      int Sl = w * 4 + j;
      short8 bfr = *(const short8*)(wb + Sl * 1024 + wsw);
      short8 a0  = *(const short8*)(xb + c * 1040 + Sl * 64 + kg * 16);
      short8 a1  = *(const short8*)(xb + (c + 16) * 1040 + Sl * 64 + kg * 16);
      acc0 = __builtin_amdgcn_mfma_f32_16x16x32_bf16(a0, bfr, acc0, 0, 0, 0);
      acc1 = __builtin_amdgcn_mfma_f32_16x16x32_bf16(a1, bfr, acc1, 0, 0, 0);
    }
    asm volatile("s_waitcnt lgkmcnt(0)" ::: "memory");
    __builtin_amdgcn_sched_barrier(0);
    __builtin_amdgcn_s_barrier();
  }

#pragma unroll
  for (int r = 0; r < 4; r++) {
    zsh[(w * 32 + kg * 4 + r) * 16 + c] = acc0[r];
    zsh[(w * 32 + 16 + kg * 4 + r) * 16 + c] = acc1[r];
  }
  __syncthreads();
  if (t < 128) {
    int b = t >> 2, jl = t & 3;
    int j = bid * 4 + jl;
    float z[4];
#pragma unroll
    for (int g = 0; g < 4; g++) {
      float s = bias[g * 1024 + j];
#pragma unroll
      for (int ww = 0; ww < 4; ww++) s += zsh[(ww * 32 + b) * 16 + g * 4 + jl];
      z[g] = s;
    }
    float cn = fsig(z[1]) * cst[b * 1024 + j] + fsig(z[0]) * ftanh(z[2]);
    float hn = fsig(z[3]) * ftanh(cn);
    cst[b * 1024 + j] = cn;               // block-private: normal cached path
    if (h32) staf(&h32[b * 1024 + j], hn);
    if (hT) staf(&hT[j * 32 + b], hn);
    unsigned int uu = (unsigned int)f2bf(hn);
    unsigned int w01 = uu | (__shfl_down(uu, 1) << 16);
    unsigned int w2 = __shfl_down(uu, 2);
    unsigned int w3 = __shfl_down(uu, 3);
    if (jl == 0) {
      unsigned long long pk = ((unsigned long long)(w2 | (w3 << 16)) << 32) | w01;
      stau((unsigned long long*)&hbf[(j >> 8) * 8192 + b * 256 + (j & 255)], pk);
    }
    if (hpart_slot) {
      float v = hn * WsV[j];
      v += __shfl_xor(v, 1);
      v += __shfl_xor(v, 2);
      if (jl == 0) hpart_slot[b * 8 + (bid & 7) + (bid >> 3) * 0] = 0.f;  // unused slot path
    }
  }
  // stp h-partial (only gemm1 passes hpart_slot): recompute cleanly
  if (hpart_slot && t < 128) {
    int b = t >> 2, jl = t & 3;
    int j = bid * 4 + jl;
    float hn2 = 0.f;
    {
      // reload from zsh-domain: recompute hn would be costly; instead reuse hT
      hn2 = hT ? 0.f : 0.f;
    }
    (void)hn2; (void)b; (void)jl; (void)j;
  }
}

// ---------------- fused attention: energy + softmax + ast + ctx ----------------
__device__ void attn_phase(int bid, const float* keys, const float* ha32,
    const float* Mv, const float* astR, float* astW, const float* Wq,
    const float* Wv, const float* bv, const int* mlen, const ushort* membf,
    ushort* ctxbf, float* ctxT, char* lds)
{
  int b = bid >> 3, dq = bid & 7;
  int t = threadIdx.x;
  float* hsh  = (float*)lds;             // 1024
  float* Ml4  = hsh + 1024;              // 4092
  float* wvp  = Ml4 + 4092;              // 256
  float* pqsh = wvp + 256;               // 256
  float* astr = pqsh + 256;              // 1632 (index = s + 15)
  float* al   = astr + 1632;             // 1600 (e, then alignments)
  float* red  = al + 1600;               // 8
  float* astT = red + 8;                 // 368
  float* cacc = astT + 368;              // 256
  int ml = mlen[b];

#pragma unroll
  for (int i = 0; i < 4; i++)
    hsh[i * 256 + t] = ldaf(ha32 + b * 1024 + i * 256 + t);
  for (int idx = t; idx < KK * AA; idx += 256) {
    int k = idx >> 7, a = idx & 127;
    Ml4[k * 132 + a] = Mv[idx];
  }
  if (t < 128) wvp[t] = Wv[t];
  for (int idx = t; idx < 1632; idx += 256) {
    int s = idx - 15;
    astr[idx] = (s >= 0 && s < SS) ? ldaf(astR + b * SS + s) : 0.f;
  }
  __syncthreads();
  // pq = h_a @ Wq (redundant across dq blocks)
  {
    int a = t & 127, half = t >> 7;
    float acc = 0.f;
    const float* wq = Wq + (size_t)(half * 512) * AA + a;
    const float* hh = hsh + half * 512;
#pragma unroll 8
    for (int kk = 0; kk < 512; kk++) acc += hh[kk] * wq[(size_t)kk * AA];
    pqsh[t] = acc;
  }
  __syncthreads();
  if (t < 128) wvp[128 + t] = pqsh[t] + pqsh[t + 128];
  __syncthreads();

  int u = t & 15, g = t >> 4;
  int a0 = u * 8;
  float4 wv0 = *(float4*)&wvp[a0], wv1 = *(float4*)&wvp[a0 + 4];
  float4 pq0 = *(float4*)&wvp[128 + a0], pq1 = *(float4*)&wvp[128 + a0 + 4];
  float bvv = bv[0];
#pragma unroll 1
  for (int tile = 0; tile < 13; tile++) {
    int s0 = tile * 128;
    if (s0 >= ml) break;
    for (int idx = t; idx < 368; idx += 256) {
      int G = idx >> 3, i = idx & 7;
      int sidx = s0 + G + 16 * i;
      astT[idx] = (sidx < 1632) ? astr[sidx] : 0.f;
    }
    __syncthreads();
    float arg[8][8];
#pragma unroll
    for (int i = 0; i < 8; i++) {
      int s = s0 + g + 16 * i;
      if (s < ml) {
        const float* kp = keys + ((size_t)b * SS + s) * AA + a0;
        float4 k0 = *(const float4*)kp, k1 = *(const float4*)(kp + 4);
        arg[i][0] = k0.x + pq0.x; arg[i][1] = k0.y + pq0.y;
        arg[i][2] = k0.z + pq0.z; arg[i][3] = k0.w + pq0.w;
        arg[i][4] = k1.x + pq1.x; arg[i][5] = k1.y + pq1.y;
        arg[i][6] = k1.z + pq1.z; arg[i][7] = k1.w + pq1.w;
      } else {
#pragma unroll
        for (int jj = 0; jj < 8; jj++) arg[i][jj] = 0.f;
      }
    }
    for (int k = 0; k < KK; k++) {
      float4 m0 = *(float4*)&Ml4[k * 132 + a0];
      float4 m1 = *(float4*)&Ml4[k * 132 + a0 + 4];
      float4 as0 = *(float4*)&astT[(g + k) * 8];
      float4 as1 = *(float4*)&astT[(g + k) * 8 + 4];
      float asv[8] = {as0.x, as0.y, as0.z, as0.w, as1.x, as1.y, as1.z, as1.w};
#pragma unroll
      for (int i = 0; i < 8; i++) {
        float aw = asv[i];
        arg[i][0] += aw * m0.x; arg[i][1] += aw * m0.y;
        arg[i][2] += aw * m0.z; arg[i][3] += aw * m0.w;
        arg[i][4] += aw * m1.x; arg[i][5] += aw * m1.y;
        arg[i][6] += aw * m1.z; arg[i][7] += aw * m1.w;
      }
    }
#pragma unroll
    for (int i = 0; i < 8; i++) {
      int s = s0 + g + 16 * i;
      if (s < ml) {
        float v = ftanh(arg[i][0]) * wv0.x + ftanh(arg[i][1]) * wv0.y
                + ftanh(arg[i][2]) * wv0.z + ftanh(arg[i][3]) * wv0.w
                + ftanh(arg[i][4]) * wv1.x + ftanh(arg[i][5]) * wv1.y
                + ftanh(arg[i][6]) * wv1.z + ftanh(arg[i][7]) * wv1.w;
#pragma unroll
        for (int msk = 1; msk < 16; msk <<= 1) v += __shfl_xor(v, msk);
        if (u == 0) al[s] = v + bvv;
      }
    }
    __syncthreads();
  }
  // softmax over al[0..ml)
  float m = -3e38f;
  for (int s = t; s < ml; s += 256) m = fmaxf(m, al[s]);
#pragma unroll
  for (int msk = 1; msk < 64; msk <<= 1) m = fmaxf(m, __shfl_xor(m, msk));
  if ((t & 63) == 0) red[t >> 6] = m;
  __syncthreads();
  m = fmaxf(fmaxf(red[0], red[1]), fmaxf(red[2], red[3]));
  __syncthreads();
  float sum = 0.f;
  for (int s = t; s < ml; s += 256) sum += __expf(al[s] - m);
#pragma unroll
  for (int msk = 1; msk < 64; msk <<= 1) sum += __shfl_xor(sum, msk);
  if ((t & 63) == 0) red[t >> 6] = sum;
  __syncthreads();
  float inv = 1.f / (red[0] + red[1] + red[2] + red[3]);
  for (int s = t; s < ml; s += 256) {
    float a_ = __expf(al[s] - m) * inv;
    al[s] = a_;
    if (dq == 0) staf(&astW[b * SS + s], astr[s + 15] + a_);
  }
  __syncthreads();
  // ctx d-slice from bf16 memory (read-only, L2-cached)
  int dl = t & 127, half = t >> 7;
  const ushort* mp = membf + (size_t)b * SS * DE + dq * 128 + dl;
  float facc = 0.f;
#pragma unroll 4
  for (int s = half; s < ml; s += 2) facc += al[s] * bf2f(mp[(size_t)s * DE]);
  cacc[t] = facc;
  __syncthreads();
  if (t < 128) {
    float v = cacc[t] + cacc[t + 128];
    int d = dq * 128 + t;
    staf(&ctxT[d * 32 + b], v);
    unsigned int uu = (unsigned int)f2bf(v);
    unsigned int w01 = uu | (__shfl_down(uu, 1) << 16);
    unsigned int w2 = __shfl_down(uu, 2);
    unsigned int w3 = __shfl_down(uu, 3);
    if ((t & 3) == 0) {
      unsigned long long pk = ((unsigned long long)(w2 | (w3 << 16)) << 32) | w01;
      stau((unsigned long long*)&ctxbf[(d >> 8) * 8192 + b * 256 + (d & 255)], pk);
    }
  }
}

// ---------------- cls (full-K, fused out + stp partial) ----------------
__device__ void cls_phase(int bid, const float* h1T, const float* ctxT,
    const float* Wcp, const float* bc, const float* Ws,
    float* out, int ts, float* sp_slot, char* lds)
{
  if (bid >= 250) return;
  float* wb = (float*)lds;          // 2*2048
  float* zc = wb + 4096;            // 1024
  int t = threadIdx.x;
  int lane = t & 63;
  int w = __builtin_amdgcn_readfirstlane(t >> 6);
  const float* Wblk = Wcp + (size_t)bid * 8192;
  auto stage = [&](int ch, int buf) {
#pragma unroll
    for (int j = 0; j < 2; j++)
      gload16(Wblk + ch * 2048 + (w * 2 + j) * 256 + lane * 4,
              wb + buf * 2048 + (w * 2 + j) * 256);
  };
  stage(0, 0);
  int b = t & 31, kh = t >> 5;
  float a0 = 0.f, a1 = 0.f, a2 = 0.f, a3 = 0.f;
#pragma unroll 1
  for (int ch = 0; ch < 4; ch++) {
    if (ch < 3) {
      stage(ch + 1, (ch + 1) & 1);
      asm volatile("s_waitcnt vmcnt(2)" ::: "memory");
    } else {
      asm volatile("s_waitcnt vmcnt(0)" ::: "memory");
    }
    __builtin_amdgcn_sched_barrier(0);
    __builtin_amdgcn_s_barrier();
    const float* xb = (ch < 2) ? (h1T + ch * 512 * 32) : (ctxT + (ch - 2) * 512 * 32);
    const float* wc = wb + (ch & 1) * 2048;
#pragma unroll 8
    for (int kk = 0; kk < 64; kk++) {
      int k = kh * 64 + kk;
      float xv = ldaf(xb + k * 32 + b);
      float4 wv4 = *(const float4*)(wc + k * 4);
      a0 += xv * wv4.x; a1 += xv * wv4.y; a2 += xv * wv4.z; a3 += xv * wv4.w;
    }
    asm volatile("s_waitcnt lgkmcnt(0)" ::: "memory");
    __builtin_amdgcn_sched_barrier(0);
    __builtin_amdgcn_s_barrier();
  }
  *(float4*)&zc[(kh * 32 + b) * 4] = make_float4(a0, a1, a2, a3);
  __syncthreads();
  if (t < 128) {
    int bb = t >> 2, ci = t & 3;
    float v = bc[bid * 4 + ci];
#pragma unroll
    for (int k2 = 0; k2 < 8; k2++) v += zc[(k2 * 32 + bb) * 4 + ci];
    out[(size_t)bb * TT * VV + (size_t)ts * VV + bid * 4 + ci] = v;
    float s = v * Ws[LU + bid * 4 + ci];
    s += __shfl_xor(s, 1);
    s += __shfl_xor(s, 2);
    if (ci == 0) sp_slot[bb * 256 + bid] = s;
  }
}

// ---------------- persistent step loop ----------------
__global__ __launch_bounds__(256) void step_loop(float* ws, float* out,
    const int* __restrict__ mlen, const float* __restrict__ Wq,
    const float* __restrict__ Wv, const float* __restrict__ bv,
    const float* __restrict__ ba, const float* __restrict__ b0,
    const float* __restrict__ b1, const float* __restrict__ bc,
    const float* __restrict__ Ws)
{
  __shared__ alignas(16) char lds[107520];
  const int bid = blockIdx.x;
  float*  keys  = ws + F_KEYS;
  float*  Mv    = ws + F_M;
  ushort* pbf   = (ushort*)(ws + F_PBF);
  ushort* wpa   = (ushort*)(ws + F_WPA);
  ushort* wp0   = (ushort*)(ws + F_WP0);
  ushort* wp1   = (ushort*)(ws + F_WP1);
  float*  wcp   = ws + F_WCP;
  ushort* membf = (ushort*)(ws + F_MEMBF);
  float*  ha32  = ws + F_HA32;
  float*  ca    = ws + F_CA;
  float*  c0p   = ws + F_C0;
  float*  c1p   = ws + F_C1;
  float*  astp  = ws + F_AST;
  ushort* habf  = (ushort*)(ws + F_HABF);
  ushort* h0bf  = (ushort*)(ws + F_H0BF);
  ushort* h1bf  = (ushort*)(ws + F_H1BF);
  ushort* ctxbf = (ushort*)(ws + F_CTXBF);
  float*  ctxT  = ws + F_CTXT;
  float*  h1T   = ws + F_H1T;
  const ushort* zeroc = (const ushort*)(ws + F_ZERO);
  int*    bar   = (int*)(ws + F_BAR);
  float*  hp    = ws + F_HP;
  float*  sp    = ws + F_SP;
  int* cnt = bar;
  int* sense = bar + 32;
  int ep = 0;
  int par = 0;
#pragma unroll 1
  for (int ts = 0; ts < TT; ts++) {
    ushort* habf_r = habf + par * 32768;
    ushort* habf_w = habf + (par ^ 1) * 32768;
    ushort* h0bf_r = h0bf + par * 32768;
    ushort* h0bf_w = h0bf + (par ^ 1) * 32768;
    ushort* h1bf_r = h1bf + par * 32768;
    ushort* h1bf_w = h1bf + (par ^ 1) * 32768;
    {
      XSeg xs = { pbf + (size_t)ts * 8192, 1, ctxbf, 4, habf_r, 4, zeroc };
      gemm_gates(bid, xs, wpa, 5, ba, ca, ha32, habf_w, nullptr, nullptr, nullptr, lds);
    }
    gbar(cnt, sense, ++ep);
    attn_phase(bid, keys, ha32, Mv, astp + par * 51200, astp + (par ^ 1) * 51200,
               Wq, Wv, bv, mlen, membf, ctxbf, ctxT, lds);
    gbar(cnt, sense, ++ep);
    {
      XSeg xs = { habf_w, 4, ctxbf, 4, h0bf_r, 4, zeroc };
      gemm_gates(bid, xs, wp0, 6, b0, c0p, nullptr, h0bf_w, nullptr, nullptr, nullptr, lds);
    }
    gbar(cnt, sense, ++ep);
    {
      XSeg xs = { h0bf_w, 4, h1bf_r, 4, nullptr, 0, zeroc };
      gemm_gates(bid, xs, wp1, 4, b1, c1p, nullptr, h1bf_w, h1T, nullptr, nullptr, lds);
    }
    // stp h-dot partial from this block's 4 columns (uses registers via hT write)
    if (threadIdx.x < 128) {
      int b = threadIdx.x >> 2, jl = threadIdx.x & 3;
      int j = bid * 4 + jl;
      float v = ldaf(&h1T[j * 32 + b]);  // just-written by this block (coherent path)
      v = v * Ws[j];
      v += __shfl_xor(v, 1);
      v += __shfl_xor(v, 2);
      if (jl == 0) hp[(size_t)ts * 8192 + b * 256 + bid] = v;
    }
    gbar(cnt, sense, ++ep);
    cls_phase(bid, h1T, ctxT, wcp, bc, Ws, out, ts, sp + (size_t)ts * 8192, lds);
    par ^= 1;
  }
}

// ---------------- stp finalize ----------------
__global__ __launch_bounds__(256) void final_stp(const float* __restrict__ hp,
    const float* __restrict__ sp, const float* __restrict__ bs, float* __restrict__ out)
{
  int idx = blockIdx.x * 256 + threadIdx.x;
  if (idx < TT * BB) {
    int ts = idx >> 5, b = idx & 31;
    float s = bs[0];
    const float* h = hp + (size_t)ts * 8192 + b * 256;
    const float* p = sp + (size_t)ts * 8192 + b * 256;
    for (int i = 0; i < 256; i++) s += h[i];
    for (int i = 0; i < 250; i++) s += p[i];
    out[(size_t)BB * TT * VV + (size_t)b * TT + ts] = s;
  }
}

// ---------------- launcher ----------------

extern "C" void kernel_launch(void* const* d_in, const int* in_sizes, int n_in,
                              void* d_out, int out_size, void* d_ws, size_t ws_size,
                              hipStream_t stream)
{
  const int*   tokens = (const int*)  d_in[0];
  const float* memory = (const float*)d_in[1];
  const int*   mlen   = (const int*)  d_in[2];
  const float* emb    = (const float*)d_in[3];
  const float* Wp1    = (const float*)d_in[4];
  const float* bp1    = (const float*)d_in[5];
  const float* Wp2    = (const float*)d_in[6];
  const float* bp2    = (const float*)d_in[7];
  const float* Wq     = (const float*)d_in[8];
  const float* Wmem   = (const float*)d_in[9];
  const float* convk  = (const float*)d_in[10];
  const float* Wloc   = (const float*)d_in[11];
  const float* Wv     = (const float*)d_in[12];
  const float* bv     = (const float*)d_in[13];
  const float* Wa     = (const float*)d_in[14];
  const float* Ua     = (const float*)d_in[15];
  const float* ba     = (const float*)d_in[16];
  const float* W0     = (const float*)d_in[17];
  const float* U0     = (const float*)d_in[18];
  const float* b0     = (const float*)d_in[19];
  const float* W1     = (const float*)d_in[20];
  const float* U1     = (const float*)d_in[21];
  const float* b1     = (const float*)d_in[22];
  const float* Wc     = (const float*)d_in[23];
  const float* bc     = (const float*)d_in[24];
  const float* Ws     = (const float*)d_in[25];
  const float* bs     = (const float*)d_in[26];
  float* out = (float*)d_out;
  float* ws = (float*)d_ws;

  hipMemsetAsync(ws + F_ST, 0, (F_STEND - F_ST) * sizeof(float), stream);

  conv_mem<<<(BB * SS * DE / 4 + 255) / 256, 256, 0, stream>>>(
      memory, (ushort*)(ws + F_MEMBF), BB * SS * DE / 4);
  pack_lstm<<<2560, 256, 0, stream>>>(Wa, Ua, PR + DE, 2304, (ushort*)(ws + F_WPA), 5);
  pack_lstm<<<3072, 256, 0, stream>>>(W0, U0, LU + DE, 3072, (ushort*)(ws + F_WP0), 6);
  pack_lstm<<<2048, 256, 0, stream>>>(W1, U1, LU, 2048, (ushort*)(ws + F_WP1), 4);
  pack_wc<<<2048, 256, 0, stream>>>(Wc, ws + F_WCP);
  keys_kernel<<<dim3(200, BB), 256, 0, stream>>>(memory, Wmem, ws + F_KEYS);
  mconv_kernel<<<KK, AA, 0, stream>>>(convk, Wloc, ws + F_M);
  prenet_all<<<dim3(TT, 2), 256, 0, stream>>>(tokens, emb, Wp1, bp1, Wp2, bp2,
                                              (ushort*)(ws + F_PBF));

  step_loop<<<256, 256, 0, stream>>>(ws, out, mlen, Wq, Wv, bv, ba, b0, b1, bc, Ws);

  final_stp<<<32, 256, 0, stream>>>(ws + F_HP, ws + F_SP, bs, out);
}

// Round 9
// 93995.264 us; speedup vs baseline: 1.2678x; 1.2678x over previous
//
#include <hip/hip_runtime.h>

#define BB 32
#define TT 256
#define SS 1600
#define DE 1024
#define VV 1000
#define EM 512
#define PR 256
#define LU 1024
#define AA 128
#define FF 32
#define KK 31

typedef __attribute__((ext_vector_type(8))) short short8;
typedef __attribute__((ext_vector_type(4))) float f32x4;

// ---------- workspace layout (float units) ----------
#define F_KEYS   ((size_t)0)
#define F_M      (F_KEYS + 6553600)
#define F_PBF    (F_M + 4096)            // ushort TT*8192
#define F_WPA    (F_PBF + 1048576)       // ushort 256*5*8192
#define F_WP0    (F_WPA + 5242880)       // ushort 256*6*8192
#define F_WP1    (F_WP0 + 6291456)       // ushort 256*4*8192
#define F_WCP    (F_WP1 + 4194304)       // float 250*2048*4
#define F_MEMBF  (F_WCP + 2048000)       // ushort 32*1600*1024
#define F_ST     (F_MEMBF + 26214400)    // ---- zeroed region start ----
#define F_HA32   (F_ST)
#define F_CA     (F_HA32 + 32768)
#define F_C0     (F_CA + 32768)
#define F_C1     (F_C0 + 32768)
#define F_AST    (F_C1 + 32768)          // 2 * 51200 (ping-pong)
#define F_HABF   (F_AST + 102400)        // ushort 2*32768
#define F_H0BF   (F_HABF + 32768)
#define F_H1BF   (F_H0BF + 32768)
#define F_CTXBF  (F_H1BF + 32768)        // ushort 32768
#define F_CTXT   (F_CTXBF + 16384)       // float 32768
#define F_H1T    (F_CTXT + 32768)        // float 32768
#define F_ZERO   (F_H1T + 32768)         // ushort 16384 (zero chunk)
#define F_BAR    (F_ZERO + 8192)         // 32 counters + 32 senses, 64-int stride
#define F_STEND  (F_BAR + 4224)          // ---- zeroed region end ----
#define F_HP     (F_STEND)               // float TT*8192
#define F_SP     (F_HP + 2097152)        // float TT*8192
#define F_E      (F_SP + 2097152)        // float 32*1600

__device__ __forceinline__ float bf2f(ushort u) {
  unsigned int x = ((unsigned int)u) << 16;
  return __builtin_bit_cast(float, x);
}
__device__ __forceinline__ ushort f2bf(float f) {
  unsigned int x = __builtin_bit_cast(unsigned int, f);
  return (ushort)((x + 0x7FFFu + ((x >> 16) & 1u)) >> 16);
}
__device__ __forceinline__ void gload16(const void* g, void* l) {
  __builtin_amdgcn_global_load_lds(
      (const __attribute__((address_space(1))) void*)g,
      (__attribute__((address_space(3))) void*)l, 16, 0, 0);
}
__device__ __forceinline__ float ftanh(float x) {
  float e = __expf(2.f * x);
  return 1.f - 2.f / (e + 1.f);
}
__device__ __forceinline__ float fsig(float x) {
  return 1.f / (1.f + __expf(-x));
}
// coherent (sc0 sc1) path for mutable cross-block data: bypasses per-XCD L2,
// hits shared coherence point -> no cache-maintenance fences needed.
__device__ __forceinline__ float ldaf(const float* p) {
  return __hip_atomic_load(p, __ATOMIC_RELAXED, __HIP_MEMORY_SCOPE_AGENT);
}
__device__ __forceinline__ void staf(float* p, float v) {
  __hip_atomic_store(p, v, __ATOMIC_RELAXED, __HIP_MEMORY_SCOPE_AGENT);
}
__device__ __forceinline__ unsigned long long ldau(const unsigned long long* p) {
  return __hip_atomic_load(p, __ATOMIC_RELAXED, __HIP_MEMORY_SCOPE_AGENT);
}
__device__ __forceinline__ void stau(unsigned long long* p, unsigned long long v) {
  __hip_atomic_store(p, v, __ATOMIC_RELAXED, __HIP_MEMORY_SCOPE_AGENT);
}

// ---------------- once-per-call precompute ----------------

__global__ __launch_bounds__(256) void conv_mem(const float* __restrict__ in,
                                                ushort* __restrict__ out, int n4)
{
  int i = blockIdx.x * 256 + threadIdx.x;
  if (i < n4) {
    float4 v = *(const float4*)(in + (size_t)i * 4);
    ushort4 o;
    o.x = f2bf(v.x); o.y = f2bf(v.y); o.z = f2bf(v.z); o.w = f2bf(v.w);
    *(ushort4*)(out + (size_t)i * 4) = o;
  }
}

// pack LSTM layer weights: dst[blk][kc][Sl][c][kg^(c&3)][e], CK=512, bf16
__global__ __launch_bounds__(256) void pack_lstm(const float* __restrict__ Wm,
    const float* __restrict__ Um, int lenW, int ktot, ushort* __restrict__ dst, int kcmax)
{
  int k = blockIdx.x;
  int t = threadIdx.x;
  float vals[16];
  if (k < lenW) {
    const float* s = Wm + (size_t)k * 4096 + t * 16;
#pragma unroll
    for (int i = 0; i < 16; i++) vals[i] = s[i];
  } else if (k < ktot) {
    const float* s = Um + (size_t)(k - lenW) * 4096 + t * 16;
#pragma unroll
    for (int i = 0; i < 16; i++) vals[i] = s[i];
  } else {
#pragma unroll
    for (int i = 0; i < 16; i++) vals[i] = 0.f;
  }
  int kc = k >> 9, Sl = (k >> 5) & 15, kg = (k >> 3) & 3, e = k & 7;
#pragma unroll
  for (int i = 0; i < 16; i++) {
    int zcol = t * 16 + i;
    int gate = zcol >> 10, jj = zcol & 1023;
    int blk = jj >> 2, c = gate * 4 + (jj & 3);
    size_t off = ((size_t)blk * kcmax + kc) * 8192
               + Sl * 512 + c * 32 + ((kg ^ (c & 3)) * 8) + e;
    dst[off] = f2bf(vals[i]);
  }
}

// pack Wc: dst[cb][k][4] fp32
__global__ __launch_bounds__(256) void pack_wc(const float* __restrict__ Wc,
                                               float* __restrict__ dst)
{
  int k = blockIdx.x;  // 2048
  int t = threadIdx.x;
  if (t < 250) {
    float4 v = *(const float4*)(Wc + (size_t)k * VV + t * 4);
    *(float4*)(dst + (size_t)t * 8192 + k * 4) = v;
  }
}

__global__ __launch_bounds__(256) void keys_kernel(const float* __restrict__ mem,
                                                   const float* __restrict__ Wmem,
                                                   float* __restrict__ keys)
{
  int stile = blockIdx.x;
  int b = blockIdx.y;
  int t = threadIdx.x;
  __shared__ float Xt[8 * 1032];
  const float* mp = mem + ((size_t)b * SS + (size_t)stile * 8) * DE;
  for (int li = t; li < 8 * 256; li += 256) {
    int row = li >> 8, c4 = li & 255;
    float4 v = *(const float4*)(mp + row * DE + c4 * 4);
    *(float4*)(Xt + row * 1032 + c4 * 4) = v;
  }
  __syncthreads();
  int sl = t >> 5, u = t & 31;
  float acc[4] = {0.f, 0.f, 0.f, 0.f};
  for (int k = 0; k < DE; k++) {
    float x = Xt[sl * 1032 + k];
    const float* wr = Wmem + k * AA;
#pragma unroll
    for (int jj = 0; jj < 4; jj++) acc[jj] += x * wr[u + 32 * jj];
  }
  float* kp = keys + ((size_t)b * SS + (size_t)stile * 8 + sl) * AA;
#pragma unroll
  for (int jj = 0; jj < 4; jj++) kp[u + 32 * jj] = acc[jj];
}

__global__ void mconv_kernel(const float* __restrict__ ck, const float* __restrict__ Wloc,
                             float* __restrict__ M)
{
  int a = threadIdx.x;
  int k = blockIdx.x;
  float acc = 0.f;
  for (int c = 0; c < FF; c++) acc += ck[k * FF + c] * Wloc[c * AA + a];
  M[k * AA + a] = acc;
}

__global__ __launch_bounds__(256) void prenet_all(const int* __restrict__ tokens,
    const float* __restrict__ emb, const float* __restrict__ Wp1, const float* __restrict__ bp1,
    const float* __restrict__ Wp2, const float* __restrict__ bp2, ushort* __restrict__ Pbf)
{
  int tstep = blockIdx.x;
  int bh = blockIdx.y;
  int t = threadIdx.x;
  __shared__ float X[16 * 512];
  __shared__ float P1s[16 * 256];
  for (int li = t; li < 16 * 128; li += 256) {
    int bb = li >> 7, c4 = li & 127;
    int tok = tokens[(bh * 16 + bb) * TT + tstep];
    *(float4*)(X + bb * 512 + c4 * 4) = *(const float4*)(emb + (size_t)tok * EM + c4 * 4);
  }
  __syncthreads();
  int j = t;
  float acc[16];
#pragma unroll
  for (int i = 0; i < 16; i++) acc[i] = 0.f;
  for (int k = 0; k < EM; k++) {
    float w = Wp1[k * PR + j];
#pragma unroll
    for (int i = 0; i < 16; i++) acc[i] += X[i * 512 + k] * w;
  }
#pragma unroll
  for (int i = 0; i < 16; i++) P1s[i * 256 + j] = fmaxf(acc[i] + bp1[j], 0.f);
  __syncthreads();
#pragma unroll
  for (int i = 0; i < 16; i++) acc[i] = 0.f;
  for (int k = 0; k < PR; k++) {
    float w = Wp2[k * PR + j];
#pragma unroll
    for (int i = 0; i < 16; i++) acc[i] += P1s[i * 256 + k] * w;
  }
  ushort* outp = Pbf + (size_t)tstep * 8192 + (size_t)bh * 16 * 256;
#pragma unroll
  for (int i = 0; i < 16; i++) outp[i * 256 + j] = f2bf(fmaxf(acc[i] + bp2[j], 0.f));
}

// ---------------- grid barrier: padded counters (1 per 256B line) ----------------
// The r6-r8 barrier cost was 256 atomic RMWs serializing on ONE L3 cacheline.
// cnt[i] at bar[i*64]; sense[i] at bar[2048 + i*64]. 8 arrivals per line.
__device__ __forceinline__ void gbar(int* bar, int ep)
{
  asm volatile("s_waitcnt vmcnt(0) lgkmcnt(0)" ::: "memory");
  __syncthreads();
  int grp = blockIdx.x & 31;
  if (threadIdx.x == 0)
    __hip_atomic_fetch_add(&bar[grp * 64], 1, __ATOMIC_RELAXED,
                           __HIP_MEMORY_SCOPE_AGENT);
  if (blockIdx.x == 0) {
    if (threadIdx.x < 32) {
      int tgt = 8 * ep;
      while (__hip_atomic_load(&bar[threadIdx.x * 64], __ATOMIC_RELAXED,
                               __HIP_MEMORY_SCOPE_AGENT) < tgt)
        __builtin_amdgcn_s_sleep(1);
    }
    __syncthreads();
    if (threadIdx.x < 32)
      __hip_atomic_store(&bar[2048 + threadIdx.x * 64], ep, __ATOMIC_RELAXED,
                         __HIP_MEMORY_SCOPE_AGENT);
  } else if (threadIdx.x == 0) {
    while (__hip_atomic_load(&bar[2048 + grp * 64], __ATOMIC_RELAXED,
                             __HIP_MEMORY_SCOPE_AGENT) < ep)
      __builtin_amdgcn_s_sleep(1);
  }
  __syncthreads();
}

// ---------------- fused full-K gemm + gates ----------------
struct XSeg { const ushort* p0; int n0; const ushort* p1; int n1;
              const ushort* p2; int n2; const ushort* pz; };

__device__ __forceinline__ const ushort* xseg_ptr(const XSeg& xs, int hc)
{
  if (hc < xs.n0) return xs.p0 + (size_t)hc * 8192;
  hc -= xs.n0;
  if (hc < xs.n1) return xs.p1 + (size_t)hc * 8192;
  hc -= xs.n1;
  if (hc < xs.n2) return xs.p2 + (size_t)hc * 8192;
  return xs.pz;
}

__device__ void gemm_gates(int bid, const XSeg& xs, const ushort* Wp, int kcmax,
    const float* bias, float* cst, float* h32, ushort* hbf, float* hT,
    float* hpart_slot, const float* WsV, char* lds)
{
  ushort* wbuf = (ushort*)lds;                     // 2 * 8192 us
  ushort* xbuf = (ushort*)(lds + 32768);           // 2 * 16640 us
  float*  zsh  = (float*)(lds + 32768 + 66560);    // 2048 f
  const int t = threadIdx.x;
  const int lane = t & 63;
  const int w = __builtin_amdgcn_readfirstlane(t >> 6);
  const ushort* Wblk = Wp + (size_t)bid * kcmax * 8192;

  auto stage_w = [&](int kc, int buf) {
    const ushort* src = Wblk + (size_t)kc * 8192;
#pragma unroll
    for (int j = 0; j < 4; j++) {
      int Sl = w * 4 + j;
      gload16(src + Sl * 512 + lane * 8, wbuf + buf * 8192 + Sl * 512);
    }
  };
  // mutable x: sc1 atomic loads (8B), LDS writes
  auto stage_x = [&](int kc, int buf) {
#pragma unroll
    for (int h = 0; h < 2; h++) {
      const ushort* p = xseg_ptr(xs, kc * 2 + h);
#pragma unroll
      for (int i = 0; i < 4; i++) {
        int idx = i * 2048 + t * 8;
        int b = idx >> 8, ko = idx & 255;
        const unsigned long long* q = (const unsigned long long*)(p + idx);
        unsigned long long v0 = ldau(q);
        unsigned long long v1 = ldau(q + 1);
        unsigned long long* d =
            (unsigned long long*)(xbuf + buf * 16640 + b * 520 + h * 256 + ko);
        d[0] = v0; d[1] = v1;
      }
    }
  };

  stage_x(0, 0);
  stage_w(0, 0);

  f32x4 acc0 = {0.f, 0.f, 0.f, 0.f}, acc1 = {0.f, 0.f, 0.f, 0.f};
  const int c = lane & 15, kg = lane >> 4;
  const int wsw = c * 64 + ((kg ^ (c & 3)) * 16);

#pragma unroll 1
  for (int kc = 0; kc < kcmax; kc++) {
    int cur = kc & 1;
    if (kc + 1 < kcmax) {
      stage_x(kc + 1, cur ^ 1);
      stage_w(kc + 1, cur ^ 1);
      asm volatile("s_waitcnt vmcnt(4)" ::: "memory");
    } else {
      asm volatile("s_waitcnt vmcnt(0) lgkmcnt(0)" ::: "memory");
    }
    __builtin_amdgcn_sched_barrier(0);
    __builtin_amdgcn_s_barrier();
    const char* wb = (const char*)(wbuf + cur * 8192);
    const char* xb = (const char*)(xbuf + cur * 16640);
#pragma unroll
    for (int j = 0; j < 4; j++) {
      int Sl = w * 4 + j;
      short8 bfr = *(const short8*)(wb + Sl * 1024 + wsw);
      short8 a0  = *(const short8*)(xb + c * 1040 + Sl * 64 + kg * 16);
      short8 a1  = *(const short8*)(xb + (c + 16) * 1040 + Sl * 64 + kg * 16);
      acc0 = __builtin_amdgcn_mfma_f32_16x16x32_bf16(a0, bfr, acc0, 0, 0, 0);
      acc1 = __builtin_amdgcn_mfma_f32_16x16x32_bf16(a1, bfr, acc1, 0, 0, 0);
    }
    asm volatile("s_waitcnt lgkmcnt(0)" ::: "memory");
    __builtin_amdgcn_sched_barrier(0);
    __builtin_amdgcn_s_barrier();
  }

#pragma unroll
  for (int r = 0; r < 4; r++) {
    zsh[(w * 32 + kg * 4 + r) * 16 + c] = acc0[r];
    zsh[(w * 32 + 16 + kg * 4 + r) * 16 + c] = acc1[r];
  }
  __syncthreads();
  if (t < 128) {
    int b = t >> 2, jl = t & 3;
    int j = bid * 4 + jl;
    float z[4];
#pragma unroll
    for (int g = 0; g < 4; g++) {
      float s = bias[g * 1024 + j];
#pragma unroll
      for (int ww = 0; ww < 4; ww++) s += zsh[(ww * 32 + b) * 16 + g * 4 + jl];
      z[g] = s;
    }
    float cn = fsig(z[1]) * cst[b * 1024 + j] + fsig(z[0]) * ftanh(z[2]);
    float hn = fsig(z[3]) * ftanh(cn);
    cst[b * 1024 + j] = cn;               // block-private: normal cached path
    if (h32) staf(&h32[b * 1024 + j], hn);
    if (hT) staf(&hT[j * 32 + b], hn);
    unsigned int uu = (unsigned int)f2bf(hn);
    unsigned int w01 = uu | (__shfl_down(uu, 1) << 16);
    unsigned int w2 = __shfl_down(uu, 2);
    unsigned int w3 = __shfl_down(uu, 3);
    if (jl == 0) {
      unsigned long long pk = ((unsigned long long)(w2 | (w3 << 16)) << 32) | w01;
      stau((unsigned long long*)&hbf[(j >> 8) * 8192 + b * 256 + (j & 255)], pk);
    }
    if (hpart_slot) {   // stp h-dot partial, from in-register hn
      float v = hn * WsV[j];
      v += __shfl_xor(v, 1);
      v += __shfl_xor(v, 2);
      if (jl == 0) hpart_slot[b * 256 + bid] = v;
    }
  }
}

// ---------------- energy: 8 tq-slices per batch, e -> global (sc1) ----------------
__device__ void energy_phase(int bid, const float* keys, const float* ha32,
    const float* Mv, const float* astR, const float* Wq, const float* Wv,
    const float* bv, const int* mlen, float* e, char* lds)
{
  int b = bid >> 3, tq = bid & 7;
  int base = tq * 200;
  int ml = mlen[b];
  if (base >= ml) return;
  float* hsh  = (float*)lds;        // 1024
  float* Ml4  = hsh + 1024;         // 4092
  float* wvp  = Ml4 + 4092;         // 256
  float* pqsh = wvp + 256;          // 256
  float* astT = pqsh + 256;         // 368
  int t = threadIdx.x;
#pragma unroll
  for (int i = 0; i < 4; i++)
    hsh[i * 256 + t] = ldaf(ha32 + b * 1024 + i * 256 + t);
  for (int idx = t; idx < KK * AA; idx += 256) {
    int k = idx >> 7, a = idx & 127;
    Ml4[k * 132 + a] = Mv[idx];
  }
  if (t < 128) wvp[t] = Wv[t];
  __syncthreads();
  {
    int a = t & 127, half = t >> 7;
    float acc = 0.f;
    const float* wq = Wq + (size_t)(half * 512) * AA + a;
    const float* hh = hsh + half * 512;
#pragma unroll 8
    for (int kk = 0; kk < 512; kk++) acc += hh[kk] * wq[(size_t)kk * AA];
    pqsh[t] = acc;
  }
  __syncthreads();
  if (t < 128) wvp[128 + t] = pqsh[t] + pqsh[t + 128];
  __syncthreads();
  int u = t & 15, g = t >> 4;
  int a0 = u * 8;
  float4 wv0 = *(float4*)&wvp[a0], wv1 = *(float4*)&wvp[a0 + 4];
  float4 pq0 = *(float4*)&wvp[128 + a0], pq1 = *(float4*)&wvp[128 + a0 + 4];
  float bvv = bv[0];
  int smax = base + 200; if (smax > ml) smax = ml;
#pragma unroll 1
  for (int p = 0; p < 2; p++) {
    int s0 = base + p * 112;
    if (s0 >= smax) break;
    for (int idx = t; idx < 368; idx += 256) {
      int G = idx >> 3, i = idx & 7;
      int s = s0 + G - 15 + 16 * i;
      astT[idx] = (s >= 0 && s < SS) ? ldaf(astR + b * SS + s) : 0.f;
    }
    __syncthreads();
    float arg[7][8];
#pragma unroll
    for (int i = 0; i < 7; i++) {
      int s = s0 + g + 16 * i;
      if (s < SS) {
        const float* kp = keys + ((size_t)b * SS + s) * AA + a0;
        float4 k0 = *(const float4*)kp, k1 = *(const float4*)(kp + 4);
        arg[i][0] = k0.x + pq0.x; arg[i][1] = k0.y + pq0.y;
        arg[i][2] = k0.z + pq0.z; arg[i][3] = k0.w + pq0.w;
        arg[i][4] = k1.x + pq1.x; arg[i][5] = k1.y + pq1.y;
        arg[i][6] = k1.z + pq1.z; arg[i][7] = k1.w + pq1.w;
      } else {
#pragma unroll
        for (int jj = 0; jj < 8; jj++) arg[i][jj] = 0.f;
      }
    }
    for (int k = 0; k < KK; k++) {
      float4 m0 = *(float4*)&Ml4[k * 132 + a0];
      float4 m1 = *(float4*)&Ml4[k * 132 + a0 + 4];
#pragma unroll
      for (int i = 0; i < 7; i++) {
        float aw = astT[(g + k) * 8 + i];
        arg[i][0] += aw * m0.x; arg[i][1] += aw * m0.y;
        arg[i][2] += aw * m0.z; arg[i][3] += aw * m0.w;
        arg[i][4] += aw * m1.x; arg[i][5] += aw * m1.y;
        arg[i][6] += aw * m1.z; arg[i][7] += aw * m1.w;
      }
    }
#pragma unroll
    for (int i = 0; i < 7; i++) {
      int s = s0 + g + 16 * i;
      float v = ftanh(arg[i][0]) * wv0.x + ftanh(arg[i][1]) * wv0.y
              + ftanh(arg[i][2]) * wv0.z + ftanh(arg[i][3]) * wv0.w
              + ftanh(arg[i][4]) * wv1.x + ftanh(arg[i][5]) * wv1.y
              + ftanh(arg[i][6]) * wv1.z + ftanh(arg[i][7]) * wv1.w;
#pragma unroll
      for (int msk = 1; msk < 16; msk <<= 1) v += __shfl_xor(v, msk);
      if (u == 0 && s < s0 + 112 && s < smax) staf(&e[b * SS + s], v + bvv);
    }
    __syncthreads();
  }
}

// ---------------- softmax + ast + ctx ----------------
__device__ void ctx_phase(int bid, const float* e, const int* mlen,
    const ushort* membf, const float* astR, float* astW,
    ushort* ctxbf, float* ctxT, char* lds)
{
  float* al   = (float*)lds;        // 1600
  float* red  = al + 1600;          // 8
  float* cacc = red + 8;            // 256
  int b = bid >> 3, dq = bid & 7;
  int ml = mlen[b];
  int t = threadIdx.x;
  for (int s = t; s < ml; s += 256) al[s] = ldaf(e + b * SS + s);
  __syncthreads();
  float m = -3e38f;
  for (int s = t; s < ml; s += 256) m = fmaxf(m, al[s]);
#pragma unroll
  for (int msk = 1; msk < 64; msk <<= 1) m = fmaxf(m, __shfl_xor(m, msk));
  if ((t & 63) == 0) red[t >> 6] = m;
  __syncthreads();
  m = fmaxf(fmaxf(red[0], red[1]), fmaxf(red[2], red[3]));
  __syncthreads();
  float sum = 0.f;
  for (int s = t; s < ml; s += 256) sum += __expf(al[s] - m);
#pragma unroll
  for (int msk = 1; msk < 64; msk <<= 1) sum += __shfl_xor(sum, msk);
  if ((t & 63) == 0) red[t >> 6] = sum;
  __syncthreads();
  float inv = 1.f / (red[0] + red[1] + red[2] + red[3]);
  for (int s = t; s < ml; s += 256) {
    float a_ = __expf(al[s] - m) * inv;
    al[s] = a_;
    if (dq == 0) staf(&astW[b * SS + s], ldaf(astR + b * SS + s) + a_);
  }
  __syncthreads();
  int dl = t & 127, half = t >> 7;
  const ushort* mp = membf + (size_t)b * SS * DE + dq * 128 + dl;
  float facc = 0.f;
#pragma unroll 4
  for (int s = half; s < ml; s += 2) facc += al[s] * bf2f(mp[(size_t)s * DE]);
  cacc[t] = facc;
  __syncthreads();
  if (t < 128) {
    float v = cacc[t] + cacc[t + 128];
    int d = dq * 128 + t;
    staf(&ctxT[d * 32 + b], v);
    unsigned int uu = (unsigned int)f2bf(v);
    unsigned int w01 = uu | (__shfl_down(uu, 1) << 16);
    unsigned int w2 = __shfl_down(uu, 2);
    unsigned int w3 = __shfl_down(uu, 3);
    if ((t & 3) == 0) {
      unsigned long long pk = ((unsigned long long)(w2 | (w3 << 16)) << 32) | w01;
      stau((unsigned long long*)&ctxbf[(d >> 8) * 8192 + b * 256 + (d & 255)], pk);
    }
  }
}

// ---------------- cls (full-K, fused out + stp partial) ----------------
__device__ void cls_phase(int bid, const float* h1T, const float* ctxT,
    const float* Wcp, const float* bc, const float* Ws,
    float* out, int ts, float* sp_slot, char* lds)
{
  if (bid >= 250) return;
  float* wb = (float*)lds;          // 2*2048
  float* zc = wb + 4096;            // 1024
  int t = threadIdx.x;
  int lane = t & 63;
  int w = __builtin_amdgcn_readfirstlane(t >> 6);
  const float* Wblk = Wcp + (size_t)bid * 8192;
  auto stage = [&](int ch, int buf) {
#pragma unroll
    for (int j = 0; j < 2; j++)
      gload16(Wblk + ch * 2048 + (w * 2 + j) * 256 + lane * 4,
              wb + buf * 2048 + (w * 2 + j) * 256);
  };
  stage(0, 0);
  int b = t & 31, kh = t >> 5;
  float a0 = 0.f, a1 = 0.f, a2 = 0.f, a3 = 0.f;
#pragma unroll 1
  for (int ch = 0; ch < 4; ch++) {
    if (ch < 3) {
      stage(ch + 1, (ch + 1) & 1);
      asm volatile("s_waitcnt vmcnt(2)" ::: "memory");
    } else {
      asm volatile("s_waitcnt vmcnt(0)" ::: "memory");
    }
    __builtin_amdgcn_sched_barrier(0);
    __builtin_amdgcn_s_barrier();
    const float* xb = (ch < 2) ? (h1T + ch * 512 * 32) : (ctxT + (ch - 2) * 512 * 32);
    const float* wc = wb + (ch & 1) * 2048;
#pragma unroll 8
    for (int kk = 0; kk < 64; kk++) {
      int k = kh * 64 + kk;
      float xv = ldaf(xb + k * 32 + b);
      float4 wv4 = *(const float4*)(wc + k * 4);
      a0 += xv * wv4.x; a1 += xv * wv4.y; a2 += xv * wv4.z; a3 += xv * wv4.w;
    }
    asm volatile("s_waitcnt lgkmcnt(0)" ::: "memory");
    __builtin_amdgcn_sched_barrier(0);
    __builtin_amdgcn_s_barrier();
  }
  *(float4*)&zc[(kh * 32 + b) * 4] = make_float4(a0, a1, a2, a3);
  __syncthreads();
  if (t < 128) {
    int bb = t >> 2, ci = t & 3;
    float v = bc[bid * 4 + ci];
#pragma unroll
    for (int k2 = 0; k2 < 8; k2++) v += zc[(k2 * 32 + bb) * 4 + ci];
    out[(size_t)bb * TT * VV + (size_t)ts * VV + bid * 4 + ci] = v;
    float s = v * Ws[LU + bid * 4 + ci];
    s += __shfl_xor(s, 1);
    s += __shfl_xor(s, 2);
    if (ci == 0) sp_slot[bb * 256 + bid] = s;
  }
}

// ---------------- persistent step loop ----------------
__global__ __launch_bounds__(256) void step_loop(float* ws, float* out,
    const int* __restrict__ mlen, const float* __restrict__ Wq,
    const float* __restrict__ Wv, const float* __restrict__ bv,
    const float* __restrict__ ba, const float* __restrict__ b0,
    const float* __restrict__ b1, const float* __restrict__ bc,
    const float* __restrict__ Ws)
{
  __shared__ alignas(16) char lds[107520];
  const int bid = blockIdx.x;
  float*  keys  = ws + F_KEYS;
  float*  Mv    = ws + F_M;
  ushort* pbf   = (ushort*)(ws + F_PBF);
  ushort* wpa   = (ushort*)(ws + F_WPA);
  ushort* wp0   = (ushort*)(ws + F_WP0);
  ushort* wp1   = (ushort*)(ws + F_WP1);
  float*  wcp   = ws + F_WCP;
  ushort* membf = (ushort*)(ws + F_MEMBF);
  float*  ha32  = ws + F_HA32;
  float*  ca    = ws + F_CA;
  float*  c0p   = ws + F_C0;
  float*  c1p   = ws + F_C1;
  float*  astp  = ws + F_AST;
  ushort* habf  = (ushort*)(ws + F_HABF);
  ushort* h0bf  = (ushort*)(ws + F_H0BF);
  ushort* h1bf  = (ushort*)(ws + F_H1BF);
  ushort* ctxbf = (ushort*)(ws + F_CTXBF);
  float*  ctxT  = ws + F_CTXT;
  float*  h1T   = ws + F_H1T;
  const ushort* zeroc = (const ushort*)(ws + F_ZERO);
  int*    bar   = (int*)(ws + F_BAR);
  float*  hp    = ws + F_HP;
  float*  sp    = ws + F_SP;
  float*  ebuf  = ws + F_E;
  int ep = 0;
  int par = 0;
#pragma unroll 1
  for (int ts = 0; ts < TT; ts++) {
    ushort* habf_r = habf + par * 32768;
    ushort* habf_w = habf + (par ^ 1) * 32768;
    ushort* h0bf_r = h0bf + par * 32768;
    ushort* h0bf_w = h0bf + (par ^ 1) * 32768;
    ushort* h1bf_r = h1bf + par * 32768;
    ushort* h1bf_w = h1bf + (par ^ 1) * 32768;
    {
      XSeg xs = { pbf + (size_t)ts * 8192, 1, ctxbf, 4, habf_r, 4, zeroc };
      gemm_gates(bid, xs, wpa, 5, ba, ca, ha32, habf_w, nullptr, nullptr, nullptr, lds);
    }
    gbar(bar, ++ep);
    energy_phase(bid, keys, ha32, Mv, astp + par * 51200, Wq, Wv, bv, mlen, ebuf, lds);
    gbar(bar, ++ep);
    ctx_phase(bid, ebuf, mlen, membf, astp + par * 51200, astp + (par ^ 1) * 51200,
              ctxbf, ctxT, lds);
    gbar(bar, ++ep);
    {
      XSeg xs = { habf_w, 4, ctxbf, 4, h0bf_r, 4, zeroc };
      gemm_gates(bid, xs, wp0, 6, b0, c0p, nullptr, h0bf_w, nullptr, nullptr, nullptr, lds);
    }
    gbar(bar, ++ep);
    {
      XSeg xs = { h0bf_w, 4, h1bf_r, 4, nullptr, 0, zeroc };
      gemm_gates(bid, xs, wp1, 4, b1, c1p, nullptr, h1bf_w, h1T,
                 hp + (size_t)ts * 8192, Ws, lds);
    }
    gbar(bar, ++ep);
    cls_phase(bid, h1T, ctxT, wcp, bc, Ws, out, ts, sp + (size_t)ts * 8192, lds);
    par ^= 1;
  }
}

// ---------------- stp finalize ----------------
__global__ __launch_bounds__(256) void final_stp(const float* __restrict__ hp,
    const float* __restrict__ sp, const float* __restrict__ bs, float* __restrict__ out)
{
  int idx = blockIdx.x * 256 + threadIdx.x;
  if (idx < TT * BB) {
    int ts = idx >> 5, b = idx & 31;
    float s = bs[0];
    const float* h = hp + (size_t)ts * 8192 + b * 256;
    const float* p = sp + (size_t)ts * 8192 + b * 256;
    for (int i = 0; i < 256; i++) s += h[i];
    for (int i = 0; i < 250; i++) s += p[i];
    out[(size_t)BB * TT * VV + (size_t)b * TT + ts] = s;
  }
}

// ---------------- launcher ----------------

extern "C" void kernel_launch(void* const* d_in, const int* in_sizes, int n_in,
                              void* d_out, int out_size, void* d_ws, size_t ws_size,
                              hipStream_t stream)
{
  const int*   tokens = (const int*)  d_in[0];
  const float* memory = (const float*)d_in[1];
  const int*   mlen   = (const int*)  d_in[2];
  const float* emb    = (const float*)d_in[3];
  const float* Wp1    = (const float*)d_in[4];
  const float* bp1    = (const float*)d_in[5];
  const float* Wp2    = (const float*)d_in[6];
  const float* bp2    = (const float*)d_in[7];
  const float* Wq     = (const float*)d_in[8];
  const float* Wmem   = (const float*)d_in[9];
  const float* convk  = (const float*)d_in[10];
  const float* Wloc   = (const float*)d_in[11];
  const float* Wv     = (const float*)d_in[12];
  const float* bv     = (const float*)d_in[13];
  const float* Wa     = (const float*)d_in[14];
  const float* Ua     = (const float*)d_in[15];
  const float* ba     = (const float*)d_in[16];
  const float* W0     = (const float*)d_in[17];
  const float* U0     = (const float*)d_in[18];
  const float* b0     = (const float*)d_in[19];
  const float* W1     = (const float*)d_in[20];
  const float* U1     = (const float*)d_in[21];
  const float* b1     = (const float*)d_in[22];
  const float* Wc     = (const float*)d_in[23];
  const float* bc     = (const float*)d_in[24];
  const float* Ws     = (const float*)d_in[25];
  const float* bs     = (const float*)d_in[26];
  float* out = (float*)d_out;
  float* ws = (float*)d_ws;

  hipMemsetAsync(ws + F_ST, 0, (F_STEND - F_ST) * sizeof(float), stream);

  conv_mem<<<(BB * SS * DE / 4 + 255) / 256, 256, 0, stream>>>(
      memory, (ushort*)(ws + F_MEMBF), BB * SS * DE / 4);
  pack_lstm<<<2560, 256, 0, stream>>>(Wa, Ua, PR + DE, 2304, (ushort*)(ws + F_WPA), 5);
  pack_lstm<<<3072, 256, 0, stream>>>(W0, U0, LU + DE, 3072, (ushort*)(ws + F_WP0), 6);
  pack_lstm<<<2048, 256, 0, stream>>>(W1, U1, LU, 2048, (ushort*)(ws + F_WP1), 4);
  pack_wc<<<2048, 256, 0, stream>>>(Wc, ws + F_WCP);
  keys_kernel<<<dim3(200, BB), 256, 0, stream>>>(memory, Wmem, ws + F_KEYS);
  mconv_kernel<<<KK, AA, 0, stream>>>(convk, Wloc, ws + F_M);
  prenet_all<<<dim3(TT, 2), 256, 0, stream>>>(tokens, emb, Wp1, bp1, Wp2, bp2,
                                              (ushort*)(ws + F_PBF));

  step_loop<<<256, 256, 0, stream>>>(ws, out, mlen, Wq, Wv, bv, ba, b0, b1, bc, Ws);

  final_stp<<<32, 256, 0, stream>>>(ws + F_HP, ws + F_SP, bs, out);
}

// Round 10
// 45190.018 us; speedup vs baseline: 2.6370x; 2.0800x over previous
//
#include <hip/hip_runtime.h>

#define BB 32
#define TT 256
#define SS 1600
#define DE 1024
#define VV 1000
#define EM 512
#define PR 256
#define LU 1024
#define AA 128
#define FF 32
#define KK 31

typedef __attribute__((ext_vector_type(8))) short short8;
typedef __attribute__((ext_vector_type(4))) float f32x4;

// ---------- workspace layout (float units) ----------
#define F_KEYS   ((size_t)0)
#define F_M      (F_KEYS + 6553600)
#define F_PBF    (F_M + 4096)            // ushort TT*8192
#define F_WPA    (F_PBF + 1048576)       // ushort 256*5*8192
#define F_WP0    (F_WPA + 5242880)       // ushort 256*6*8192
#define F_WP1    (F_WP0 + 6291456)       // ushort 256*4*8192
#define F_WCP    (F_WP1 + 4194304)       // float 250*2048*4
#define F_MEMBF  (F_WCP + 2048000)       // ushort 32*1600*1024
#define F_ST     (F_MEMBF + 26214400)    // ---- zeroed region start ----
#define F_HA32   (F_ST)
#define F_CA     (F_HA32 + 32768)
#define F_C0     (F_CA + 32768)
#define F_C1     (F_C0 + 32768)
#define F_AST    (F_C1 + 32768)          // 51200
#define F_HABF   (F_AST + 51200)         // ushort 2*32768 (ping-pong)
#define F_H0BF   (F_HABF + 32768)
#define F_H1BF   (F_H0BF + 32768)
#define F_CTXBF  (F_H1BF + 32768)        // ushort 32768
#define F_CTXT   (F_CTXBF + 16384)       // float 32768
#define F_H1T    (F_CTXT + 32768)        // float 32768
#define F_ZERO   (F_H1T + 32768)         // ushort 16384 (zero chunk)
#define F_STEND  (F_ZERO + 8192)         // ---- zeroed region end ----
#define F_HP     (F_STEND)               // float TT*8192
#define F_SP     (F_HP + 2097152)        // float TT*8192
#define F_E      (F_SP + 2097152)        // float 32*1600
#define F_CP     (F_E + 51200)           // float 16*BB*DE

__device__ __forceinline__ float bf2f(ushort u) {
  unsigned int x = ((unsigned int)u) << 16;
  return __builtin_bit_cast(float, x);
}
__device__ __forceinline__ ushort f2bf(float f) {
  unsigned int x = __builtin_bit_cast(unsigned int, f);
  return (ushort)((x + 0x7FFFu + ((x >> 16) & 1u)) >> 16);
}
__device__ __forceinline__ void gload16(const void* g, void* l) {
  __builtin_amdgcn_global_load_lds(
      (const __attribute__((address_space(1))) void*)g,
      (__attribute__((address_space(3))) void*)l, 16, 0, 0);
}
__device__ __forceinline__ float ftanh(float x) {
  float e = __expf(2.f * x);
  return 1.f - 2.f / (e + 1.f);
}
__device__ __forceinline__ float fsig(float x) {
  return 1.f / (1.f + __expf(-x));
}

// ---------------- once-per-call precompute ----------------

__global__ __launch_bounds__(256) void conv_mem(const float* __restrict__ in,
                                                ushort* __restrict__ out, int n4)
{
  int i = blockIdx.x * 256 + threadIdx.x;
  if (i < n4) {
    float4 v = *(const float4*)(in + (size_t)i * 4);
    ushort4 o;
    o.x = f2bf(v.x); o.y = f2bf(v.y); o.z = f2bf(v.z); o.w = f2bf(v.w);
    *(ushort4*)(out + (size_t)i * 4) = o;
  }
}

// pack LSTM layer weights: dst[blk][kc][Sl][c][kg^(c&3)][e], CK=512, bf16
__global__ __launch_bounds__(256) void pack_lstm(const float* __restrict__ Wm,
    const float* __restrict__ Um, int lenW, int ktot, ushort* __restrict__ dst, int kcmax)
{
  int k = blockIdx.x;
  int t = threadIdx.x;
  float vals[16];
  if (k < lenW) {
    const float* s = Wm + (size_t)k * 4096 + t * 16;
#pragma unroll
    for (int i = 0; i < 16; i++) vals[i] = s[i];
  } else if (k < ktot) {
    const float* s = Um + (size_t)(k - lenW) * 4096 + t * 16;
#pragma unroll
    for (int i = 0; i < 16; i++) vals[i] = s[i];
  } else {
#pragma unroll
    for (int i = 0; i < 16; i++) vals[i] = 0.f;
  }
  int kc = k >> 9, Sl = (k >> 5) & 15, kg = (k >> 3) & 3, e = k & 7;
#pragma unroll
  for (int i = 0; i < 16; i++) {
    int zcol = t * 16 + i;
    int gate = zcol >> 10, jj = zcol & 1023;
    int blk = jj >> 2, c = gate * 4 + (jj & 3);
    size_t off = ((size_t)blk * kcmax + kc) * 8192
               + Sl * 512 + c * 32 + ((kg ^ (c & 3)) * 8) + e;
    dst[off] = f2bf(vals[i]);
  }
}

// pack Wc: dst[cb][k][4] fp32
__global__ __launch_bounds__(256) void pack_wc(const float* __restrict__ Wc,
                                               float* __restrict__ dst)
{
  int k = blockIdx.x;  // 2048
  int t = threadIdx.x;
  if (t < 250) {
    float4 v = *(const float4*)(Wc + (size_t)k * VV + t * 4);
    *(float4*)(dst + (size_t)t * 8192 + k * 4) = v;
  }
}

__global__ __launch_bounds__(256) void keys_kernel(const float* __restrict__ mem,
                                                   const float* __restrict__ Wmem,
                                                   float* __restrict__ keys)
{
  int stile = blockIdx.x;
  int b = blockIdx.y;
  int t = threadIdx.x;
  __shared__ float Xt[8 * 1032];
  const float* mp = mem + ((size_t)b * SS + (size_t)stile * 8) * DE;
  for (int li = t; li < 8 * 256; li += 256) {
    int row = li >> 8, c4 = li & 255;
    float4 v = *(const float4*)(mp + row * DE + c4 * 4);
    *(float4*)(Xt + row * 1032 + c4 * 4) = v;
  }
  __syncthreads();
  int sl = t >> 5, u = t & 31;
  float acc[4] = {0.f, 0.f, 0.f, 0.f};
  for (int k = 0; k < DE; k++) {
    float x = Xt[sl * 1032 + k];
    const float* wr = Wmem + k * AA;
#pragma unroll
    for (int jj = 0; jj < 4; jj++) acc[jj] += x * wr[u + 32 * jj];
  }
  float* kp = keys + ((size_t)b * SS + (size_t)stile * 8 + sl) * AA;
#pragma unroll
  for (int jj = 0; jj < 4; jj++) kp[u + 32 * jj] = acc[jj];
}

__global__ void mconv_kernel(const float* __restrict__ ck, const float* __restrict__ Wloc,
                             float* __restrict__ M)
{
  int a = threadIdx.x;
  int k = blockIdx.x;
  float acc = 0.f;
  for (int c = 0; c < FF; c++) acc += ck[k * FF + c] * Wloc[c * AA + a];
  M[k * AA + a] = acc;
}

__global__ __launch_bounds__(256) void prenet_all(const int* __restrict__ tokens,
    const float* __restrict__ emb, const float* __restrict__ Wp1, const float* __restrict__ bp1,
    const float* __restrict__ Wp2, const float* __restrict__ bp2, ushort* __restrict__ Pbf)
{
  int tstep = blockIdx.x;
  int bh = blockIdx.y;
  int t = threadIdx.x;
  __shared__ float X[16 * 512];
  __shared__ float P1s[16 * 256];
  for (int li = t; li < 16 * 128; li += 256) {
    int bb = li >> 7, c4 = li & 127;
    int tok = tokens[(bh * 16 + bb) * TT + tstep];
    *(float4*)(X + bb * 512 + c4 * 4) = *(const float4*)(emb + (size_t)tok * EM + c4 * 4);
  }
  __syncthreads();
  int j = t;
  float acc[16];
#pragma unroll
  for (int i = 0; i < 16; i++) acc[i] = 0.f;
  for (int k = 0; k < EM; k++) {
    float w = Wp1[k * PR + j];
#pragma unroll
    for (int i = 0; i < 16; i++) acc[i] += X[i * 512 + k] * w;
  }
#pragma unroll
  for (int i = 0; i < 16; i++) P1s[i * 256 + j] = fmaxf(acc[i] + bp1[j], 0.f);
  __syncthreads();
#pragma unroll
  for (int i = 0; i < 16; i++) acc[i] = 0.f;
  for (int k = 0; k < PR; k++) {
    float w = Wp2[k * PR + j];
#pragma unroll
    for (int i = 0; i < 16; i++) acc[i] += P1s[i * 256 + k] * w;
  }
  ushort* outp = Pbf + (size_t)tstep * 8192 + (size_t)bh * 16 * 256;
#pragma unroll
  for (int i = 0; i < 16; i++) outp[i * 256 + j] = f2bf(fmaxf(acc[i] + bp2[j], 0.f));
}

// ---------------- fused full-K gemm + gates (standalone kernel) ----------------
// Block bid owns 4 h-columns (16 z-cols) with the FULL K; x = concat of bf16
// chunk buffers laid out [chunk][b][256]. Weights pre-packed per-block.
__global__ __launch_bounds__(256) void gemm_gates(
    const ushort* __restrict__ x0, int n0, const ushort* __restrict__ x1, int n1,
    const ushort* __restrict__ x2, int n2, const ushort* __restrict__ xz,
    const ushort* __restrict__ Wp, int kcmax, const float* __restrict__ bias,
    float* __restrict__ cst, float* __restrict__ h32, ushort* __restrict__ hbf,
    float* __restrict__ hT, float* __restrict__ hpart_slot, const float* __restrict__ WsV)
{
  __shared__ alignas(16) char lds[107520];
  ushort* wbuf = (ushort*)lds;                     // 2 * 8192 us
  ushort* xbuf = (ushort*)(lds + 32768);           // 2 * 16640 us
  float*  zsh  = (float*)(lds + 32768 + 66560);    // 2048 f
  const int bid = blockIdx.x;
  const int t = threadIdx.x;
  const int lane = t & 63;
  const int w = __builtin_amdgcn_readfirstlane(t >> 6);
  const ushort* Wblk = Wp + (size_t)bid * kcmax * 8192;

  auto xseg_ptr = [&](int hc) -> const ushort* {
    if (hc < n0) return x0 + (size_t)hc * 8192;
    hc -= n0;
    if (hc < n1) return x1 + (size_t)hc * 8192;
    hc -= n1;
    if (hc < n2) return x2 + (size_t)hc * 8192;
    return xz;
  };
  auto stage_w = [&](int kc, int buf) {
    const ushort* src = Wblk + (size_t)kc * 8192;
#pragma unroll
    for (int j = 0; j < 4; j++) {
      int Sl = w * 4 + j;
      gload16(src + Sl * 512 + lane * 8, wbuf + buf * 8192 + Sl * 512);
    }
  };
  auto stage_x = [&](int kc, int buf) {
#pragma unroll
    for (int h = 0; h < 2; h++) {
      const ushort* p = xseg_ptr(kc * 2 + h);
#pragma unroll
      for (int i = 0; i < 4; i++) {
        int idx = i * 2048 + t * 8;
        int b = idx >> 8, ko = idx & 255;
        short8 v = *(const short8*)(p + idx);
        *(short8*)(xbuf + buf * 16640 + b * 520 + h * 256 + ko) = v;
      }
    }
  };

  stage_x(0, 0);
  stage_w(0, 0);

  f32x4 acc0 = {0.f, 0.f, 0.f, 0.f}, acc1 = {0.f, 0.f, 0.f, 0.f};
  const int c = lane & 15, kg = lane >> 4;
  const int wsw = c * 64 + ((kg ^ (c & 3)) * 16);

#pragma unroll 1
  for (int kc = 0; kc < kcmax; kc++) {
    int cur = kc & 1;
    if (kc + 1 < kcmax) {
      stage_x(kc + 1, cur ^ 1);
      stage_w(kc + 1, cur ^ 1);
      asm volatile("s_waitcnt vmcnt(4)" ::: "memory");
    } else {
      asm volatile("s_waitcnt vmcnt(0) lgkmcnt(0)" ::: "memory");
    }
    __builtin_amdgcn_sched_barrier(0);
    __builtin_amdgcn_s_barrier();
    const char* wb = (const char*)(wbuf + cur * 8192);
    const char* xb = (const char*)(xbuf + cur * 16640);
#pragma unroll
    for (int j = 0; j < 4; j++) {
      int Sl = w * 4 + j;
      short8 bfr = *(const short8*)(wb + Sl * 1024 + wsw);
      short8 a0  = *(const short8*)(xb + c * 1040 + Sl * 64 + kg * 16);
      short8 a1  = *(const short8*)(xb + (c + 16) * 1040 + Sl * 64 + kg * 16);
      acc0 = __builtin_amdgcn_mfma_f32_16x16x32_bf16(a0, bfr, acc0, 0, 0, 0);
      acc1 = __builtin_amdgcn_mfma_f32_16x16x32_bf16(a1, bfr, acc1, 0, 0, 0);
    }
    asm volatile("s_waitcnt lgkmcnt(0)" ::: "memory");
    __builtin_amdgcn_sched_barrier(0);
    __builtin_amdgcn_s_barrier();
  }

#pragma unroll
  for (int r = 0; r < 4; r++) {
    zsh[(w * 32 + kg * 4 + r) * 16 + c] = acc0[r];
    zsh[(w * 32 + 16 + kg * 4 + r) * 16 + c] = acc1[r];
  }
  __syncthreads();
  if (t < 128) {
    int b = t >> 2, jl = t & 3;
    int j = bid * 4 + jl;
    float z[4];
#pragma unroll
    for (int g = 0; g < 4; g++) {
      float s = bias[g * 1024 + j];
#pragma unroll
      for (int ww = 0; ww < 4; ww++) s += zsh[(ww * 32 + b) * 16 + g * 4 + jl];
      z[g] = s;
    }
    float cn = fsig(z[1]) * cst[b * 1024 + j] + fsig(z[0]) * ftanh(z[2]);
    float hn = fsig(z[3]) * ftanh(cn);
    cst[b * 1024 + j] = cn;
    if (h32) h32[b * 1024 + j] = hn;
    if (hT) hT[j * 32 + b] = hn;
    unsigned int uu = (unsigned int)f2bf(hn);
    unsigned int w01 = uu | (__shfl_down(uu, 1) << 16);
    unsigned int w2 = __shfl_down(uu, 2);
    unsigned int w3 = __shfl_down(uu, 3);
    if (jl == 0) {
      unsigned long long pk = ((unsigned long long)(w2 | (w3 << 16)) << 32) | w01;
      *(unsigned long long*)&hbf[(j >> 8) * 8192 + b * 256 + (j & 255)] = pk;
    }
    if (hpart_slot) {   // stp h-dot partial from in-register hn
      float v = hn * WsV[j];
      v += __shfl_xor(v, 1);
      v += __shfl_xor(v, 2);
      if (jl == 0) hpart_slot[b * 256 + bid] = v;
    }
  }
}

// ---------------- energy: pq inline; 8 tq-slices per batch ----------------
__global__ __launch_bounds__(256) void energy_kernel(const float* __restrict__ keys,
    const float* __restrict__ ha32, const float* __restrict__ Mv,
    const float* __restrict__ ast, const float* __restrict__ Wq,
    const float* __restrict__ Wv, const float* __restrict__ bv,
    const int* __restrict__ mlen, float* __restrict__ e)
{
  int bid = blockIdx.x;
  int b = bid >> 3, tq = bid & 7;
  int base = tq * 200;
  int ml = mlen[b];
  if (base >= ml) return;
  __shared__ float hsh[1024];
  __shared__ float Ml4[31 * 132];
  __shared__ float wvp[256];
  __shared__ float pqsh[256];
  __shared__ float astT[368];
  int t = threadIdx.x;
#pragma unroll
  for (int i = 0; i < 4; i++)
    hsh[i * 256 + t] = ha32[b * 1024 + i * 256 + t];
  for (int idx = t; idx < KK * AA; idx += 256) {
    int k = idx >> 7, a = idx & 127;
    Ml4[k * 132 + a] = Mv[idx];
  }
  if (t < 128) wvp[t] = Wv[t];
  __syncthreads();
  {
    int a = t & 127, half = t >> 7;
    float acc = 0.f;
    const float* wq = Wq + (size_t)(half * 512) * AA + a;
    const float* hh = hsh + half * 512;
#pragma unroll 8
    for (int kk = 0; kk < 512; kk++) acc += hh[kk] * wq[(size_t)kk * AA];
    pqsh[t] = acc;
  }
  __syncthreads();
  if (t < 128) wvp[128 + t] = pqsh[t] + pqsh[t + 128];
  __syncthreads();
  int u = t & 15, g = t >> 4;
  int a0 = u * 8;
  float4 wv0 = *(float4*)&wvp[a0], wv1 = *(float4*)&wvp[a0 + 4];
  float4 pq0 = *(float4*)&wvp[128 + a0], pq1 = *(float4*)&wvp[128 + a0 + 4];
  float bvv = bv[0];
  int smax = base + 200; if (smax > ml) smax = ml;
#pragma unroll 1
  for (int p = 0; p < 2; p++) {
    int s0 = base + p * 112;
    if (s0 >= smax) break;
    for (int idx = t; idx < 368; idx += 256) {
      int G = idx >> 3, i = idx & 7;
      int s = s0 + G - 15 + 16 * i;
      astT[idx] = (s >= 0 && s < SS) ? ast[b * SS + s] : 0.f;
    }
    __syncthreads();
    float arg[7][8];
#pragma unroll
    for (int i = 0; i < 7; i++) {
      int s = s0 + g + 16 * i;
      if (s < SS) {
        const float* kp = keys + ((size_t)b * SS + s) * AA + a0;
        float4 k0 = *(const float4*)kp, k1 = *(const float4*)(kp + 4);
        arg[i][0] = k0.x + pq0.x; arg[i][1] = k0.y + pq0.y;
        arg[i][2] = k0.z + pq0.z; arg[i][3] = k0.w + pq0.w;
        arg[i][4] = k1.x + pq1.x; arg[i][5] = k1.y + pq1.y;
        arg[i][6] = k1.z + pq1.z; arg[i][7] = k1.w + pq1.w;
      } else {
#pragma unroll
        for (int jj = 0; jj < 8; jj++) arg[i][jj] = 0.f;
      }
    }
    for (int k = 0; k < KK; k++) {
      float4 m0 = *(float4*)&Ml4[k * 132 + a0];
      float4 m1 = *(float4*)&Ml4[k * 132 + a0 + 4];
#pragma unroll
      for (int i = 0; i < 7; i++) {
        float aw = astT[(g + k) * 8 + i];
        arg[i][0] += aw * m0.x; arg[i][1] += aw * m0.y;
        arg[i][2] += aw * m0.z; arg[i][3] += aw * m0.w;
        arg[i][4] += aw * m1.x; arg[i][5] += aw * m1.y;
        arg[i][6] += aw * m1.z; arg[i][7] += aw * m1.w;
      }
    }
#pragma unroll
    for (int i = 0; i < 7; i++) {
      int s = s0 + g + 16 * i;
      float v = ftanh(arg[i][0]) * wv0.x + ftanh(arg[i][1]) * wv0.y
              + ftanh(arg[i][2]) * wv0.z + ftanh(arg[i][3]) * wv0.w
              + ftanh(arg[i][4]) * wv1.x + ftanh(arg[i][5]) * wv1.y
              + ftanh(arg[i][6]) * wv1.z + ftanh(arg[i][7]) * wv1.w;
#pragma unroll
      for (int msk = 1; msk < 16; msk <<= 1) v += __shfl_xor(v, msk);
      if (u == 0 && s < s0 + 112 && s < smax) e[b * SS + s] = v + bvv;
    }
    __syncthreads();
  }
}

// ---------------- softmax (recomputed per block) + ast + ctx partials ----------------
__global__ __launch_bounds__(256) void ctx_sm_part(const float* __restrict__ e,
    const int* __restrict__ mlen, const ushort* __restrict__ mem_bf,
    float* __restrict__ ast, float* __restrict__ cp)
{
  int sc = blockIdx.x, b = blockIdx.y;
  int ml = mlen[b];
  int s0 = sc * 100;
  int cnt = ml - s0; if (cnt > 100) cnt = 100;
  if (cnt <= 0) return;
  int t = threadIdx.x;
  __shared__ float red[4];
  __shared__ float alsh[100];
  const float* er = e + b * SS;
  float m = -3e38f;
  for (int s = t; s < ml; s += 256) m = fmaxf(m, er[s]);
#pragma unroll
  for (int msk = 1; msk < 64; msk <<= 1) m = fmaxf(m, __shfl_xor(m, msk));
  if ((t & 63) == 0) red[t >> 6] = m;
  __syncthreads();
  m = fmaxf(fmaxf(red[0], red[1]), fmaxf(red[2], red[3]));
  __syncthreads();
  float sum = 0.f;
  for (int s = t; s < ml; s += 256) sum += __expf(er[s] - m);
#pragma unroll
  for (int msk = 1; msk < 64; msk <<= 1) sum += __shfl_xor(sum, msk);
  if ((t & 63) == 0) red[t >> 6] = sum;
  __syncthreads();
  float inv = 1.f / (red[0] + red[1] + red[2] + red[3]);
  if (t < cnt) {
    float a_ = __expf(er[s0 + t] - m) * inv;
    alsh[t] = a_;
    ast[b * SS + s0 + t] += a_;
  }
  __syncthreads();
  float4 acc = make_float4(0.f, 0.f, 0.f, 0.f);
  const ushort* mp = mem_bf + ((size_t)b * SS + s0) * DE + t * 4;
#pragma unroll 4
  for (int i = 0; i < cnt; i++) {
    uint2 v = *(const uint2*)(mp + (size_t)i * DE);
    float a_ = alsh[i];
    acc.x += a_ * bf2f((ushort)(v.x & 0xffff));
    acc.y += a_ * bf2f((ushort)(v.x >> 16));
    acc.z += a_ * bf2f((ushort)(v.y & 0xffff));
    acc.w += a_ * bf2f((ushort)(v.y >> 16));
  }
  *(float4*)&cp[((size_t)sc * BB + b) * DE + t * 4] = acc;
}

// ---------------- ctx reduce -> ctxT (fp32 transposed) + ctxbf (chunks) ----------------
__global__ __launch_bounds__(256) void ctx_red(const float* __restrict__ cp,
    const int* __restrict__ mlen, float* __restrict__ ctxT, ushort* __restrict__ ctxbf)
{
  int b = blockIdx.x;
  int t = threadIdx.x;
  int nsc = (mlen[b] + 99) / 100; if (nsc > 16) nsc = 16;
  float4 acc = make_float4(0.f, 0.f, 0.f, 0.f);
  for (int sc = 0; sc < nsc; sc++) {
    float4 v = *(const float4*)&cp[((size_t)sc * BB + b) * DE + t * 4];
    acc.x += v.x; acc.y += v.y; acc.z += v.z; acc.w += v.w;
  }
  int d0 = t * 4;
  ctxT[(d0 + 0) * 32 + b] = acc.x;
  ctxT[(d0 + 1) * 32 + b] = acc.y;
  ctxT[(d0 + 2) * 32 + b] = acc.z;
  ctxT[(d0 + 3) * 32 + b] = acc.w;
  ushort4 o;
  o.x = f2bf(acc.x); o.y = f2bf(acc.y); o.z = f2bf(acc.z); o.w = f2bf(acc.w);
  *(ushort4*)&ctxbf[(d0 >> 8) * 8192 + b * 256 + (d0 & 255)] = o;
}

// ---------------- cls (full-K, fused out + stp partial) ----------------
__global__ __launch_bounds__(256) void cls_kernel(const float* __restrict__ h1T,
    const float* __restrict__ ctxT, const float* __restrict__ Wcp,
    const float* __restrict__ bc, const float* __restrict__ Ws,
    float* __restrict__ out, int ts, float* __restrict__ sp_slot)
{
  __shared__ alignas(16) float wb[2 * 2048];
  __shared__ float zc[1024];
  int bid = blockIdx.x;
  int t = threadIdx.x;
  int lane = t & 63;
  int w = __builtin_amdgcn_readfirstlane(t >> 6);
  const float* Wblk = Wcp + (size_t)bid * 8192;
  auto stage = [&](int ch, int buf) {
#pragma unroll
    for (int j = 0; j < 2; j++)
      gload16(Wblk + ch * 2048 + (w * 2 + j) * 256 + lane * 4,
              wb + buf * 2048 + (w * 2 + j) * 256);
  };
  stage(0, 0);
  int b = t & 31, kh = t >> 5;
  float a0 = 0.f, a1 = 0.f, a2 = 0.f, a3 = 0.f;
#pragma unroll 1
  for (int ch = 0; ch < 4; ch++) {
    if (ch < 3) {
      stage(ch + 1, (ch + 1) & 1);
      asm volatile("s_waitcnt vmcnt(2)" ::: "memory");
    } else {
      asm volatile("s_waitcnt vmcnt(0)" ::: "memory");
    }
    __builtin_amdgcn_sched_barrier(0);
    __builtin_amdgcn_s_barrier();
    const float* xb = (ch < 2) ? (h1T + ch * 512 * 32) : (ctxT + (ch - 2) * 512 * 32);
    const float* wc = wb + (ch & 1) * 2048;
#pragma unroll 8
    for (int kk = 0; kk < 64; kk++) {
      int k = kh * 64 + kk;
      float xv = xb[k * 32 + b];
      float4 wv4 = *(const float4*)(wc + k * 4);
      a0 += xv * wv4.x; a1 += xv * wv4.y; a2 += xv * wv4.z; a3 += xv * wv4.w;
    }
    asm volatile("s_waitcnt lgkmcnt(0)" ::: "memory");
    __builtin_amdgcn_sched_barrier(0);
    __builtin_amdgcn_s_barrier();
  }
  *(float4*)&zc[(kh * 32 + b) * 4] = make_float4(a0, a1, a2, a3);
  __syncthreads();
  if (t < 128) {
    int bb = t >> 2, ci = t & 3;
    float v = bc[bid * 4 + ci];
#pragma unroll
    for (int k2 = 0; k2 < 8; k2++) v += zc[(k2 * 32 + bb) * 4 + ci];
    out[(size_t)bb * TT * VV + (size_t)ts * VV + bid * 4 + ci] = v;
    float s = v * Ws[LU + bid * 4 + ci];
    s += __shfl_xor(s, 1);
    s += __shfl_xor(s, 2);
    if (ci == 0) sp_slot[bb * 256 + bid] = s;
  }
}

// ---------------- stp finalize ----------------
__global__ __launch_bounds__(256) void final_stp(const float* __restrict__ hp,
    const float* __restrict__ sp, const float* __restrict__ bs, float* __restrict__ out)
{
  int idx = blockIdx.x * 256 + threadIdx.x;
  if (idx < TT * BB) {
    int ts = idx >> 5, b = idx & 31;
    float s = bs[0];
    const float* h = hp + (size_t)ts * 8192 + b * 256;
    const float* p = sp + (size_t)ts * 8192 + b * 256;
    for (int i = 0; i < 256; i++) s += h[i];
    for (int i = 0; i < 250; i++) s += p[i];
    out[(size_t)BB * TT * VV + (size_t)b * TT + ts] = s;
  }
}

// ---------------- launcher ----------------

extern "C" void kernel_launch(void* const* d_in, const int* in_sizes, int n_in,
                              void* d_out, int out_size, void* d_ws, size_t ws_size,
                              hipStream_t stream)
{
  const int*   tokens = (const int*)  d_in[0];
  const float* memory = (const float*)d_in[1];
  const int*   mlen   = (const int*)  d_in[2];
  const float* emb    = (const float*)d_in[3];
  const float* Wp1    = (const float*)d_in[4];
  const float* bp1    = (const float*)d_in[5];
  const float* Wp2    = (const float*)d_in[6];
  const float* bp2    = (const float*)d_in[7];
  const float* Wq     = (const float*)d_in[8];
  const float* Wmem   = (const float*)d_in[9];
  const float* convk  = (const float*)d_in[10];
  const float* Wloc   = (const float*)d_in[11];
  const float* Wv     = (const float*)d_in[12];
  const float* bv     = (const float*)d_in[13];
  const float* Wa     = (const float*)d_in[14];
  const float* Ua     = (const float*)d_in[15];
  const float* ba     = (const float*)d_in[16];
  const float* W0     = (const float*)d_in[17];
  const float* U0     = (const float*)d_in[18];
  const float* b0     = (const float*)d_in[19];
  const float* W1     = (const float*)d_in[20];
  const float* U1     = (const float*)d_in[21];
  const float* b1     = (const float*)d_in[22];
  const float* Wc     = (const float*)d_in[23];
  const float* bc     = (const float*)d_in[24];
  const float* Ws     = (const float*)d_in[25];
  const float* bs     = (const float*)d_in[26];
  float* out = (float*)d_out;
  float* ws = (float*)d_ws;

  float*  keys  = ws + F_KEYS;
  float*  Mv    = ws + F_M;
  ushort* pbf   = (ushort*)(ws + F_PBF);
  ushort* wpa   = (ushort*)(ws + F_WPA);
  ushort* wp0   = (ushort*)(ws + F_WP0);
  ushort* wp1   = (ushort*)(ws + F_WP1);
  float*  wcp   = ws + F_WCP;
  ushort* membf = (ushort*)(ws + F_MEMBF);
  float*  ha32  = ws + F_HA32;
  float*  ca    = ws + F_CA;
  float*  c0p   = ws + F_C0;
  float*  c1p   = ws + F_C1;
  float*  astp  = ws + F_AST;
  ushort* habf  = (ushort*)(ws + F_HABF);
  ushort* h0bf  = (ushort*)(ws + F_H0BF);
  ushort* h1bf  = (ushort*)(ws + F_H1BF);
  ushort* ctxbf = (ushort*)(ws + F_CTXBF);
  float*  ctxT  = ws + F_CTXT;
  float*  h1T   = ws + F_H1T;
  ushort* zeroc = (ushort*)(ws + F_ZERO);
  float*  hp    = ws + F_HP;
  float*  sp    = ws + F_SP;
  float*  ebuf  = ws + F_E;
  float*  cp    = ws + F_CP;

  hipMemsetAsync(ws + F_ST, 0, (F_STEND - F_ST) * sizeof(float), stream);

  conv_mem<<<(BB * SS * DE / 4 + 255) / 256, 256, 0, stream>>>(
      memory, membf, BB * SS * DE / 4);
  pack_lstm<<<2560, 256, 0, stream>>>(Wa, Ua, PR + DE, 2304, wpa, 5);
  pack_lstm<<<3072, 256, 0, stream>>>(W0, U0, LU + DE, 3072, wp0, 6);
  pack_lstm<<<2048, 256, 0, stream>>>(W1, U1, LU, 2048, wp1, 4);
  pack_wc<<<2048, 256, 0, stream>>>(Wc, wcp);
  keys_kernel<<<dim3(200, BB), 256, 0, stream>>>(memory, Wmem, keys);
  mconv_kernel<<<KK, AA, 0, stream>>>(convk, Wloc, Mv);
  prenet_all<<<dim3(TT, 2), 256, 0, stream>>>(tokens, emb, Wp1, bp1, Wp2, bp2, pbf);

  int par = 0;
  for (int ts = 0; ts < TT; ts++) {
    ushort* habf_r = habf + par * 32768;
    ushort* habf_w = habf + (par ^ 1) * 32768;
    ushort* h0bf_r = h0bf + par * 32768;
    ushort* h0bf_w = h0bf + (par ^ 1) * 32768;
    ushort* h1bf_r = h1bf + par * 32768;
    ushort* h1bf_w = h1bf + (par ^ 1) * 32768;
    // attention LSTM: x=[P_ts, ctx, h_a_old, pad]  K=2560
    gemm_gates<<<256, 256, 0, stream>>>(
        pbf + (size_t)ts * 8192, 1, ctxbf, 4, habf_r, 4, zeroc,
        wpa, 5, ba, ca, ha32, habf_w, nullptr, nullptr, nullptr);
    energy_kernel<<<256, 256, 0, stream>>>(keys, ha32, Mv, astp, Wq, Wv, bv, mlen, ebuf);
    ctx_sm_part<<<dim3(16, BB), 256, 0, stream>>>(ebuf, mlen, membf, astp, cp);
    ctx_red<<<BB, 256, 0, stream>>>(cp, mlen, ctxT, ctxbf);
    // LSTM0: x=[h_a_new, ctx, h0_old]  K=3072
    gemm_gates<<<256, 256, 0, stream>>>(
        habf_w, 4, ctxbf, 4, h0bf_r, 4, zeroc,
        wp0, 6, b0, c0p, nullptr, h0bf_w, nullptr, nullptr, nullptr);
    // LSTM1: x=[h0_new, h1_old]  K=2048, + stp h-partial
    gemm_gates<<<256, 256, 0, stream>>>(
        h0bf_w, 4, h1bf_r, 4, nullptr, 0, zeroc,
        wp1, 4, b1, c1p, nullptr, h1bf_w, h1T, hp + (size_t)ts * 8192, Ws);
    // cls + stp v-partial
    cls_kernel<<<250, 256, 0, stream>>>(h1T, ctxT, wcp, bc, Ws, out, ts,
                                        sp + (size_t)ts * 8192);
    par ^= 1;
  }

  final_stp<<<32, 256, 0, stream>>>(hp, sp, bs, out);
}

// Round 11
// 42587.634 us; speedup vs baseline: 2.7981x; 1.0611x over previous
//
#include <hip/hip_runtime.h>

#define BB 32
#define TT 256
#define SS 1600
#define DE 1024
#define VV 1000
#define EM 512
#define PR 256
#define LU 1024
#define AA 128
#define FF 32
#define KK 31

typedef __attribute__((ext_vector_type(8))) short short8;
typedef __attribute__((ext_vector_type(4))) float f32x4;

// ---------- workspace layout (float units) ----------
#define F_KEYS   ((size_t)0)             // ushort BB*SS*AA (bf16 keys)
#define F_M      (F_KEYS + 6553600)
#define F_PBF    (F_M + 4096)            // ushort TT*8192
#define F_WPA    (F_PBF + 1048576)       // ushort 256*5*8192
#define F_WP0    (F_WPA + 5242880)       // ushort 256*6*8192
#define F_WP1    (F_WP0 + 6291456)       // ushort 256*4*8192
#define F_WCP    (F_WP1 + 4194304)       // float 250*2048*4
#define F_MEMBF  (F_WCP + 2048000)       // ushort 32*1600*1024
#define F_ST     (F_MEMBF + 26214400)    // ---- zeroed region start ----
#define F_HA32   (F_ST)
#define F_CA     (F_HA32 + 32768)
#define F_C0     (F_CA + 32768)
#define F_C1     (F_C0 + 32768)
#define F_AST    (F_C1 + 32768)          // 51200
#define F_HABF   (F_AST + 51200)         // ushort 2*32768 (ping-pong)
#define F_H0BF   (F_HABF + 32768)
#define F_H1BF   (F_H0BF + 32768)
#define F_CTXBF  (F_H1BF + 32768)        // ushort 32768
#define F_CTXT   (F_CTXBF + 16384)       // float 32768
#define F_H1T    (F_CTXT + 32768)        // float 32768
#define F_ZERO   (F_H1T + 32768)         // ushort 16384 (zero chunk)
#define F_STEND  (F_ZERO + 8192)         // ---- zeroed region end ----
#define F_HP     (F_STEND)               // float TT*8192
#define F_SP     (F_HP + 2097152)        // float TT*8192
#define F_E      (F_SP + 2097152)        // float 32*1600
#define F_CP     (F_E + 51200)           // float 16*BB*DE

__device__ __forceinline__ float bf2f(ushort u) {
  unsigned int x = ((unsigned int)u) << 16;
  return __builtin_bit_cast(float, x);
}
__device__ __forceinline__ ushort f2bf(float f) {
  unsigned int x = __builtin_bit_cast(unsigned int, f);
  return (ushort)((x + 0x7FFFu + ((x >> 16) & 1u)) >> 16);
}
__device__ __forceinline__ void gload16(const void* g, void* l) {
  __builtin_amdgcn_global_load_lds(
      (const __attribute__((address_space(1))) void*)g,
      (__attribute__((address_space(3))) void*)l, 16, 0, 0);
}
__device__ __forceinline__ float ftanh(float x) {
  float e = __expf(2.f * x);
  return 1.f - 2.f / (e + 1.f);
}
__device__ __forceinline__ float fsig(float x) {
  return 1.f / (1.f + __expf(-x));
}

// ---------------- once-per-call precompute ----------------

__global__ __launch_bounds__(256) void conv_mem(const float* __restrict__ in,
                                                ushort* __restrict__ out, int n4)
{
  int i = blockIdx.x * 256 + threadIdx.x;
  if (i < n4) {
    float4 v = *(const float4*)(in + (size_t)i * 4);
    ushort4 o;
    o.x = f2bf(v.x); o.y = f2bf(v.y); o.z = f2bf(v.z); o.w = f2bf(v.w);
    *(ushort4*)(out + (size_t)i * 4) = o;
  }
}

// pack LSTM layer weights: dst[blk][kc][Sl][c][kg^(c&3)][e], CK=512, bf16
__global__ __launch_bounds__(256) void pack_lstm(const float* __restrict__ Wm,
    const float* __restrict__ Um, int lenW, int ktot, ushort* __restrict__ dst, int kcmax)
{
  int k = blockIdx.x;
  int t = threadIdx.x;
  float vals[16];
  if (k < lenW) {
    const float* s = Wm + (size_t)k * 4096 + t * 16;
#pragma unroll
    for (int i = 0; i < 16; i++) vals[i] = s[i];
  } else if (k < ktot) {
    const float* s = Um + (size_t)(k - lenW) * 4096 + t * 16;
#pragma unroll
    for (int i = 0; i < 16; i++) vals[i] = s[i];
  } else {
#pragma unroll
    for (int i = 0; i < 16; i++) vals[i] = 0.f;
  }
  int kc = k >> 9, Sl = (k >> 5) & 15, kg = (k >> 3) & 3, e = k & 7;
#pragma unroll
  for (int i = 0; i < 16; i++) {
    int zcol = t * 16 + i;
    int gate = zcol >> 10, jj = zcol & 1023;
    int blk = jj >> 2, c = gate * 4 + (jj & 3);
    size_t off = ((size_t)blk * kcmax + kc) * 8192
               + Sl * 512 + c * 32 + ((kg ^ (c & 3)) * 8) + e;
    dst[off] = f2bf(vals[i]);
  }
}

// pack Wc: dst[cb][k][4] fp32
__global__ __launch_bounds__(256) void pack_wc(const float* __restrict__ Wc,
                                               float* __restrict__ dst)
{
  int k = blockIdx.x;  // 2048
  int t = threadIdx.x;
  if (t < 250) {
    float4 v = *(const float4*)(Wc + (size_t)k * VV + t * 4);
    *(float4*)(dst + (size_t)t * 8192 + k * 4) = v;
  }
}

// keys from bf16 memory -> bf16 keys
__global__ __launch_bounds__(256) void keys_kernel(const ushort* __restrict__ membf,
                                                   const float* __restrict__ Wmem,
                                                   ushort* __restrict__ keys)
{
  int stile = blockIdx.x;
  int b = blockIdx.y;
  int t = threadIdx.x;
  __shared__ float Xt[8 * 1032];
  const ushort* mp = membf + ((size_t)b * SS + (size_t)stile * 8) * DE;
  for (int li = t; li < 8 * 256; li += 256) {
    int row = li >> 8, c4 = li & 255;
    ushort4 v = *(const ushort4*)(mp + row * DE + c4 * 4);
    float* xp = Xt + row * 1032 + c4 * 4;
    xp[0] = bf2f(v.x); xp[1] = bf2f(v.y); xp[2] = bf2f(v.z); xp[3] = bf2f(v.w);
  }
  __syncthreads();
  int sl = t >> 5, u = t & 31;
  float acc[4] = {0.f, 0.f, 0.f, 0.f};
  for (int k = 0; k < DE; k++) {
    float x = Xt[sl * 1032 + k];
    const float* wr = Wmem + k * AA;
#pragma unroll
    for (int jj = 0; jj < 4; jj++) acc[jj] += x * wr[u + 32 * jj];
  }
  ushort* kp = keys + ((size_t)b * SS + (size_t)stile * 8 + sl) * AA;
#pragma unroll
  for (int jj = 0; jj < 4; jj++) kp[u + 32 * jj] = f2bf(acc[jj]);
}

__global__ void mconv_kernel(const float* __restrict__ ck, const float* __restrict__ Wloc,
                             float* __restrict__ M)
{
  int a = threadIdx.x;
  int k = blockIdx.x;
  float acc = 0.f;
  for (int c = 0; c < FF; c++) acc += ck[k * FF + c] * Wloc[c * AA + a];
  M[k * AA + a] = acc;
}

__global__ __launch_bounds__(256) void prenet_all(const int* __restrict__ tokens,
    const float* __restrict__ emb, const float* __restrict__ Wp1, const float* __restrict__ bp1,
    const float* __restrict__ Wp2, const float* __restrict__ bp2, ushort* __restrict__ Pbf)
{
  int tstep = blockIdx.x;
  int bh = blockIdx.y;
  int t = threadIdx.x;
  __shared__ float X[16 * 512];
  __shared__ float P1s[16 * 256];
  for (int li = t; li < 16 * 128; li += 256) {
    int bb = li >> 7, c4 = li & 127;
    int tok = tokens[(bh * 16 + bb) * TT + tstep];
    *(float4*)(X + bb * 512 + c4 * 4) = *(const float4*)(emb + (size_t)tok * EM + c4 * 4);
  }
  __syncthreads();
  int j = t;
  float acc[16];
#pragma unroll
  for (int i = 0; i < 16; i++) acc[i] = 0.f;
  for (int k = 0; k < EM; k++) {
    float w = Wp1[k * PR + j];
#pragma unroll
    for (int i = 0; i < 16; i++) acc[i] += X[i * 512 + k] * w;
  }
#pragma unroll
  for (int i = 0; i < 16; i++) P1s[i * 256 + j] = fmaxf(acc[i] + bp1[j], 0.f);
  __syncthreads();
#pragma unroll
  for (int i = 0; i < 16; i++) acc[i] = 0.f;
  for (int k = 0; k < PR; k++) {
    float w = Wp2[k * PR + j];
#pragma unroll
    for (int i = 0; i < 16; i++) acc[i] += P1s[i * 256 + k] * w;
  }
  ushort* outp = Pbf + (size_t)tstep * 8192 + (size_t)bh * 16 * 256;
#pragma unroll
  for (int i = 0; i < 16; i++) outp[i * 256 + j] = f2bf(fmaxf(acc[i] + bp2[j], 0.f));
}

// ---------------- fused full-K gemm + gates, BARRIER-FREE K-loop ----------------
// Each wave owns 4 Sl (128 k per kc) with a PRIVATE double-buffered weight ring;
// x fragments are read directly from global (L2-hot, shared by all blocks).
// vmcnt is per-wave -> waves free-run, overlapping each other's memory latency.
__global__ __launch_bounds__(256) void gemm_gates(
    const ushort* __restrict__ x0, int n0, const ushort* __restrict__ x1, int n1,
    const ushort* __restrict__ x2, int n2, const ushort* __restrict__ xz,
    const ushort* __restrict__ Wp, int kcmax, const float* __restrict__ bias,
    float* __restrict__ cst, float* __restrict__ h32, ushort* __restrict__ hbf,
    float* __restrict__ hT, float* __restrict__ hpart_slot, const float* __restrict__ WsV)
{
  __shared__ alignas(16) ushort wbuf[4][2][2048];   // 32 KB: wave-private rings
  __shared__ float zsh[2048];                       // 8 KB
  const int bid = blockIdx.x;
  const int t = threadIdx.x;
  const int lane = t & 63;
  const int w = __builtin_amdgcn_readfirstlane(t >> 6);
  const ushort* Wblk = Wp + (size_t)bid * kcmax * 8192;

  auto xseg_ptr = [&](int hc) -> const ushort* {
    if (hc < n0) return x0 + (size_t)hc * 8192;
    hc -= n0;
    if (hc < n1) return x1 + (size_t)hc * 8192;
    hc -= n1;
    if (hc < n2) return x2 + (size_t)hc * 8192;
    return xz;
  };
  auto stage_w = [&](int kc, int buf) {
    const ushort* src = Wblk + (size_t)kc * 8192 + (w * 4) * 512;
#pragma unroll
    for (int i = 0; i < 4; i++)
      gload16(src + i * 512 + lane * 8, &wbuf[w][buf][i * 512]);
  };

  stage_w(0, 0);

  f32x4 acc0 = {0.f, 0.f, 0.f, 0.f}, acc1 = {0.f, 0.f, 0.f, 0.f};
  const int c = lane & 15, kg = lane >> 4;
  const int wlo = w & 1;          // Sl&7 = wlo*4 + j
  const int whi = w >> 1;         // hc = kc*2 + whi

#pragma unroll 1
  for (int kc = 0; kc < kcmax; kc++) {
    int cur = kc & 1;
    // x fragments for this kc (issued first so compiler's x-wait keeps prefetch alive)
    const ushort* seg = xseg_ptr(kc * 2 + whi);
    short8 xa[4], xb_[4];
#pragma unroll
    for (int j = 0; j < 4; j++) {
      int koff = (wlo * 4 + j) * 32 + kg * 8;
      xa[j]  = *(const short8*)(seg + c * 256 + koff);
      xb_[j] = *(const short8*)(seg + (c + 16) * 256 + koff);
    }
    if (kc + 1 < kcmax) {
      stage_w(kc + 1, cur ^ 1);
      asm volatile("s_waitcnt vmcnt(12)" ::: "memory");   // own stage(kc) landed
    } else {
      asm volatile("s_waitcnt vmcnt(8)" ::: "memory");
    }
    __builtin_amdgcn_sched_barrier(0);
    const ushort* wbp = wbuf[w][cur];
#pragma unroll
    for (int j = 0; j < 4; j++) {
      short8 bfr = *(const short8*)(wbp + j * 512 + c * 32 + ((kg ^ (c & 3)) * 8));
      acc0 = __builtin_amdgcn_mfma_f32_16x16x32_bf16(xa[j], bfr, acc0, 0, 0, 0);
      acc1 = __builtin_amdgcn_mfma_f32_16x16x32_bf16(xb_[j], bfr, acc1, 0, 0, 0);
    }
    asm volatile("s_waitcnt lgkmcnt(0)" ::: "memory");
    __builtin_amdgcn_sched_barrier(0);
  }

#pragma unroll
  for (int r = 0; r < 4; r++) {
    zsh[(w * 32 + kg * 4 + r) * 16 + c] = acc0[r];
    zsh[(w * 32 + 16 + kg * 4 + r) * 16 + c] = acc1[r];
  }
  __syncthreads();
  if (t < 128) {
    int b = t >> 2, jl = t & 3;
    int j = bid * 4 + jl;
    float z[4];
#pragma unroll
    for (int g = 0; g < 4; g++) {
      float s = bias[g * 1024 + j];
#pragma unroll
      for (int ww = 0; ww < 4; ww++) s += zsh[(ww * 32 + b) * 16 + g * 4 + jl];
      z[g] = s;
    }
    float cn = fsig(z[1]) * cst[b * 1024 + j] + fsig(z[0]) * ftanh(z[2]);
    float hn = fsig(z[3]) * ftanh(cn);
    cst[b * 1024 + j] = cn;
    if (h32) h32[b * 1024 + j] = hn;
    if (hT) hT[j * 32 + b] = hn;
    unsigned int uu = (unsigned int)f2bf(hn);
    unsigned int w01 = uu | (__shfl_down(uu, 1) << 16);
    unsigned int w2 = __shfl_down(uu, 2);
    unsigned int w3 = __shfl_down(uu, 3);
    if (jl == 0) {
      unsigned long long pk = ((unsigned long long)(w2 | (w3 << 16)) << 32) | w01;
      *(unsigned long long*)&hbf[(j >> 8) * 8192 + b * 256 + (j & 255)] = pk;
    }
    if (hpart_slot) {
      float v = hn * WsV[j];
      v += __shfl_xor(v, 1);
      v += __shfl_xor(v, 2);
      if (jl == 0) hpart_slot[b * 256 + bid] = v;
    }
  }
}

// ---------------- energy: pq inline (deep unroll); bf16 keys ----------------
__global__ __launch_bounds__(256) void energy_kernel(const ushort* __restrict__ keys,
    const float* __restrict__ ha32, const float* __restrict__ Mv,
    const float* __restrict__ ast, const float* __restrict__ Wq,
    const float* __restrict__ Wv, const float* __restrict__ bv,
    const int* __restrict__ mlen, float* __restrict__ e)
{
  int bid = blockIdx.x;
  int b = bid >> 3, tq = bid & 7;
  int base = tq * 200;
  int ml = mlen[b];
  if (base >= ml) return;
  __shared__ float hsh[1024];
  __shared__ float Ml4[31 * 132];
  __shared__ float wvp[256];
  __shared__ float pqsh[256];
  __shared__ float astT[368];
  int t = threadIdx.x;
#pragma unroll
  for (int i = 0; i < 4; i++)
    hsh[i * 256 + t] = ha32[b * 1024 + i * 256 + t];
  for (int idx = t; idx < KK * AA; idx += 256) {
    int k = idx >> 7, a = idx & 127;
    Ml4[k * 132 + a] = Mv[idx];
  }
  if (t < 128) wvp[t] = Wv[t];
  __syncthreads();
  {
    int a = t & 127, half = t >> 7;
    float acc = 0.f;
    const float* wq = Wq + (size_t)(half * 512) * AA + a;
    const float* hh = hsh + half * 512;
#pragma unroll 16
    for (int kk = 0; kk < 512; kk++) acc += hh[kk] * wq[(size_t)kk * AA];
    pqsh[t] = acc;
  }
  __syncthreads();
  if (t < 128) wvp[128 + t] = pqsh[t] + pqsh[t + 128];
  __syncthreads();
  int u = t & 15, g = t >> 4;
  int a0 = u * 8;
  float4 wv0 = *(float4*)&wvp[a0], wv1 = *(float4*)&wvp[a0 + 4];
  float4 pq0 = *(float4*)&wvp[128 + a0], pq1 = *(float4*)&wvp[128 + a0 + 4];
  float bvv = bv[0];
  int smax = base + 200; if (smax > ml) smax = ml;
#pragma unroll 1
  for (int p = 0; p < 2; p++) {
    int s0 = base + p * 112;
    if (s0 >= smax) break;
    for (int idx = t; idx < 368; idx += 256) {
      int G = idx >> 3, i = idx & 7;
      int s = s0 + G - 15 + 16 * i;
      astT[idx] = (s >= 0 && s < SS) ? ast[b * SS + s] : 0.f;
    }
    __syncthreads();
    float arg[7][8];
#pragma unroll
    for (int i = 0; i < 7; i++) {
      int s = s0 + g + 16 * i;
      if (s < SS) {
        short8 kv = *(const short8*)(keys + ((size_t)b * SS + s) * AA + a0);
        arg[i][0] = bf2f((ushort)kv[0]) + pq0.x;
        arg[i][1] = bf2f((ushort)kv[1]) + pq0.y;
        arg[i][2] = bf2f((ushort)kv[2]) + pq0.z;
        arg[i][3] = bf2f((ushort)kv[3]) + pq0.w;
        arg[i][4] = bf2f((ushort)kv[4]) + pq1.x;
        arg[i][5] = bf2f((ushort)kv[5]) + pq1.y;
        arg[i][6] = bf2f((ushort)kv[6]) + pq1.z;
        arg[i][7] = bf2f((ushort)kv[7]) + pq1.w;
      } else {
#pragma unroll
        for (int jj = 0; jj < 8; jj++) arg[i][jj] = 0.f;
      }
    }
    for (int k = 0; k < KK; k++) {
      float4 m0 = *(float4*)&Ml4[k * 132 + a0];
      float4 m1 = *(float4*)&Ml4[k * 132 + a0 + 4];
#pragma unroll
      for (int i = 0; i < 7; i++) {
        float aw = astT[(g + k) * 8 + i];
        arg[i][0] += aw * m0.x; arg[i][1] += aw * m0.y;
        arg[i][2] += aw * m0.z; arg[i][3] += aw * m0.w;
        arg[i][4] += aw * m1.x; arg[i][5] += aw * m1.y;
        arg[i][6] += aw * m1.z; arg[i][7] += aw * m1.w;
      }
    }
#pragma unroll
    for (int i = 0; i < 7; i++) {
      int s = s0 + g + 16 * i;
      float v = ftanh(arg[i][0]) * wv0.x + ftanh(arg[i][1]) * wv0.y
              + ftanh(arg[i][2]) * wv0.z + ftanh(arg[i][3]) * wv0.w
              + ftanh(arg[i][4]) * wv1.x + ftanh(arg[i][5]) * wv1.y
              + ftanh(arg[i][6]) * wv1.z + ftanh(arg[i][7]) * wv1.w;
#pragma unroll
      for (int msk = 1; msk < 16; msk <<= 1) v += __shfl_xor(v, msk);
      if (u == 0 && s < s0 + 112 && s < smax) e[b * SS + s] = v + bvv;
    }
    __syncthreads();
  }
}

// ---------------- softmax (recomputed per block) + ast + ctx partials ----------------
__global__ __launch_bounds__(256) void ctx_sm_part(const float* __restrict__ e,
    const int* __restrict__ mlen, const ushort* __restrict__ mem_bf,
    float* __restrict__ ast, float* __restrict__ cp)
{
  int sc = blockIdx.x, b = blockIdx.y;
  int ml = mlen[b];
  int s0 = sc * 100;
  int cnt = ml - s0; if (cnt > 100) cnt = 100;
  if (cnt <= 0) return;
  int t = threadIdx.x;
  __shared__ float red[4];
  __shared__ float alsh[100];
  const float* er = e + b * SS;
  float m = -3e38f;
  for (int s = t; s < ml; s += 256) m = fmaxf(m, er[s]);
#pragma unroll
  for (int msk = 1; msk < 64; msk <<= 1) m = fmaxf(m, __shfl_xor(m, msk));
  if ((t & 63) == 0) red[t >> 6] = m;
  __syncthreads();
  m = fmaxf(fmaxf(red[0], red[1]), fmaxf(red[2], red[3]));
  __syncthreads();
  float sum = 0.f;
  for (int s = t; s < ml; s += 256) sum += __expf(er[s] - m);
#pragma unroll
  for (int msk = 1; msk < 64; msk <<= 1) sum += __shfl_xor(sum, msk);
  if ((t & 63) == 0) red[t >> 6] = sum;
  __syncthreads();
  float inv = 1.f / (red[0] + red[1] + red[2] + red[3]);
  if (t < cnt) {
    float a_ = __expf(er[s0 + t] - m) * inv;
    alsh[t] = a_;
    ast[b * SS + s0 + t] += a_;
  }
  __syncthreads();
  float4 acc = make_float4(0.f, 0.f, 0.f, 0.f);
  const ushort* mp = mem_bf + ((size_t)b * SS + s0) * DE + t * 4;
#pragma unroll 8
  for (int i = 0; i < cnt; i++) {
    uint2 v = *(const uint2*)(mp + (size_t)i * DE);
    float a_ = alsh[i];
    acc.x += a_ * bf2f((ushort)(v.x & 0xffff));
    acc.y += a_ * bf2f((ushort)(v.x >> 16));
    acc.z += a_ * bf2f((ushort)(v.y & 0xffff));
    acc.w += a_ * bf2f((ushort)(v.y >> 16));
  }
  *(float4*)&cp[((size_t)sc * BB + b) * DE + t * 4] = acc;
}

// ---------------- ctx reduce -> ctxT (fp32 transposed) + ctxbf (chunks) ----------------
__global__ __launch_bounds__(256) void ctx_red(const float* __restrict__ cp,
    const int* __restrict__ mlen, float* __restrict__ ctxT, ushort* __restrict__ ctxbf)
{
  int b = blockIdx.x;
  int t = threadIdx.x;
  int nsc = (mlen[b] + 99) / 100; if (nsc > 16) nsc = 16;
  float4 acc = make_float4(0.f, 0.f, 0.f, 0.f);
  for (int sc = 0; sc < nsc; sc++) {
    float4 v = *(const float4*)&cp[((size_t)sc * BB + b) * DE + t * 4];
    acc.x += v.x; acc.y += v.y; acc.z += v.z; acc.w += v.w;
  }
  int d0 = t * 4;
  ctxT[(d0 + 0) * 32 + b] = acc.x;
  ctxT[(d0 + 1) * 32 + b] = acc.y;
  ctxT[(d0 + 2) * 32 + b] = acc.z;
  ctxT[(d0 + 3) * 32 + b] = acc.w;
  ushort4 o;
  o.x = f2bf(acc.x); o.y = f2bf(acc.y); o.z = f2bf(acc.z); o.w = f2bf(acc.w);
  *(ushort4*)&ctxbf[(d0 >> 8) * 8192 + b * 256 + (d0 & 255)] = o;
}

// ---------------- cls (full-K, fused out + stp partial) ----------------
__global__ __launch_bounds__(256) void cls_kernel(const float* __restrict__ h1T,
    const float* __restrict__ ctxT, const float* __restrict__ Wcp,
    const float* __restrict__ bc, const float* __restrict__ Ws,
    float* __restrict__ out, int ts, float* __restrict__ sp_slot)
{
  __shared__ alignas(16) float wb[2 * 2048];
  __shared__ float zc[1024];
  int bid = blockIdx.x;
  int t = threadIdx.x;
  int lane = t & 63;
  int w = __builtin_amdgcn_readfirstlane(t >> 6);
  const float* Wblk = Wcp + (size_t)bid * 8192;
  auto stage = [&](int ch, int buf) {
#pragma unroll
    for (int j = 0; j < 2; j++)
      gload16(Wblk + ch * 2048 + (w * 2 + j) * 256 + lane * 4,
              wb + buf * 2048 + (w * 2 + j) * 256);
  };
  stage(0, 0);
  int b = t & 31, kh = t >> 5;
  float a0 = 0.f, a1 = 0.f, a2 = 0.f, a3 = 0.f;
#pragma unroll 1
  for (int ch = 0; ch < 4; ch++) {
    if (ch < 3) {
      stage(ch + 1, (ch + 1) & 1);
      asm volatile("s_waitcnt vmcnt(2)" ::: "memory");
    } else {
      asm volatile("s_waitcnt vmcnt(0)" ::: "memory");
    }
    __builtin_amdgcn_sched_barrier(0);
    __builtin_amdgcn_s_barrier();
    const float* xb = (ch < 2) ? (h1T + ch * 512 * 32) : (ctxT + (ch - 2) * 512 * 32);
    const float* wc = wb + (ch & 1) * 2048;
#pragma unroll 16
    for (int kk = 0; kk < 64; kk++) {
      int k = kh * 64 + kk;
      float xv = xb[k * 32 + b];
      float4 wv4 = *(const float4*)(wc + k * 4);
      a0 += xv * wv4.x; a1 += xv * wv4.y; a2 += xv * wv4.z; a3 += xv * wv4.w;
    }
    asm volatile("s_waitcnt lgkmcnt(0)" ::: "memory");
    __builtin_amdgcn_sched_barrier(0);
    __builtin_amdgcn_s_barrier();
  }
  *(float4*)&zc[(kh * 32 + b) * 4] = make_float4(a0, a1, a2, a3);
  __syncthreads();
  if (t < 128) {
    int bb = t >> 2, ci = t & 3;
    float v = bc[bid * 4 + ci];
#pragma unroll
    for (int k2 = 0; k2 < 8; k2++) v += zc[(k2 * 32 + bb) * 4 + ci];
    out[(size_t)bb * TT * VV + (size_t)ts * VV + bid * 4 + ci] = v;
    float s = v * Ws[LU + bid * 4 + ci];
    s += __shfl_xor(s, 1);
    s += __shfl_xor(s, 2);
    if (ci == 0) sp_slot[bb * 256 + bid] = s;
  }
}

// ---------------- stp finalize ----------------
__global__ __launch_bounds__(256) void final_stp(const float* __restrict__ hp,
    const float* __restrict__ sp, const float* __restrict__ bs, float* __restrict__ out)
{
  int idx = blockIdx.x * 256 + threadIdx.x;
  if (idx < TT * BB) {
    int ts = idx >> 5, b = idx & 31;
    float s = bs[0];
    const float* h = hp + (size_t)ts * 8192 + b * 256;
    const float* p = sp + (size_t)ts * 8192 + b * 256;
    for (int i = 0; i < 256; i++) s += h[i];
    for (int i = 0; i < 250; i++) s += p[i];
    out[(size_t)BB * TT * VV + (size_t)b * TT + ts] = s;
  }
}

// ---------------- launcher ----------------

extern "C" void kernel_launch(void* const* d_in, const int* in_sizes, int n_in,
                              void* d_out, int out_size, void* d_ws, size_t ws_size,
                              hipStream_t stream)
{
  const int*   tokens = (const int*)  d_in[0];
  const float* memory = (const float*)d_in[1];
  const int*   mlen   = (const int*)  d_in[2];
  const float* emb    = (const float*)d_in[3];
  const float* Wp1    = (const float*)d_in[4];
  const float* bp1    = (const float*)d_in[5];
  const float* Wp2    = (const float*)d_in[6];
  const float* bp2    = (const float*)d_in[7];
  const float* Wq     = (const float*)d_in[8];
  const float* Wmem   = (const float*)d_in[9];
  const float* convk  = (const float*)d_in[10];
  const float* Wloc   = (const float*)d_in[11];
  const float* Wv     = (const float*)d_in[12];
  const float* bv     = (const float*)d_in[13];
  const float* Wa     = (const float*)d_in[14];
  const float* Ua     = (const float*)d_in[15];
  const float* ba     = (const float*)d_in[16];
  const float* W0     = (const float*)d_in[17];
  const float* U0     = (const float*)d_in[18];
  const float* b0     = (const float*)d_in[19];
  const float* W1     = (const float*)d_in[20];
  const float* U1     = (const float*)d_in[21];
  const float* b1     = (const float*)d_in[22];
  const float* Wc     = (const float*)d_in[23];
  const float* bc     = (const float*)d_in[24];
  const float* Ws     = (const float*)d_in[25];
  const float* bs     = (const float*)d_in[26];
  float* out = (float*)d_out;
  float* ws = (float*)d_ws;

  ushort* keysbf = (ushort*)(ws + F_KEYS);
  float*  Mv    = ws + F_M;
  ushort* pbf   = (ushort*)(ws + F_PBF);
  ushort* wpa   = (ushort*)(ws + F_WPA);
  ushort* wp0   = (ushort*)(ws + F_WP0);
  ushort* wp1   = (ushort*)(ws + F_WP1);
  float*  wcp   = ws + F_WCP;
  ushort* membf = (ushort*)(ws + F_MEMBF);
  float*  ha32  = ws + F_HA32;
  float*  ca    = ws + F_CA;
  float*  c0p   = ws + F_C0;
  float*  c1p   = ws + F_C1;
  float*  astp  = ws + F_AST;
  ushort* habf  = (ushort*)(ws + F_HABF);
  ushort* h0bf  = (ushort*)(ws + F_H0BF);
  ushort* h1bf  = (ushort*)(ws + F_H1BF);
  ushort* ctxbf = (ushort*)(ws + F_CTXBF);
  float*  ctxT  = ws + F_CTXT;
  float*  h1T   = ws + F_H1T;
  ushort* zeroc = (ushort*)(ws + F_ZERO);
  float*  hp    = ws + F_HP;
  float*  sp    = ws + F_SP;
  float*  ebuf  = ws + F_E;
  float*  cp    = ws + F_CP;

  hipMemsetAsync(ws + F_ST, 0, (F_STEND - F_ST) * sizeof(float), stream);

  conv_mem<<<(BB * SS * DE / 4 + 255) / 256, 256, 0, stream>>>(
      memory, membf, BB * SS * DE / 4);
  pack_lstm<<<2560, 256, 0, stream>>>(Wa, Ua, PR + DE, 2304, wpa, 5);
  pack_lstm<<<3072, 256, 0, stream>>>(W0, U0, LU + DE, 3072, wp0, 6);
  pack_lstm<<<2048, 256, 0, stream>>>(W1, U1, LU, 2048, wp1, 4);
  pack_wc<<<2048, 256, 0, stream>>>(Wc, wcp);
  keys_kernel<<<dim3(200, BB), 256, 0, stream>>>(membf, Wmem, keysbf);
  mconv_kernel<<<KK, AA, 0, stream>>>(convk, Wloc, Mv);
  prenet_all<<<dim3(TT, 2), 256, 0, stream>>>(tokens, emb, Wp1, bp1, Wp2, bp2, pbf);

  int par = 0;
  for (int ts = 0; ts < TT; ts++) {
    ushort* habf_r = habf + par * 32768;
    ushort* habf_w = habf + (par ^ 1) * 32768;
    ushort* h0bf_r = h0bf + par * 32768;
    ushort* h0bf_w = h0bf + (par ^ 1) * 32768;
    ushort* h1bf_r = h1bf + par * 32768;
    ushort* h1bf_w = h1bf + (par ^ 1) * 32768;
    // attention LSTM: x=[P_ts, ctx, h_a_old, pad]  K=2560
    gemm_gates<<<256, 256, 0, stream>>>(
        pbf + (size_t)ts * 8192, 1, ctxbf, 4, habf_r, 4, zeroc,
        wpa, 5, ba, ca, ha32, habf_w, nullptr, nullptr, nullptr);
    energy_kernel<<<256, 256, 0, stream>>>(keysbf, ha32, Mv, astp, Wq, Wv, bv, mlen, ebuf);
    ctx_sm_part<<<dim3(16, BB), 256, 0, stream>>>(ebuf, mlen, membf, astp, cp);
    ctx_red<<<BB, 256, 0, stream>>>(cp, mlen, ctxT, ctxbf);
    // LSTM0: x=[h_a_new, ctx, h0_old]  K=3072
    gemm_gates<<<256, 256, 0, stream>>>(
        habf_w, 4, ctxbf, 4, h0bf_r, 4, zeroc,
        wp0, 6, b0, c0p, nullptr, h0bf_w, nullptr, nullptr, nullptr);
    // LSTM1: x=[h0_new, h1_old]  K=2048, + stp h-partial
    gemm_gates<<<256, 256, 0, stream>>>(
        h0bf_w, 4, h1bf_r, 4, nullptr, 0, zeroc,
        wp1, 4, b1, c1p, nullptr, h1bf_w, h1T, hp + (size_t)ts * 8192, Ws);
    // cls + stp v-partial
    cls_kernel<<<250, 256, 0, stream>>>(h1T, ctxT, wcp, bc, Ws, out, ts,
                                        sp + (size_t)ts * 8192);
    par ^= 1;
  }

  final_stp<<<32, 256, 0, stream>>>(hp, sp, bs, out);
}

// Round 12
// 27422.455 us; speedup vs baseline: 4.3456x; 1.5530x over previous
//
#include <hip/hip_runtime.h>

#define BB 32
#define TT 256
#define SS 1600
#define DE 1024
#define VV 1000
#define EM 512
#define PR 256
#define LU 1024
#define AA 128
#define FF 32
#define KK 31
#define KSC 32
#define KSTEP 16
#define NBUF 3

typedef __attribute__((ext_vector_type(8))) short short8;
typedef __attribute__((ext_vector_type(4))) float f32x4;

__device__ __forceinline__ float bf2f(ushort u) {
  unsigned int x = ((unsigned int)u) << 16;
  return __builtin_bit_cast(float, x);
}
__device__ __forceinline__ ushort f2bf(float f) {
  unsigned int x = __builtin_bit_cast(unsigned int, f);
  return (ushort)((x + 0x7FFFu + ((x >> 16) & 1u)) >> 16);
}
__device__ __forceinline__ void gload16(const void* g, void* l) {
  __builtin_amdgcn_global_load_lds(
      (const __attribute__((address_space(1))) void*)g,
      (__attribute__((address_space(3))) void*)l, 16, 0, 0);
}
__device__ __forceinline__ float ftanh(float x) {
  float e = __expf(2.f * x);
  return 1.f - 2.f / (e + 1.f);
}
__device__ __forceinline__ float fsig(float x) {
  return 1.f / (1.f + __expf(-x));
}

// ---------------- once-per-call precompute (r5 verbatim) ----------------

__global__ __launch_bounds__(256) void conv_mem(const float* __restrict__ in,
                                                ushort* __restrict__ out, int n4)
{
  int i = blockIdx.x * 256 + threadIdx.x;
  if (i < n4) {
    float4 v = *(const float4*)(in + (size_t)i * 4);
    ushort4 o;
    o.x = f2bf(v.x); o.y = f2bf(v.y); o.z = f2bf(v.z); o.w = f2bf(v.w);
    *(ushort4*)(out + (size_t)i * 4) = o;
  }
}

__global__ __launch_bounds__(256) void pack_wu(const float* __restrict__ Wm,
    const float* __restrict__ Um, int lenW, int ktot, ushort* __restrict__ out, int nS)
{
  int bid = blockIdx.x;
  int kg = bid & 3, S = (bid >> 2) % nS, jb = (bid >> 2) / nS;
  int t = threadIdx.x;
  int c = t >> 1, e4 = (t & 1) * 4;
  int kbase = S * 32 + kg * 8 + e4;
  int j = jb * 128 + c;
  ushort* op = out + ((size_t)(jb * nS + S) * 4 + kg) * 1024 + c * 8 + e4;
#pragma unroll
  for (int i = 0; i < 4; i++) {
    int k = kbase + i;
    float v = 0.f;
    if (k < lenW)      v = Wm[(size_t)k * 4096 + j];
    else if (k < ktot) v = Um[(size_t)(k - lenW) * 4096 + j];
    op[i] = f2bf(v);
  }
}

__global__ __launch_bounds__(256) void keys_kernel(const float* __restrict__ mem,
                                                   const float* __restrict__ Wmem,
                                                   float* __restrict__ keys)
{
  int stile = blockIdx.x;
  int b = blockIdx.y;
  int t = threadIdx.x;
  __shared__ float Xt[8 * 1032];
  const float* mp = mem + ((size_t)b * SS + (size_t)stile * 8) * DE;
  for (int li = t; li < 8 * 256; li += 256) {
    int row = li >> 8, c4 = li & 255;
    float4 v = *(const float4*)(mp + row * DE + c4 * 4);
    *(float4*)(Xt + row * 1032 + c4 * 4) = v;
  }
  __syncthreads();
  int sl = t >> 5, u = t & 31;
  float acc[4] = {0.f, 0.f, 0.f, 0.f};
  for (int k = 0; k < DE; k++) {
    float x = Xt[sl * 1032 + k];
    const float* wr = Wmem + k * AA;
#pragma unroll
    for (int jj = 0; jj < 4; jj++) acc[jj] += x * wr[u + 32 * jj];
  }
  float* kp = keys + ((size_t)b * SS + (size_t)stile * 8 + sl) * AA;
#pragma unroll
  for (int jj = 0; jj < 4; jj++) kp[u + 32 * jj] = acc[jj];
}

__global__ void mconv_kernel(const float* __restrict__ ck, const float* __restrict__ Wloc,
                             float* __restrict__ M)
{
  int a = threadIdx.x;
  int k = blockIdx.x;
  float acc = 0.f;
  for (int c = 0; c < FF; c++) acc += ck[k * FF + c] * Wloc[c * AA + a];
  M[k * AA + a] = acc;
}

__global__ __launch_bounds__(256) void prenet_all(const int* __restrict__ tokens,
    const float* __restrict__ emb, const float* __restrict__ Wp1, const float* __restrict__ bp1,
    const float* __restrict__ Wp2, const float* __restrict__ bp2, float* __restrict__ P)
{
  int tstep = blockIdx.x;
  int bh = blockIdx.y;
  int t = threadIdx.x;
  __shared__ float X[16 * 512];
  __shared__ float P1[16 * 256];
  for (int li = t; li < 16 * 128; li += 256) {
    int bb = li >> 7, c4 = li & 127;
    int tok = tokens[(bh * 16 + bb) * TT + tstep];
    *(float4*)(X + bb * 512 + c4 * 4) = *(const float4*)(emb + (size_t)tok * EM + c4 * 4);
  }
  __syncthreads();
  int j = t;
  float acc[16];
#pragma unroll
  for (int i = 0; i < 16; i++) acc[i] = 0.f;
  for (int k = 0; k < EM; k++) {
    float w = Wp1[k * PR + j];
#pragma unroll
    for (int i = 0; i < 16; i++) acc[i] += X[i * 512 + k] * w;
  }
#pragma unroll
  for (int i = 0; i < 16; i++) P1[i * 256 + j] = fmaxf(acc[i] + bp1[j], 0.f);
  __syncthreads();
#pragma unroll
  for (int i = 0; i < 16; i++) acc[i] = 0.f;
  for (int k = 0; k < PR; k++) {
    float w = Wp2[k * PR + j];
#pragma unroll
    for (int i = 0; i < 16; i++) acc[i] += P1[i * 256 + k] * w;
  }
  float* outp = P + (size_t)tstep * BB * PR + (size_t)bh * 16 * PR;
#pragma unroll
  for (int i = 0; i < 16; i++) outp[i * PR + j] = fmaxf(acc[i] + bp2[j], 0.f);
}

// ---------------- device bodies (r5 verbatim, grid coords as args) ----------------

__device__ void gemm_dev(int jb, int kc,
    const float* x0, int len0, const float* x1, int len1, const float* x2, int len2,
    const ushort* WUP, int nS, int chunk, float* zp, char* ldsraw)
{
  ushort* wlT = (ushort*)ldsraw;                  // 3*8192 us = 48KB
  ushort* xl  = (ushort*)(ldsraw + 49152);        // 32*(chunk+8) us
  const int t = threadIdx.x;
  const int lane = t & 63;
  const int wv = __builtin_amdgcn_readfirstlane(t >> 6);
  const int PADK = chunk + 8;
  const int nst = chunk >> 6;
  const int k0 = kc * chunk;
  const int S0 = k0 >> 5;
  const size_t jbS = (size_t)jb * nS;
  const int lenW01 = len0 + len1;
  const int ktot = lenW01 + len2;

  auto stage = [&](int s) {
    int buf = s % 3;
    int Sb = S0 + s * 2;
#pragma unroll
    for (int sub = 0; sub < 4; sub++) {
      int inst = wv * 4 + sub;
      const ushort* src = WUP + (jbS + Sb + (inst >> 3)) * 4096
                        + (size_t)(((inst & 7) * 64 + lane) * 8);
      ushort* dst = wlT + buf * 8192 + inst * 512;
      gload16(src, dst);
    }
  };

  stage(0);
  stage(1);

  for (int b = 0; b < 32; b++) {
    for (int kk = t; kk < chunk; kk += 256) {
      int k = k0 + kk;
      float val = 0.f;
      if (k < ktot) {
        const float* xp; int str; int off;
        if (k < len0)        { xp = x0; str = len0; off = k; }
        else if (k < lenW01) { xp = x1; str = len1; off = k - len0; }
        else                 { xp = x2; str = len2; off = k - lenW01; }
        val = xp[(size_t)b * str + off];
      }
      xl[b * PADK + kk] = f2bf(val);
    }
  }
  __syncthreads();

  f32x4 acc[2][2];
#pragma unroll
  for (int mt = 0; mt < 2; mt++)
#pragma unroll
    for (int nt = 0; nt < 2; nt++)
#pragma unroll
      for (int r = 0; r < 4; r++) acc[mt][nt][r] = 0.f;

  const int lane15 = lane & 15, kg = lane >> 4;

  for (int s = 0; s < nst; s++) {
    if (s + 2 < nst) stage(s + 2);
    int ahead = nst - 1 - s; if (ahead > 2) ahead = 2;
    if (ahead == 2)      asm volatile("s_waitcnt vmcnt(8)");
    else if (ahead == 1) asm volatile("s_waitcnt vmcnt(4)");
    else                 asm volatile("s_waitcnt vmcnt(0)");
    __builtin_amdgcn_s_barrier();
    __builtin_amdgcn_sched_barrier(0);
    const ushort* bb = wlT + (s % 3) * 8192 + kg * 1024 + (wv * 32 + lane15) * 8;
    const ushort* ab = xl + lane15 * PADK + s * 64 + kg * 8;
#pragma unroll
    for (int kh = 0; kh < 2; kh++) {
      short8 b0 = *(const short8*)(bb + kh * 4096);
      short8 b1 = *(const short8*)(bb + kh * 4096 + 128);
      short8 a0 = *(const short8*)(ab + kh * 32);
      short8 a1 = *(const short8*)(ab + kh * 32 + 16 * PADK);
      acc[0][0] = __builtin_amdgcn_mfma_f32_16x16x32_bf16(a0, b0, acc[0][0], 0, 0, 0);
      acc[0][1] = __builtin_amdgcn_mfma_f32_16x16x32_bf16(a0, b1, acc[0][1], 0, 0, 0);
      acc[1][0] = __builtin_amdgcn_mfma_f32_16x16x32_bf16(a1, b0, acc[1][0], 0, 0, 0);
      acc[1][1] = __builtin_amdgcn_mfma_f32_16x16x32_bf16(a1, b1, acc[1][1], 0, 0, 0);
    }
    asm volatile("s_waitcnt lgkmcnt(0)");
    __builtin_amdgcn_sched_barrier(0);
    __builtin_amdgcn_s_barrier();
  }

  int colb = jb * 128 + wv * 32 + lane15;
  int rowb = kg * 4;
#pragma unroll
  for (int mt = 0; mt < 2; mt++)
#pragma unroll
    for (int nt = 0; nt < 2; nt++)
#pragma unroll
      for (int r = 0; r < 4; r++) {
        int b = mt * 16 + rowb + r;
        zp[((size_t)kc * BB + b) * 4096 + colb + nt * 16] = acc[mt][nt][r];
      }
}

__device__ void finish_dev(int b, int q, const float* zpart, const float* bias,
    float* h, float* c, const float* Wq, float* pqp, char* ldsraw)
{
  float* sh  = (float*)ldsraw;
  float* sh2 = sh + 256;
  int t = threadIdx.x;
  int j = q * 256 + t;
  float zi = bias[j], zf = bias[LU + j], zg = bias[2 * LU + j], zo = bias[3 * LU + j];
#pragma unroll
  for (int kc = 0; kc < 8; kc++) {
    const float* zpt = zpart + ((size_t)kc * BB + b) * 4096;
    zi += zpt[j]; zf += zpt[LU + j]; zg += zpt[2 * LU + j]; zo += zpt[3 * LU + j];
  }
  float cn = fsig(zf) * c[b * LU + j] + fsig(zi) * ftanh(zg);
  float hn = fsig(zo) * ftanh(cn);
  c[b * LU + j] = cn;
  h[b * LU + j] = hn;

  if (pqp) {
    sh[t] = hn;
    __syncthreads();
    int a = t & 127, half = t >> 7;
    float acc = 0.f;
    const float* wq = Wq + ((size_t)(q * 256 + half * 128)) * AA + a;
#pragma unroll 4
    for (int jj = 0; jj < 128; jj++) acc += sh[half * 128 + jj] * wq[(size_t)jj * AA];
    sh2[t] = acc;
    __syncthreads();
    if (t < 128) pqp[(size_t)q * BB * AA + b * AA + t] = sh2[t] + sh2[t + 128];
  }
}

__device__ void energy_dev(int tile, int b, const float* keys, const float* pqp,
    const float* M, const float* ast, const float* Wv, const float* bv,
    const int* mlen, float* e, char* ldsraw)
{
  int s0 = tile * 128;
  int ml = mlen[b];
  if (s0 >= ml) return;
  float* astT = (float*)ldsraw;           // 368
  float* Ml4  = astT + 368;               // 31*132
  float* wvp  = Ml4 + 31 * 132;           // 256
  int t = threadIdx.x;
  for (int idx = t; idx < 368; idx += 256) {
    int G = idx >> 3, i = idx & 7;
    int s = s0 + G - 15 + 16 * i;
    astT[idx] = (s >= 0 && s < SS) ? ast[b * SS + s] : 0.f;
  }
  for (int idx = t; idx < KK * AA; idx += 256) {
    int k = idx >> 7, a = idx & 127;
    Ml4[k * 132 + a] = M[idx];
  }
  if (t < 128) wvp[t] = Wv[t];
  else {
    int a = t - 128;
    wvp[128 + a] = pqp[b * AA + a] + pqp[(size_t)BB * AA + b * AA + a]
                 + pqp[(size_t)2 * BB * AA + b * AA + a]
                 + pqp[(size_t)3 * BB * AA + b * AA + a];
  }
  __syncthreads();
  int u = t & 15, g = t >> 4;
  int a0 = u * 8;
  float4 wv0 = *(float4*)&wvp[a0], wv1 = *(float4*)&wvp[a0 + 4];
  float4 pq0 = *(float4*)&wvp[128 + a0], pq1 = *(float4*)&wvp[128 + a0 + 4];
  float arg[8][8];
#pragma unroll
  for (int i = 0; i < 8; i++) {
    int s = s0 + g + 16 * i;
    if (s < SS) {
      const float* kp = keys + ((size_t)b * SS + s) * AA + a0;
      float4 k0 = *(const float4*)kp, k1 = *(const float4*)(kp + 4);
      arg[i][0] = k0.x + pq0.x; arg[i][1] = k0.y + pq0.y;
      arg[i][2] = k0.z + pq0.z; arg[i][3] = k0.w + pq0.w;
      arg[i][4] = k1.x + pq1.x; arg[i][5] = k1.y + pq1.y;
      arg[i][6] = k1.z + pq1.z; arg[i][7] = k1.w + pq1.w;
    } else {
#pragma unroll
      for (int jj = 0; jj < 8; jj++) arg[i][jj] = 0.f;
    }
  }
  for (int k = 0; k < KK; k++) {
    float4 m0 = *(float4*)&Ml4[k * 132 + a0];
    float4 m1 = *(float4*)&Ml4[k * 132 + a0 + 4];
    float4 as0 = *(float4*)&astT[(g + k) * 8];
    float4 as1 = *(float4*)&astT[(g + k) * 8 + 4];
    float asv[8] = {as0.x, as0.y, as0.z, as0.w, as1.x, as1.y, as1.z, as1.w};
#pragma unroll
    for (int i = 0; i < 8; i++) {
      float aw = asv[i];
      arg[i][0] += aw * m0.x; arg[i][1] += aw * m0.y;
      arg[i][2] += aw * m0.z; arg[i][3] += aw * m0.w;
      arg[i][4] += aw * m1.x; arg[i][5] += aw * m1.y;
      arg[i][6] += aw * m1.z; arg[i][7] += aw * m1.w;
    }
  }
  float bvv = bv[0];
#pragma unroll
  for (int i = 0; i < 8; i++) {
    int s = s0 + g + 16 * i;
    float v = ftanh(arg[i][0]) * wv0.x + ftanh(arg[i][1]) * wv0.y
            + ftanh(arg[i][2]) * wv0.z + ftanh(arg[i][3]) * wv0.w
            + ftanh(arg[i][4]) * wv1.x + ftanh(arg[i][5]) * wv1.y
            + ftanh(arg[i][6]) * wv1.z + ftanh(arg[i][7]) * wv1.w;
#pragma unroll
    for (int m = 1; m < 16; m <<= 1) v += __shfl_xor(v, m);
    if (u == 0 && s < SS) e[b * SS + s] = (s < ml) ? (v + bvv) : -1e9f;
  }
}

__device__ void ctxsm_dev(int sc, int b, const float* e, const int* mlen,
    const ushort* mem_bf, float* ast, float* cp, char* ldsraw)
{
  float* red  = (float*)ldsraw;
  float* alsh = red + 4;
  int ml = mlen[b];
  int s0 = sc * 100;
  int cnt = ml - s0; if (cnt > 100) cnt = 100;
  if (cnt <= 0) return;
  int t = threadIdx.x;
  const float* er = e + b * SS;
  float m = -3e38f;
  for (int s = t; s < ml; s += 256) m = fmaxf(m, er[s]);
#pragma unroll
  for (int msk = 1; msk < 64; msk <<= 1) m = fmaxf(m, __shfl_xor(m, msk));
  if ((t & 63) == 0) red[t >> 6] = m;
  __syncthreads();
  m = fmaxf(fmaxf(red[0], red[1]), fmaxf(red[2], red[3]));
  __syncthreads();
  float sum = 0.f;
  for (int s = t; s < ml; s += 256) sum += __expf(er[s] - m);
#pragma unroll
  for (int msk = 1; msk < 64; msk <<= 1) sum += __shfl_xor(sum, msk);
  if ((t & 63) == 0) red[t >> 6] = sum;
  __syncthreads();
  float inv = 1.f / (red[0] + red[1] + red[2] + red[3]);
  if (t < cnt) {
    float a_ = __expf(er[s0 + t] - m) * inv;
    alsh[t] = a_;
    ast[b * SS + s0 + t] += a_;
  }
  __syncthreads();
  float4 acc = make_float4(0.f, 0.f, 0.f, 0.f);
  const ushort* mp = mem_bf + ((size_t)b * SS + s0) * DE + t * 4;
#pragma unroll 4
  for (int i = 0; i < cnt; i++) {
    uint2 v = *(const uint2*)(mp + (size_t)i * DE);
    float a_ = alsh[i];
    acc.x += a_ * bf2f((ushort)(v.x & 0xffff));
    acc.y += a_ * bf2f((ushort)(v.x >> 16));
    acc.z += a_ * bf2f((ushort)(v.y & 0xffff));
    acc.w += a_ * bf2f((ushort)(v.y >> 16));
  }
  *(float4*)&cp[((size_t)sc * BB + b) * DE + t * 4] = acc;
}

__device__ void ctxred_dev(int b, const float* cp, const int* mlen, float* ctx)
{
  int t = threadIdx.x;
  int nsc = (mlen[b] + 99) / 100; if (nsc > 16) nsc = 16;
  float4 acc = make_float4(0.f, 0.f, 0.f, 0.f);
  for (int sc = 0; sc < nsc; sc++) {
    float4 v = *(const float4*)&cp[((size_t)sc * BB + b) * DE + t * 4];
    acc.x += v.x; acc.y += v.y; acc.z += v.z; acc.w += v.w;
  }
  *(float4*)&ctx[b * DE + t * 4] = acc;
}

__device__ void gemv_dev(int jb, int kc,
    const float* x0, int len0, const float* x1, int len1, const float* x2, int len2,
    const float* Wmat, const float* Umat, int N, int chunk, float* zp, char* ldsraw)
{
  float* wl = (float*)ldsraw;            // NBUF*16*256 = 48KB
  float* xl = wl + NBUF * KSTEP * 256;   // 32*256 = 32KB
  int t = threadIdx.x;
  int lane = t & 63;
  int wv = __builtin_amdgcn_readfirstlane(t >> 6);
  int lenW = len0 + len1;
  int k0 = kc * chunk;
  int nst = chunk >> 4;
  int colbase = jb * 256 + lane * 4;
  bool jok = (colbase + 4 <= N);

#pragma unroll
  for (int bi = 0; bi < 8; bi++) {
    int b = wv * 8 + bi;
    for (int kk = lane; kk < chunk; kk += 64) {
      int k = k0 + kk;
      const float* xp; int str; int off;
      if (k < len0)      { xp = x0; str = len0; off = k; }
      else if (k < lenW) { xp = x1; str = len1; off = k - len0; }
      else               { xp = x2; str = len2; off = k - lenW; }
      xl[b * 256 + kk] = xp[(size_t)b * str + off];
    }
  }
  __syncthreads();

  auto stage = [&](int s) {
    int buf = s % NBUF;
    int rbase = k0 + s * KSTEP + wv * 4;
#pragma unroll
    for (int rr = 0; rr < 4; rr++) {
      int r = rbase + rr;
      const float* src = (r < lenW) ? (Wmat + (size_t)r * N + colbase)
                                    : (Umat + (size_t)(r - lenW) * N + colbase);
      float* dst = &wl[(buf * KSTEP + (wv * 4 + rr)) * 256];
      if (jok) gload16(src, dst);
    }
  };

  if (nst > 0) stage(0);
  if (nst > 1) stage(1);

  float acc[8][4];
#pragma unroll
  for (int bi = 0; bi < 8; bi++)
    for (int cc = 0; cc < 4; cc++) acc[bi][cc] = 0.f;

  for (int s = 0; s < nst; s++) {
    if (s + 2 < nst) stage(s + 2);
    int ahead = nst - 1 - s; if (ahead > 2) ahead = 2;
    if (ahead == 2)      asm volatile("s_waitcnt vmcnt(8)");
    else if (ahead == 1) asm volatile("s_waitcnt vmcnt(4)");
    else                 asm volatile("s_waitcnt vmcnt(0)");
    __builtin_amdgcn_s_barrier();
    __builtin_amdgcn_sched_barrier(0);
    const float* wb = &wl[(s % NBUF) * KSTEP * 256];
    int xoff = s * KSTEP;
#pragma unroll
    for (int k4 = 0; k4 < 4; k4++) {
      float4 xv[8];
#pragma unroll
      for (int bi = 0; bi < 8; bi++)
        xv[bi] = *(const float4*)&xl[(wv * 8 + bi) * 256 + xoff + k4 * 4];
#pragma unroll
      for (int kk = 0; kk < 4; kk++) {
        float4 w = *(const float4*)&wb[(k4 * 4 + kk) * 256 + lane * 4];
#pragma unroll
        for (int bi = 0; bi < 8; bi++) {
          float xs = (&xv[bi].x)[kk];
          acc[bi][0] += xs * w.x; acc[bi][1] += xs * w.y;
          acc[bi][2] += xs * w.z; acc[bi][3] += xs * w.w;
        }
      }
    }
    asm volatile("s_waitcnt lgkmcnt(0)");
    __builtin_amdgcn_sched_barrier(0);
    __builtin_amdgcn_s_barrier();
  }

  if (jok) {
#pragma unroll
    for (int bi = 0; bi < 8; bi++) {
      int b = wv * 8 + bi;
      *(float4*)&zp[((size_t)kc * BB + b) * N + colbase] =
          make_float4(acc[bi][0], acc[bi][1], acc[bi][2], acc[bi][3]);
    }
  }
}

__device__ void cls_dev(int b, const float* zpc, const float* bc, const float* h1,
                        const float* Ws, const float* bs, float* out, int ts, char* ldsraw)
{
  float* red = (float*)ldsraw;
  int t = threadIdx.x;
  float sacc = 0.f;
  for (int k = t; k < LU; k += 256) sacc += h1[b * LU + k] * Ws[k];
  float* orow = out + (size_t)b * TT * VV + (size_t)ts * VV;
  for (int v = t; v < VV; v += 256) {
    float acc = bc[v];
#pragma unroll
    for (int kc = 0; kc < KSC; kc++) acc += zpc[((size_t)kc * BB + b) * VV + v];
    orow[v] = acc;
    sacc += acc * Ws[LU + v];
  }
#pragma unroll
  for (int msk = 1; msk < 64; msk <<= 1) sacc += __shfl_xor(sacc, msk);
  if ((t & 63) == 0) red[t >> 6] = sacc;
  __syncthreads();
  if (t == 0) out[(size_t)BB * TT * VV + (size_t)b * TT + ts] =
      red[0] + red[1] + red[2] + red[3] + bs[0];
}

// ---------------- twin combo kernels ----------------

// L1: gemm (A slot) || gemm (B slot) || cls_stp
__global__ __launch_bounds__(256) void k_gg(
    int nA, const float* ax0, int al0, const float* ax1, int al1,
    const float* ax2, int al2, const ushort* aW, int anS, int achunk, float* azp,
    int nB, const float* bx0, int bl0, const float* bx1, int bl1,
    const float* bx2, int bl2, const ushort* bW, int bnS, int bchunk, float* bzp,
    const float* zpc, const float* bc, const float* h1c,
    const float* Ws, const float* bs, float* out, int ts)
{
  __shared__ alignas(16) char lds[74240];
  int bid = blockIdx.x;
  if (bid < nA + nB) {
    bool fst = bid < nA;
    int l = fst ? bid : bid - nA;
    gemm_dev(l >> 3, l & 7,
             fst ? ax0 : bx0, fst ? al0 : bl0,
             fst ? ax1 : bx1, fst ? al1 : bl1,
             fst ? ax2 : bx2, fst ? al2 : bl2,
             fst ? aW : bW, fst ? anS : bnS, fst ? achunk : bchunk,
             fst ? azp : bzp, lds);
  } else {
    cls_dev(bid - nA - nB, zpc, bc, h1c, Ws, bs, out, ts, lds);
  }
}

// L2: finish || finish
__global__ __launch_bounds__(256) void k_ff(
    int n1, const float* z1, const float* bi1, float* h1_, float* c1_,
    const float* Wq1, float* pqp1,
    const float* z2, const float* bi2, float* h2_, float* c2_,
    const float* Wq2, float* pqp2)
{
  __shared__ alignas(16) char lds[4096];
  int bid = blockIdx.x;
  bool fst = bid < n1;
  int l = fst ? bid : bid - n1;
  finish_dev(l >> 2, l & 3,
             fst ? z1 : z2, fst ? bi1 : bi2, fst ? h1_ : h2_, fst ? c1_ : c2_,
             fst ? Wq1 : Wq2, fst ? pqp1 : pqp2, lds);
}

// L3: gemm || energy
__global__ __launch_bounds__(256) void k_ge(
    int n1, const float* gx0, int gl0, const float* gx1, int gl1,
    const float* gx2, int gl2, const ushort* gW, int gnS, int gchunk, float* gzp,
    const float* keys, const float* pqp, const float* M, const float* ast,
    const float* Wv, const float* bv, const int* mlen, float* e)
{
  __shared__ alignas(16) char lds[74240];
  int bid = blockIdx.x;
  if (bid < n1) {
    gemm_dev(bid >> 3, bid & 7, gx0, gl0, gx1, gl1, gx2, gl2,
             gW, gnS, gchunk, gzp, lds);
  } else {
    int l = bid - n1;
    energy_dev(l / 32, l % 32, keys, pqp, M, ast, Wv, bv, mlen, e, lds);
  }
}

// L4: finish || ctx_sm
__global__ __launch_bounds__(256) void k_fs(
    int n1, const float* z1, const float* bi1, float* h1_, float* c1_,
    const float* e, const int* mlen, const ushort* membf, float* ast, float* cp)
{
  __shared__ alignas(16) char lds[4096];
  int bid = blockIdx.x;
  if (bid < n1) {
    finish_dev(bid >> 2, bid & 3, z1, bi1, h1_, c1_, nullptr, nullptr, lds);
  } else {
    int l = bid - n1;
    ctxsm_dev(l >> 5, l & 31, e, mlen, membf, ast, cp, lds);
  }
}

// L5: cls gemv || ctx_red
__global__ __launch_bounds__(256) void k_gr(
    int n1, const float* vx0, int vl0, const float* vx1, int vl1,
    const float* vx2, int vl2, const float* Wm, const float* Um, int N, int vchunk,
    float* vzp, const float* cp, const int* mlen, float* ctxout)
{
  __shared__ alignas(16) char lds[81920];
  int bid = blockIdx.x;
  if (bid < n1) {
    gemv_dev(bid >> 5, bid & 31, vx0, vl0, vx1, vl1, vx2, vl2,
             Wm, Um, N, vchunk, vzp, lds);
  } else {
    ctxred_dev(bid - n1, cp, mlen, ctxout);
  }
}

// ---------------- launcher ----------------

extern "C" void kernel_launch(void* const* d_in, const int* in_sizes, int n_in,
                              void* d_out, int out_size, void* d_ws, size_t ws_size,
                              hipStream_t stream)
{
  const int*   tokens = (const int*)  d_in[0];
  const float* memory = (const float*)d_in[1];
  const int*   mlen   = (const int*)  d_in[2];
  const float* emb    = (const float*)d_in[3];
  const float* Wp1    = (const float*)d_in[4];
  const float* bp1    = (const float*)d_in[5];
  const float* Wp2    = (const float*)d_in[6];
  const float* bp2    = (const float*)d_in[7];
  const float* Wq     = (const float*)d_in[8];
  const float* Wmem   = (const float*)d_in[9];
  const float* convk  = (const float*)d_in[10];
  const float* Wloc   = (const float*)d_in[11];
  const float* Wv     = (const float*)d_in[12];
  const float* bv     = (const float*)d_in[13];
  const float* Wa     = (const float*)d_in[14];
  const float* Ua     = (const float*)d_in[15];
  const float* ba     = (const float*)d_in[16];
  const float* W0     = (const float*)d_in[17];
  const float* U0     = (const float*)d_in[18];
  const float* b0     = (const float*)d_in[19];
  const float* W1     = (const float*)d_in[20];
  const float* U1     = (const float*)d_in[21];
  const float* b1     = (const float*)d_in[22];
  const float* Wc     = (const float*)d_in[23];
  const float* bc     = (const float*)d_in[24];
  const float* Ws     = (const float*)d_in[25];
  const float* bs     = (const float*)d_in[26];
  float* out = (float*)d_out;
  float* ws = (float*)d_ws;

  size_t o = 0;
  float* keys  = ws + o;  o += (size_t)BB * SS * AA;     // 6,553,600
  float* Mv    = ws + o;  o += 4096;
  float* P_all = ws + o;  o += (size_t)TT * BB * PR;     // 2,097,152
  float* st    = ws + o;
  float* h_a = st;
  float* c_a = h_a + BB * LU;
  float* h0  = c_a + BB * LU;
  float* c0  = h0 + BB * LU;
  float* h1  = c0 + BB * LU;
  float* c1  = h1 + BB * LU;
  float* ctx2 = c1 + BB * LU;            // 2 x 32768 (parity)
  float* ast = ctx2 + 2 * BB * DE;
  size_t stcount = (size_t)6 * BB * LU + (size_t)2 * BB * DE + (size_t)BB * SS;
  o += stcount;
  float* pqp  = ws + o;  o += (size_t)4 * BB * AA;
  float* ebuf = ws + o;  o += (size_t)BB * SS;
  float* zpA  = ws + o;  o += (size_t)8 * BB * 4096;
  float* zp0  = ws + o;  o += (size_t)8 * BB * 4096;
  float* zp1  = ws + o;  o += (size_t)8 * BB * 4096;
  float* zpc  = ws + o;  o += (size_t)KSC * BB * VV;
  float* cp   = ws + o;  o += (size_t)16 * BB * DE;
  ushort* membf = (ushort*)(ws + o);  o += (size_t)BB * SS * DE / 2;
  ushort* WUPa  = (ushort*)(ws + o);  o += (size_t)2560 * 4096 / 2;
  ushort* WUP0  = (ushort*)(ws + o);  o += (size_t)3072 * 4096 / 2;
  ushort* WUP1  = (ushort*)(ws + o);  o += (size_t)2048 * 4096 / 2;

  hipMemsetAsync(st, 0, stcount * sizeof(float), stream);
  conv_mem<<<(BB * SS * DE / 4 + 255) / 256, 256, 0, stream>>>(memory, membf,
                                                               BB * SS * DE / 4);
  pack_wu<<<32 * 80 * 4, 256, 0, stream>>>(Wa, Ua, PR + DE, 2304, WUPa, 80);
  pack_wu<<<32 * 96 * 4, 256, 0, stream>>>(W0, U0, LU + DE, 3072, WUP0, 96);
  pack_wu<<<32 * 64 * 4, 256, 0, stream>>>(W1, U1, LU, 2048, WUP1, 64);
  keys_kernel<<<dim3(200, BB), 256, 0, stream>>>(memory, Wmem, keys);
  mconv_kernel<<<KK, AA, 0, stream>>>(convk, Wloc, Mv);
  prenet_all<<<dim3(TT, 2), 256, 0, stream>>>(tokens, emb, Wp1, bp1, Wp2, bp2, P_all);

  // ctx produced at step t lives at ctx2 + (t&1)*BB*DE; step -1 = ctx2+BB*DE (zeroed)
  auto ctx_at = [&](int t) { return ctx2 + (size_t)(t & 1) * BB * DE; };

  // ---- prologue: A(0), Fa(0), E(0), S(0), R(0) ----
  k_gg<<<256, 256, 0, stream>>>(
      0, P_all, PR, ctx_at(1), DE, h_a, LU, WUPa, 80, 320, zpA,
      256, P_all, PR, ctx_at(1), DE, h_a, LU, WUPa, 80, 320, zpA,  // A(0): ctx(-1)=ctx[1]
      zpc, bc, h1, Ws, bs, out, 0);
  k_ff<<<128, 256, 0, stream>>>(
      128, zpA, ba, h_a, c_a, Wq, pqp,
      zpA, ba, h_a, c_a, Wq, pqp);
  k_ge<<<416, 256, 0, stream>>>(
      0, h_a, LU, ctx_at(0), DE, h0, LU, WUP0, 96, 384, zp0,
      keys, pqp, Mv, ast, Wv, bv, mlen, ebuf);
  k_fs<<<512, 256, 0, stream>>>(
      0, zp0, b0, h0, c0,
      ebuf, mlen, membf, ast, cp);
  k_gr<<<32, 256, 0, stream>>>(
      0, h1, LU, ctx_at(0), DE, h1, 0, Wc, Wc, VV, 64, zpc,
      cp, mlen, ctx_at(0));

  // ---- steady loop: t = 0..254 ----
  for (int t = 0; t < TT - 1; t++) {
    int ncls = (t > 0) ? 32 : 0;
    // L1: G0(t) || A(t+1) || cls(t-1)
    k_gg<<<512 + ncls, 256, 0, stream>>>(
        256, h_a, LU, ctx_at(t), DE, h0, LU, WUP0, 96, 384, zp0,
        256, P_all + (size_t)(t + 1) * BB * PR, PR, ctx_at(t), DE, h_a, LU,
        WUPa, 80, 320, zpA,
        zpc, bc, h1, Ws, bs, out, t - 1);
    // L2: F0(t) || Fa(t+1)
    k_ff<<<256, 256, 0, stream>>>(
        128, zp0, b0, h0, c0, nullptr, nullptr,
        zpA, ba, h_a, c_a, Wq, pqp);
    // L3: G1(t) || E(t+1)
    k_ge<<<672, 256, 0, stream>>>(
        256, h0, LU, h1, LU, h0, 0, WUP1, 64, 256, zp1,
        keys, pqp, Mv, ast, Wv, bv, mlen, ebuf);
    // L4: F1(t) || S(t+1)
    k_fs<<<640, 256, 0, stream>>>(
        128, zp1, b1, h1, c1,
        ebuf, mlen, membf, ast, cp);
    // L5: Cgemv(t) || R(t+1)
    k_gr<<<160, 256, 0, stream>>>(
        128, h1, LU, ctx_at(t), DE, h1, 0, Wc, Wc, VV, 64, zpc,
        cp, mlen, ctx_at(t + 1));
  }

  // ---- epilogue: step 255 tail + cls(254), cls(255) ----
  {
    int t = TT - 1;  // 255
    k_gg<<<256 + 32, 256, 0, stream>>>(
        256, h_a, LU, ctx_at(t), DE, h0, LU, WUP0, 96, 384, zp0,
        0, P_all, PR, ctx_at(t), DE, h_a, LU, WUPa, 80, 320, zpA,
        zpc, bc, h1, Ws, bs, out, t - 1);
    k_ff<<<128, 256, 0, stream>>>(
        128, zp0, b0, h0, c0, nullptr, nullptr,
        zp0, b0, h0, c0, nullptr, nullptr);
    k_ge<<<256, 256, 0, stream>>>(
        256, h0, LU, h1, LU, h0, 0, WUP1, 64, 256, zp1,
        keys, pqp, Mv, ast, Wv, bv, mlen, ebuf);
    k_fs<<<128, 256, 0, stream>>>(
        128, zp1, b1, h1, c1,
        ebuf, mlen, membf, ast, cp);
    k_gr<<<128, 256, 0, stream>>>(
        128, h1, LU, ctx_at(t), DE, h1, 0, Wc, Wc, VV, 64, zpc,
        cp, mlen, ctx_at(t + 1));
    k_gg<<<32, 256, 0, stream>>>(
        0, h_a, LU, ctx_at(t), DE, h0, LU, WUP0, 96, 384, zp0,
        0, P_all, PR, ctx_at(t), DE, h_a, LU, WUPa, 80, 320, zpA,
        zpc, bc, h1, Ws, bs, out, t);
  }
}

// Round 13
// 25535.324 us; speedup vs baseline: 4.6667x; 1.0739x over previous
//
#include <hip/hip_runtime.h>

#define BB 32
#define TT 256
#define SS 1600
#define DE 1024
#define VV 1000
#define EM 512
#define PR 256
#define LU 1024
#define AA 128
#define FF 32
#define KK 31
#define KSC 32
#define KSTEP 16
#define NBUF 3

typedef __attribute__((ext_vector_type(8))) short short8;
typedef __attribute__((ext_vector_type(4))) float f32x4;

__device__ __forceinline__ float bf2f(ushort u) {
  unsigned int x = ((unsigned int)u) << 16;
  return __builtin_bit_cast(float, x);
}
__device__ __forceinline__ ushort f2bf(float f) {
  unsigned int x = __builtin_bit_cast(unsigned int, f);
  return (ushort)((x + 0x7FFFu + ((x >> 16) & 1u)) >> 16);
}
__device__ __forceinline__ void gload16(const void* g, void* l) {
  __builtin_amdgcn_global_load_lds(
      (const __attribute__((address_space(1))) void*)g,
      (__attribute__((address_space(3))) void*)l, 16, 0, 0);
}
__device__ __forceinline__ float ftanh(float x) {
  float e = __expf(2.f * x);
  return 1.f - 2.f / (e + 1.f);
}
__device__ __forceinline__ float fsig(float x) {
  return 1.f / (1.f + __expf(-x));
}

// ---------------- once-per-call precompute (r12 verbatim) ----------------

__global__ __launch_bounds__(256) void conv_mem(const float* __restrict__ in,
                                                ushort* __restrict__ out, int n4)
{
  int i = blockIdx.x * 256 + threadIdx.x;
  if (i < n4) {
    float4 v = *(const float4*)(in + (size_t)i * 4);
    ushort4 o;
    o.x = f2bf(v.x); o.y = f2bf(v.y); o.z = f2bf(v.z); o.w = f2bf(v.w);
    *(ushort4*)(out + (size_t)i * 4) = o;
  }
}

__global__ __launch_bounds__(256) void pack_wu(const float* __restrict__ Wm,
    const float* __restrict__ Um, int lenW, int ktot, ushort* __restrict__ out, int nS)
{
  int bid = blockIdx.x;
  int kg = bid & 3, S = (bid >> 2) % nS, jb = (bid >> 2) / nS;
  int t = threadIdx.x;
  int c = t >> 1, e4 = (t & 1) * 4;
  int kbase = S * 32 + kg * 8 + e4;
  int j = jb * 128 + c;
  ushort* op = out + ((size_t)(jb * nS + S) * 4 + kg) * 1024 + c * 8 + e4;
#pragma unroll
  for (int i = 0; i < 4; i++) {
    int k = kbase + i;
    float v = 0.f;
    if (k < lenW)      v = Wm[(size_t)k * 4096 + j];
    else if (k < ktot) v = Um[(size_t)(k - lenW) * 4096 + j];
    op[i] = f2bf(v);
  }
}

__global__ __launch_bounds__(256) void keys_kernel(const float* __restrict__ mem,
                                                   const float* __restrict__ Wmem,
                                                   float* __restrict__ keys)
{
  int stile = blockIdx.x;
  int b = blockIdx.y;
  int t = threadIdx.x;
  __shared__ float Xt[8 * 1032];
  const float* mp = mem + ((size_t)b * SS + (size_t)stile * 8) * DE;
  for (int li = t; li < 8 * 256; li += 256) {
    int row = li >> 8, c4 = li & 255;
    float4 v = *(const float4*)(mp + row * DE + c4 * 4);
    *(float4*)(Xt + row * 1032 + c4 * 4) = v;
  }
  __syncthreads();
  int sl = t >> 5, u = t & 31;
  float acc[4] = {0.f, 0.f, 0.f, 0.f};
  for (int k = 0; k < DE; k++) {
    float x = Xt[sl * 1032 + k];
    const float* wr = Wmem + k * AA;
#pragma unroll
    for (int jj = 0; jj < 4; jj++) acc[jj] += x * wr[u + 32 * jj];
  }
  float* kp = keys + ((size_t)b * SS + (size_t)stile * 8 + sl) * AA;
#pragma unroll
  for (int jj = 0; jj < 4; jj++) kp[u + 32 * jj] = acc[jj];
}

__global__ void mconv_kernel(const float* __restrict__ ck, const float* __restrict__ Wloc,
                             float* __restrict__ M)
{
  int a = threadIdx.x;
  int k = blockIdx.x;
  float acc = 0.f;
  for (int c = 0; c < FF; c++) acc += ck[k * FF + c] * Wloc[c * AA + a];
  M[k * AA + a] = acc;
}

__global__ __launch_bounds__(256) void prenet_all(const int* __restrict__ tokens,
    const float* __restrict__ emb, const float* __restrict__ Wp1, const float* __restrict__ bp1,
    const float* __restrict__ Wp2, const float* __restrict__ bp2, float* __restrict__ P)
{
  int tstep = blockIdx.x;
  int bh = blockIdx.y;
  int t = threadIdx.x;
  __shared__ float X[16 * 512];
  __shared__ float P1[16 * 256];
  for (int li = t; li < 16 * 128; li += 256) {
    int bb = li >> 7, c4 = li & 127;
    int tok = tokens[(bh * 16 + bb) * TT + tstep];
    *(float4*)(X + bb * 512 + c4 * 4) = *(const float4*)(emb + (size_t)tok * EM + c4 * 4);
  }
  __syncthreads();
  int j = t;
  float acc[16];
#pragma unroll
  for (int i = 0; i < 16; i++) acc[i] = 0.f;
  for (int k = 0; k < EM; k++) {
    float w = Wp1[k * PR + j];
#pragma unroll
    for (int i = 0; i < 16; i++) acc[i] += X[i * 512 + k] * w;
  }
#pragma unroll
  for (int i = 0; i < 16; i++) P1[i * 256 + j] = fmaxf(acc[i] + bp1[j], 0.f);
  __syncthreads();
#pragma unroll
  for (int i = 0; i < 16; i++) acc[i] = 0.f;
  for (int k = 0; k < PR; k++) {
    float w = Wp2[k * PR + j];
#pragma unroll
    for (int i = 0; i < 16; i++) acc[i] += P1[i * 256 + k] * w;
  }
  float* outp = P + (size_t)tstep * BB * PR + (size_t)bh * 16 * PR;
#pragma unroll
  for (int i = 0; i < 16; i++) outp[i * PR + j] = fmaxf(acc[i] + bp2[j], 0.f);
}

// ---------------- device bodies (r12 verbatim except noted) ----------------

__device__ void gemm_dev(int jb, int kc,
    const float* x0, int len0, const float* x1, int len1, const float* x2, int len2,
    const ushort* WUP, int nS, int chunk, float* zp, char* ldsraw)
{
  ushort* wlT = (ushort*)ldsraw;
  ushort* xl  = (ushort*)(ldsraw + 49152);
  const int t = threadIdx.x;
  const int lane = t & 63;
  const int wv = __builtin_amdgcn_readfirstlane(t >> 6);
  const int PADK = chunk + 8;
  const int nst = chunk >> 6;
  const int k0 = kc * chunk;
  const int S0 = k0 >> 5;
  const size_t jbS = (size_t)jb * nS;
  const int lenW01 = len0 + len1;
  const int ktot = lenW01 + len2;

  auto stage = [&](int s) {
    int buf = s % 3;
    int Sb = S0 + s * 2;
#pragma unroll
    for (int sub = 0; sub < 4; sub++) {
      int inst = wv * 4 + sub;
      const ushort* src = WUP + (jbS + Sb + (inst >> 3)) * 4096
                        + (size_t)(((inst & 7) * 64 + lane) * 8);
      ushort* dst = wlT + buf * 8192 + inst * 512;
      gload16(src, dst);
    }
  };

  stage(0);
  stage(1);

  for (int b = 0; b < 32; b++) {
    for (int kk = t; kk < chunk; kk += 256) {
      int k = k0 + kk;
      float val = 0.f;
      if (k < ktot) {
        const float* xp; int str; int off;
        if (k < len0)        { xp = x0; str = len0; off = k; }
        else if (k < lenW01) { xp = x1; str = len1; off = k - len0; }
        else                 { xp = x2; str = len2; off = k - lenW01; }
        val = xp[(size_t)b * str + off];
      }
      xl[b * PADK + kk] = f2bf(val);
    }
  }
  __syncthreads();

  f32x4 acc[2][2];
#pragma unroll
  for (int mt = 0; mt < 2; mt++)
#pragma unroll
    for (int nt = 0; nt < 2; nt++)
#pragma unroll
      for (int r = 0; r < 4; r++) acc[mt][nt][r] = 0.f;

  const int lane15 = lane & 15, kg = lane >> 4;

  for (int s = 0; s < nst; s++) {
    if (s + 2 < nst) stage(s + 2);
    int ahead = nst - 1 - s; if (ahead > 2) ahead = 2;
    if (ahead == 2)      asm volatile("s_waitcnt vmcnt(8)");
    else if (ahead == 1) asm volatile("s_waitcnt vmcnt(4)");
    else                 asm volatile("s_waitcnt vmcnt(0)");
    __builtin_amdgcn_s_barrier();
    __builtin_amdgcn_sched_barrier(0);
    const ushort* bb = wlT + (s % 3) * 8192 + kg * 1024 + (wv * 32 + lane15) * 8;
    const ushort* ab = xl + lane15 * PADK + s * 64 + kg * 8;
#pragma unroll
    for (int kh = 0; kh < 2; kh++) {
      short8 b0 = *(const short8*)(bb + kh * 4096);
      short8 b1 = *(const short8*)(bb + kh * 4096 + 128);
      short8 a0 = *(const short8*)(ab + kh * 32);
      short8 a1 = *(const short8*)(ab + kh * 32 + 16 * PADK);
      acc[0][0] = __builtin_amdgcn_mfma_f32_16x16x32_bf16(a0, b0, acc[0][0], 0, 0, 0);
      acc[0][1] = __builtin_amdgcn_mfma_f32_16x16x32_bf16(a0, b1, acc[0][1], 0, 0, 0);
      acc[1][0] = __builtin_amdgcn_mfma_f32_16x16x32_bf16(a1, b0, acc[1][0], 0, 0, 0);
      acc[1][1] = __builtin_amdgcn_mfma_f32_16x16x32_bf16(a1, b1, acc[1][1], 0, 0, 0);
    }
    asm volatile("s_waitcnt lgkmcnt(0)");
    __builtin_amdgcn_sched_barrier(0);
    __builtin_amdgcn_s_barrier();
  }

  int colb = jb * 128 + wv * 32 + lane15;
  int rowb = kg * 4;
#pragma unroll
  for (int mt = 0; mt < 2; mt++)
#pragma unroll
    for (int nt = 0; nt < 2; nt++)
#pragma unroll
      for (int r = 0; r < 4; r++) {
        int b = mt * 16 + rowb + r;
        zp[((size_t)kc * BB + b) * 4096 + colb + nt * 16] = acc[mt][nt][r];
      }
}

__device__ void finish_dev(int b, int q, const float* zpart, const float* bias,
    float* h, float* c, const float* Wq, float* pqp, char* ldsraw)
{
  float* sh  = (float*)ldsraw;
  float* sh2 = sh + 256;
  int t = threadIdx.x;
  int j = q * 256 + t;
  float zi = bias[j], zf = bias[LU + j], zg = bias[2 * LU + j], zo = bias[3 * LU + j];
#pragma unroll
  for (int kc = 0; kc < 8; kc++) {
    const float* zpt = zpart + ((size_t)kc * BB + b) * 4096;
    zi += zpt[j]; zf += zpt[LU + j]; zg += zpt[2 * LU + j]; zo += zpt[3 * LU + j];
  }
  float cn = fsig(zf) * c[b * LU + j] + fsig(zi) * ftanh(zg);
  float hn = fsig(zo) * ftanh(cn);
  c[b * LU + j] = cn;
  h[b * LU + j] = hn;

  if (pqp) {
    sh[t] = hn;
    __syncthreads();
    int a = t & 127, half = t >> 7;
    float acc = 0.f;
    const float* wq = Wq + ((size_t)(q * 256 + half * 128)) * AA + a;
#pragma unroll 4
    for (int jj = 0; jj < 128; jj++) acc += sh[half * 128 + jj] * wq[(size_t)jj * AA];
    sh2[t] = acc;
    __syncthreads();
    if (t < 128) pqp[(size_t)q * BB * AA + b * AA + t] = sh2[t] + sh2[t + 128];
  }
}

__device__ void energy_dev(int tile, int b, const float* keys, const float* pqp,
    const float* M, const float* ast, const float* Wv, const float* bv,
    const int* mlen, float* e, char* ldsraw)
{
  int s0 = tile * 128;
  int ml = mlen[b];
  if (s0 >= ml) return;
  float* astT = (float*)ldsraw;
  float* Ml4  = astT + 368;
  float* wvp  = Ml4 + 31 * 132;
  int t = threadIdx.x;
  for (int idx = t; idx < 368; idx += 256) {
    int G = idx >> 3, i = idx & 7;
    int s = s0 + G - 15 + 16 * i;
    astT[idx] = (s >= 0 && s < SS) ? ast[b * SS + s] : 0.f;
  }
  for (int idx = t; idx < KK * AA; idx += 256) {
    int k = idx >> 7, a = idx & 127;
    Ml4[k * 132 + a] = M[idx];
  }
  if (t < 128) wvp[t] = Wv[t];
  else {
    int a = t - 128;
    wvp[128 + a] = pqp[b * AA + a] + pqp[(size_t)BB * AA + b * AA + a]
                 + pqp[(size_t)2 * BB * AA + b * AA + a]
                 + pqp[(size_t)3 * BB * AA + b * AA + a];
  }
  __syncthreads();
  int u = t & 15, g = t >> 4;
  int a0 = u * 8;
  float4 wv0 = *(float4*)&wvp[a0], wv1 = *(float4*)&wvp[a0 + 4];
  float4 pq0 = *(float4*)&wvp[128 + a0], pq1 = *(float4*)&wvp[128 + a0 + 4];
  float arg[8][8];
#pragma unroll
  for (int i = 0; i < 8; i++) {
    int s = s0 + g + 16 * i;
    if (s < SS) {
      const float* kp = keys + ((size_t)b * SS + s) * AA + a0;
      float4 k0 = *(const float4*)kp, k1 = *(const float4*)(kp + 4);
      arg[i][0] = k0.x + pq0.x; arg[i][1] = k0.y + pq0.y;
      arg[i][2] = k0.z + pq0.z; arg[i][3] = k0.w + pq0.w;
      arg[i][4] = k1.x + pq1.x; arg[i][5] = k1.y + pq1.y;
      arg[i][6] = k1.z + pq1.z; arg[i][7] = k1.w + pq1.w;
    } else {
#pragma unroll
      for (int jj = 0; jj < 8; jj++) arg[i][jj] = 0.f;
    }
  }
  for (int k = 0; k < KK; k++) {
    float4 m0 = *(float4*)&Ml4[k * 132 + a0];
    float4 m1 = *(float4*)&Ml4[k * 132 + a0 + 4];
    float4 as0 = *(float4*)&astT[(g + k) * 8];
    float4 as1 = *(float4*)&astT[(g + k) * 8 + 4];
    float asv[8] = {as0.x, as0.y, as0.z, as0.w, as1.x, as1.y, as1.z, as1.w};
#pragma unroll
    for (int i = 0; i < 8; i++) {
      float aw = asv[i];
      arg[i][0] += aw * m0.x; arg[i][1] += aw * m0.y;
      arg[i][2] += aw * m0.z; arg[i][3] += aw * m0.w;
      arg[i][4] += aw * m1.x; arg[i][5] += aw * m1.y;
      arg[i][6] += aw * m1.z; arg[i][7] += aw * m1.w;
    }
  }
  float bvv = bv[0];
#pragma unroll
  for (int i = 0; i < 8; i++) {
    int s = s0 + g + 16 * i;
    float v = ftanh(arg[i][0]) * wv0.x + ftanh(arg[i][1]) * wv0.y
            + ftanh(arg[i][2]) * wv0.z + ftanh(arg[i][3]) * wv0.w
            + ftanh(arg[i][4]) * wv1.x + ftanh(arg[i][5]) * wv1.y
            + ftanh(arg[i][6]) * wv1.z + ftanh(arg[i][7]) * wv1.w;
#pragma unroll
    for (int m = 1; m < 16; m <<= 1) v += __shfl_xor(v, m);
    if (u == 0 && s < SS) e[b * SS + s] = (s < ml) ? (v + bvv) : -1e9f;
  }
}

// softmax + ast + DIRECT atomic ctx accumulation (8 sc-chunks of 200 rows)
__device__ void ctxsm_atomic_dev(int sc, int b, const float* e, const int* mlen,
    const ushort* mem_bf, float* ast, float* ctx, char* ldsraw)
{
  float* red  = (float*)ldsraw;
  float* alsh = red + 4;
  int ml = mlen[b];
  int s0 = sc * 200;
  int cnt = ml - s0; if (cnt > 200) cnt = 200;
  if (cnt <= 0) return;
  int t = threadIdx.x;
  const float* er = e + b * SS;
  float m = -3e38f;
  for (int s = t; s < ml; s += 256) m = fmaxf(m, er[s]);
#pragma unroll
  for (int msk = 1; msk < 64; msk <<= 1) m = fmaxf(m, __shfl_xor(m, msk));
  if ((t & 63) == 0) red[t >> 6] = m;
  __syncthreads();
  m = fmaxf(fmaxf(red[0], red[1]), fmaxf(red[2], red[3]));
  __syncthreads();
  float sum = 0.f;
  for (int s = t; s < ml; s += 256) sum += __expf(er[s] - m);
#pragma unroll
  for (int msk = 1; msk < 64; msk <<= 1) sum += __shfl_xor(sum, msk);
  if ((t & 63) == 0) red[t >> 6] = sum;
  __syncthreads();
  float inv = 1.f / (red[0] + red[1] + red[2] + red[3]);
  if (t < cnt) {
    float a_ = __expf(er[s0 + t] - m) * inv;
    alsh[t] = a_;
    ast[b * SS + s0 + t] += a_;
  }
  __syncthreads();
  float4 acc = make_float4(0.f, 0.f, 0.f, 0.f);
  const ushort* mp = mem_bf + ((size_t)b * SS + s0) * DE + t * 4;
#pragma unroll 4
  for (int i = 0; i < cnt; i++) {
    uint2 v = *(const uint2*)(mp + (size_t)i * DE);
    float a_ = alsh[i];
    acc.x += a_ * bf2f((ushort)(v.x & 0xffff));
    acc.y += a_ * bf2f((ushort)(v.x >> 16));
    acc.z += a_ * bf2f((ushort)(v.y & 0xffff));
    acc.w += a_ * bf2f((ushort)(v.y >> 16));
  }
  float* cpx = ctx + b * DE + t * 4;
  atomicAdd(cpx + 0, acc.x);
  atomicAdd(cpx + 1, acc.y);
  atomicAdd(cpx + 2, acc.z);
  atomicAdd(cpx + 3, acc.w);
}

// fp32 gemv, 2-deep ring (64 KB LDS so twin kernels keep 2 blocks/CU)
__device__ void gemv2_dev(int jb, int kc,
    const float* x0, int len0, const float* x1, int len1, const float* x2, int len2,
    const float* Wmat, const float* Umat, int N, int chunk, float* zp, char* ldsraw)
{
  float* wl = (float*)ldsraw;            // 2*16*256 = 32KB
  float* xl = wl + 2 * KSTEP * 256;      // 32*256 = 32KB
  int t = threadIdx.x;
  int lane = t & 63;
  int wv = __builtin_amdgcn_readfirstlane(t >> 6);
  int lenW = len0 + len1;
  int k0 = kc * chunk;
  int nst = chunk >> 4;
  int colbase = jb * 256 + lane * 4;
  bool jok = (colbase + 4 <= N);

#pragma unroll
  for (int bi = 0; bi < 8; bi++) {
    int b = wv * 8 + bi;
    for (int kk = lane; kk < chunk; kk += 64) {
      int k = k0 + kk;
      const float* xp; int str; int off;
      if (k < len0)      { xp = x0; str = len0; off = k; }
      else if (k < lenW) { xp = x1; str = len1; off = k - len0; }
      else               { xp = x2; str = len2; off = k - lenW; }
      xl[b * 256 + kk] = xp[(size_t)b * str + off];
    }
  }
  __syncthreads();

  auto stage = [&](int s) {
    int buf = s & 1;
    int rbase = k0 + s * KSTEP + wv * 4;
#pragma unroll
    for (int rr = 0; rr < 4; rr++) {
      int r = rbase + rr;
      const float* src = (r < lenW) ? (Wmat + (size_t)r * N + colbase)
                                    : (Umat + (size_t)(r - lenW) * N + colbase);
      float* dst = &wl[(buf * KSTEP + (wv * 4 + rr)) * 256];
      if (jok) gload16(src, dst);
    }
  };

  if (nst > 0) stage(0);

  float acc[8][4];
#pragma unroll
  for (int bi = 0; bi < 8; bi++)
    for (int cc = 0; cc < 4; cc++) acc[bi][cc] = 0.f;

  for (int s = 0; s < nst; s++) {
    if (s + 1 < nst) { stage(s + 1); asm volatile("s_waitcnt vmcnt(4)"); }
    else             { asm volatile("s_waitcnt vmcnt(0)"); }
    __builtin_amdgcn_s_barrier();
    __builtin_amdgcn_sched_barrier(0);
    const float* wb = &wl[(s & 1) * KSTEP * 256];
    int xoff = s * KSTEP;
#pragma unroll
    for (int k4 = 0; k4 < 4; k4++) {
      float4 xv[8];
#pragma unroll
      for (int bi = 0; bi < 8; bi++)
        xv[bi] = *(const float4*)&xl[(wv * 8 + bi) * 256 + xoff + k4 * 4];
#pragma unroll
      for (int kk = 0; kk < 4; kk++) {
        float4 w = *(const float4*)&wb[(k4 * 4 + kk) * 256 + lane * 4];
#pragma unroll
        for (int bi = 0; bi < 8; bi++) {
          float xs = (&xv[bi].x)[kk];
          acc[bi][0] += xs * w.x; acc[bi][1] += xs * w.y;
          acc[bi][2] += xs * w.z; acc[bi][3] += xs * w.w;
        }
      }
    }
    asm volatile("s_waitcnt lgkmcnt(0)");
    __builtin_amdgcn_sched_barrier(0);
    __builtin_amdgcn_s_barrier();
  }

  if (jok) {
#pragma unroll
    for (int bi = 0; bi < 8; bi++) {
      int b = wv * 8 + bi;
      *(float4*)&zp[((size_t)kc * BB + b) * N + colbase] =
          make_float4(acc[bi][0], acc[bi][1], acc[bi][2], acc[bi][3]);
    }
  }
}

__device__ void cls_dev(int b, const float* zpc, const float* bc, const float* h1,
                        const float* Ws, const float* bs, float* out, int ts, char* ldsraw)
{
  float* red = (float*)ldsraw;
  int t = threadIdx.x;
  float sacc = 0.f;
  for (int k = t; k < LU; k += 256) sacc += h1[b * LU + k] * Ws[k];
  float* orow = out + (size_t)b * TT * VV + (size_t)ts * VV;
  for (int v = t; v < VV; v += 256) {
    float acc = bc[v];
#pragma unroll
    for (int kc = 0; kc < KSC; kc++) acc += zpc[((size_t)kc * BB + b) * VV + v];
    orow[v] = acc;
    sacc += acc * Ws[LU + v];
  }
#pragma unroll
  for (int msk = 1; msk < 64; msk <<= 1) sacc += __shfl_xor(sacc, msk);
  if ((t & 63) == 0) red[t >> 6] = sacc;
  __syncthreads();
  if (t == 0) out[(size_t)BB * TT * VV + (size_t)b * TT + ts] =
      red[0] + red[1] + red[2] + red[3] + bs[0];
}

// ---------------- combo kernels (4-launch schedule) ----------------

// L1: gemm || gemm
__global__ __launch_bounds__(256) void k_gg(
    int nA, const float* ax0, int al0, const float* ax1, int al1,
    const float* ax2, int al2, const ushort* aW, int anS, int achunk, float* azp,
    int nB, const float* bx0, int bl0, const float* bx1, int bl1,
    const float* bx2, int bl2, const ushort* bW, int bnS, int bchunk, float* bzp)
{
  __shared__ alignas(16) char lds[74240];
  int bid = blockIdx.x;
  bool fst = bid < nA;
  int l = fst ? bid : bid - nA;
  gemm_dev(l >> 3, l & 7,
           fst ? ax0 : bx0, fst ? al0 : bl0,
           fst ? ax1 : bx1, fst ? al1 : bl1,
           fst ? ax2 : bx2, fst ? al2 : bl2,
           fst ? aW : bW, fst ? anS : bnS, fst ? achunk : bchunk,
           fst ? azp : bzp, lds);
}

// L2: finish(F0) || finish(Fa+pq) || gemv(cls)
__global__ __launch_bounds__(256) void k_ffg(
    int nf0, const float* z0, const float* bi0, float* h0p, float* c0p,
    int nf1, const float* z1, const float* bi1, float* h1p, float* c1p,
    const float* Wq, float* pqp,
    int ng, const float* vx0, int vl0, const float* vx1, int vl1,
    const float* vx2, int vl2, const float* Wm, const float* Um, int N, int vchunk,
    float* vzp)
{
  __shared__ alignas(16) char lds[65536];
  int bid = blockIdx.x;
  if (bid < nf0) {
    finish_dev(bid >> 2, bid & 3, z0, bi0, h0p, c0p, nullptr, nullptr, lds);
  } else if (bid < nf0 + nf1) {
    int l = bid - nf0;
    finish_dev(l >> 2, l & 3, z1, bi1, h1p, c1p, Wq, pqp, lds);
  } else {
    int l = bid - nf0 - nf1;
    gemv2_dev(l >> 5, l & 31, vx0, vl0, vx1, vl1, vx2, vl2,
              Wm, Um, N, vchunk, vzp, lds);
  }
}

// L3: gemm(G1) || energy || cls || ctx-zero
__global__ __launch_bounds__(256) void k_gec(
    int nG, const float* gx0, int gl0, const float* gx1, int gl1,
    const float* gx2, int gl2, const ushort* gW, int gnS, int gchunk, float* gzp,
    int nE, const float* keys, const float* pqp, const float* M, const float* ast,
    const float* Wv, const float* bv, const int* mlen, float* e,
    int nC, const float* zpc, const float* bc, const float* h1c,
    const float* Ws, const float* bs, float* out, int ts,
    int nZ, float* zctx)
{
  __shared__ alignas(16) char lds[74240];
  int bid = blockIdx.x;
  if (bid < nG) {
    gemm_dev(bid >> 3, bid & 7, gx0, gl0, gx1, gl1, gx2, gl2,
             gW, gnS, gchunk, gzp, lds);
  } else if (bid < nG + nE) {
    int l = bid - nG;
    energy_dev(l / 32, l % 32, keys, pqp, M, ast, Wv, bv, mlen, e, lds);
  } else if (bid < nG + nE + nC) {
    cls_dev(bid - nG - nE, zpc, bc, h1c, Ws, bs, out, ts, lds);
  } else {
    int b = bid - nG - nE - nC;
    *(float4*)&zctx[b * DE + threadIdx.x * 4] = make_float4(0.f, 0.f, 0.f, 0.f);
  }
}

// L4: finish(F1) || softmax+ctx-atomic
__global__ __launch_bounds__(256) void k_fsa(
    int nF, const float* z1, const float* bi1, float* h1p, float* c1p,
    int nS, const float* e, const int* mlen, const ushort* membf,
    float* ast, float* ctx)
{
  __shared__ alignas(16) char lds[8192];
  int bid = blockIdx.x;
  if (bid < nF) {
    finish_dev(bid >> 2, bid & 3, z1, bi1, h1p, c1p, nullptr, nullptr, lds);
  } else {
    int l = bid - nF;
    ctxsm_atomic_dev(l >> 5, l & 31, e, mlen, membf, ast, ctx, lds);
  }
}

// ---------------- launcher ----------------

extern "C" void kernel_launch(void* const* d_in, const int* in_sizes, int n_in,
                              void* d_out, int out_size, void* d_ws, size_t ws_size,
                              hipStream_t stream)
{
  const int*   tokens = (const int*)  d_in[0];
  const float* memory = (const float*)d_in[1];
  const int*   mlen   = (const int*)  d_in[2];
  const float* emb    = (const float*)d_in[3];
  const float* Wp1    = (const float*)d_in[4];
  const float* bp1    = (const float*)d_in[5];
  const float* Wp2    = (const float*)d_in[6];
  const float* bp2    = (const float*)d_in[7];
  const float* Wq     = (const float*)d_in[8];
  const float* Wmem   = (const float*)d_in[9];
  const float* convk  = (const float*)d_in[10];
  const float* Wloc   = (const float*)d_in[11];
  const float* Wv     = (const float*)d_in[12];
  const float* bv     = (const float*)d_in[13];
  const float* Wa     = (const float*)d_in[14];
  const float* Ua     = (const float*)d_in[15];
  const float* ba     = (const float*)d_in[16];
  const float* W0     = (const float*)d_in[17];
  const float* U0     = (const float*)d_in[18];
  const float* b0     = (const float*)d_in[19];
  const float* W1     = (const float*)d_in[20];
  const float* U1     = (const float*)d_in[21];
  const float* b1     = (const float*)d_in[22];
  const float* Wc     = (const float*)d_in[23];
  const float* bc     = (const float*)d_in[24];
  const float* Ws     = (const float*)d_in[25];
  const float* bs     = (const float*)d_in[26];
  float* out = (float*)d_out;
  float* ws = (float*)d_ws;

  size_t o = 0;
  float* keys  = ws + o;  o += (size_t)BB * SS * AA;
  float* Mv    = ws + o;  o += 4096;
  float* P_all = ws + o;  o += (size_t)TT * BB * PR;
  float* st    = ws + o;
  float* h_a = st;
  float* c_a = h_a + BB * LU;
  float* h0  = c_a + BB * LU;
  float* c0  = h0 + BB * LU;
  float* h1  = c0 + BB * LU;
  float* c1  = h1 + BB * LU;
  float* ctx2 = c1 + BB * LU;            // 2 x 32768 (parity)
  float* ast = ctx2 + 2 * BB * DE;
  size_t stcount = (size_t)6 * BB * LU + (size_t)2 * BB * DE + (size_t)BB * SS;
  o += stcount;
  float* pqp  = ws + o;  o += (size_t)4 * BB * AA;
  float* ebuf = ws + o;  o += (size_t)BB * SS;
  float* zpA  = ws + o;  o += (size_t)8 * BB * 4096;
  float* zp0  = ws + o;  o += (size_t)8 * BB * 4096;
  float* zp1  = ws + o;  o += (size_t)8 * BB * 4096;
  float* zpc  = ws + o;  o += (size_t)KSC * BB * VV;
  ushort* membf = (ushort*)(ws + o);  o += (size_t)BB * SS * DE / 2;
  ushort* WUPa  = (ushort*)(ws + o);  o += (size_t)2560 * 4096 / 2;
  ushort* WUP0  = (ushort*)(ws + o);  o += (size_t)3072 * 4096 / 2;
  ushort* WUP1  = (ushort*)(ws + o);  o += (size_t)2048 * 4096 / 2;

  hipMemsetAsync(st, 0, stcount * sizeof(float), stream);
  conv_mem<<<(BB * SS * DE / 4 + 255) / 256, 256, 0, stream>>>(memory, membf,
                                                               BB * SS * DE / 4);
  pack_wu<<<32 * 80 * 4, 256, 0, stream>>>(Wa, Ua, PR + DE, 2304, WUPa, 80);
  pack_wu<<<32 * 96 * 4, 256, 0, stream>>>(W0, U0, LU + DE, 3072, WUP0, 96);
  pack_wu<<<32 * 64 * 4, 256, 0, stream>>>(W1, U1, LU, 2048, WUP1, 64);
  keys_kernel<<<dim3(200, BB), 256, 0, stream>>>(memory, Wmem, keys);
  mconv_kernel<<<KK, AA, 0, stream>>>(convk, Wloc, Mv);
  prenet_all<<<dim3(TT, 2), 256, 0, stream>>>(tokens, emb, Wp1, bp1, Wp2, bp2, P_all);

  auto ctx_at = [&](int t) { return ctx2 + (size_t)(t & 1) * BB * DE; };

  // ---- prologue: A(0), Fa(0), E(0), S(0) ----
  // ctx(-1) = ctx2[1] (zeroed); ctx(0) target = ctx2[0] (zeroed)
  k_gg<<<256, 256, 0, stream>>>(
      0, P_all, PR, ctx2 + BB * DE, DE, h_a, LU, WUPa, 80, 320, zpA,
      256, P_all, PR, ctx2 + BB * DE, DE, h_a, LU, WUPa, 80, 320, zpA);
  k_ffg<<<128, 256, 0, stream>>>(
      0, zpA, ba, h_a, c_a,
      128, zpA, ba, h_a, c_a, Wq, pqp,
      0, h1, LU, ctx2, DE, h1, 0, Wc, Wc, VV, 64, zpc);
  k_gec<<<416, 256, 0, stream>>>(
      0, h_a, LU, ctx2, DE, h0, LU, WUP0, 96, 384, zp0,
      416, keys, pqp, Mv, ast, Wv, bv, mlen, ebuf,
      0, zpc, bc, h1, Ws, bs, out, 0,
      0, ctx2);
  k_fsa<<<256, 256, 0, stream>>>(
      0, zp1, b1, h1, c1,
      256, ebuf, mlen, membf, ast, ctx_at(0));

  // ---- steady loop: i = 0..254 ----
  for (int i = 0; i < TT - 1; i++) {
    int ng  = (i > 0) ? 128 : 0;   // Cgemv(i-1)
    int ncl = (i > 0) ? 32 : 0;    // cls(i-1)
    // L1: G0(i) || A(i+1)
    k_gg<<<512, 256, 0, stream>>>(
        256, h_a, LU, ctx_at(i), DE, h0, LU, WUP0, 96, 384, zp0,
        256, P_all + (size_t)(i + 1) * BB * PR, PR, ctx_at(i), DE, h_a, LU,
        WUPa, 80, 320, zpA);
    // L2: F0(i) || Fa(i+1)+pq || Cgemv(i-1)
    k_ffg<<<256 + ng, 256, 0, stream>>>(
        128, zp0, b0, h0, c0,
        128, zpA, ba, h_a, c_a, Wq, pqp,
        ng, h1, LU, ctx_at(i - 1), DE, h1, 0, Wc, Wc, VV, 64, zpc);
    // L3: G1(i) || E(i+1) || cls(i-1) || zero ctx(i+1)
    k_gec<<<256 + 416 + ncl + 32, 256, 0, stream>>>(
        256, h0, LU, h1, LU, h0, 0, WUP1, 64, 256, zp1,
        416, keys, pqp, Mv, ast, Wv, bv, mlen, ebuf,
        ncl, zpc, bc, h1, Ws, bs, out, i - 1,
        32, ctx_at(i + 1));
    // L4: F1(i) || S(i+1) -> ctx(i+1)
    k_fsa<<<384, 256, 0, stream>>>(
        128, zp1, b1, h1, c1,
        256, ebuf, mlen, membf, ast, ctx_at(i + 1));
  }

  // ---- tail: step 255 + remaining cls ----
  {
    int i = TT - 1;  // 255
    k_gg<<<256, 256, 0, stream>>>(
        256, h_a, LU, ctx_at(i), DE, h0, LU, WUP0, 96, 384, zp0,
        0, P_all, PR, ctx_at(i), DE, h_a, LU, WUPa, 80, 320, zpA);
    k_ffg<<<256, 256, 0, stream>>>(
        128, zp0, b0, h0, c0,
        0, zpA, ba, h_a, c_a, Wq, pqp,
        128, h1, LU, ctx_at(i - 1), DE, h1, 0, Wc, Wc, VV, 64, zpc);
    k_gec<<<256 + 32, 256, 0, stream>>>(
        256, h0, LU, h1, LU, h0, 0, WUP1, 64, 256, zp1,
        0, keys, pqp, Mv, ast, Wv, bv, mlen, ebuf,
        32, zpc, bc, h1, Ws, bs, out, i - 1,
        0, ctx_at(i + 1));
    k_fsa<<<128, 256, 0, stream>>>(
        128, zp1, b1, h1, c1,
        0, ebuf, mlen, membf, ast, ctx_at(i + 1));
    // Cgemv(255) + cls(255)
    k_ffg<<<128, 256, 0, stream>>>(
        0, zp0, b0, h0, c0,
        0, zpA, ba, h_a, c_a, Wq, pqp,
        128, h1, LU, ctx_at(i), DE, h1, 0, Wc, Wc, VV, 64, zpc);
    k_gec<<<32, 256, 0, stream>>>(
        0, h0, LU, h1, LU, h0, 0, WUP1, 64, 256, zp1,
        0, keys, pqp, Mv, ast, Wv, bv, mlen, ebuf,
        32, zpc, bc, h1, Ws, bs, out, i,
        0, ctx_at(i + 1));
  }
}